// Round 22
// baseline (425.375 us; speedup 1.0000x reference)
//
#include <hip/hip_runtime.h>
#include <math.h>

// Shapes (compile-time constants from the reference)
#define Hh 1024
#define Ss 1024
#define Bb 2
#define NHh 16
#define HDd 64
#define Tt 2048   // B*S
#define Ll 256
#define Cc 2048
#define Ee 8
#define Dd 2048
#define EPSf 1e-5f
#define PADROWS 5120

using bf16x8 = __attribute__((ext_vector_type(8))) short;
using f32x4  = __attribute__((ext_vector_type(4))) float;
using ushort8 = __attribute__((ext_vector_type(8))) unsigned short;

__device__ __forceinline__ float geluf(float x) {
    return 0.5f * x * (1.0f + erff(x * 0.70710678118654752f));
}

__device__ __forceinline__ unsigned short f2bf(float x) {
    union { float f; unsigned int u; } c; c.f = x;
    unsigned int r = (c.u + 0x7fffu + ((c.u >> 16) & 1u)) >> 16;
    return (unsigned short)r;
}

__device__ __forceinline__ void gload16(const void* g, void* l) {
    __builtin_amdgcn_global_load_lds(
        (const __attribute__((address_space(1))) void*)g,
        (__attribute__((address_space(3))) void*)l, 16, 0, 0);
}

// ---------------- 128x64 transpose-cast tile, 256-thread variant ----------------
__device__ __forceinline__ void tcast_tile(const float* __restrict__ src,
        unsigned short* __restrict__ dst, int R, int C, int lt,
        unsigned short* __restrict__ tb, int tid) {
    int gx = R >> 7;
    int rt = lt % gx, ct = lt / gx;
    int r0 = rt * 128, c0 = ct * 64;
    int lr = tid >> 4;               // 0..15
    int lc4 = (tid & 15) << 2;       // 0..60
    #pragma unroll
    for (int p = 0; p < 8; ++p) {
        int row = lr + 16 * p;       // 0..127
        float4 v = *(const float4*)&src[(size_t)(r0 + row) * C + c0 + lc4];
        ushort4 h; h.x = f2bf(v.x); h.y = f2bf(v.y); h.z = f2bf(v.z); h.w = f2bf(v.w);
        *(ushort4*)&tb[row * 70 + lc4] = h;
    }
    __syncthreads();
    int wr = tid >> 5;               // 0..7
    int wc4 = (tid & 31) << 2;       // 0..124
    #pragma unroll
    for (int p = 0; p < 8; ++p) {
        int orow = wr + 8 * p;       // 0..63
        ushort4 o;
        o.x = tb[(wc4 + 0) * 70 + orow];
        o.y = tb[(wc4 + 1) * 70 + orow];
        o.z = tb[(wc4 + 2) * 70 + orow];
        o.w = tb[(wc4 + 3) * 70 + orow];
        *(ushort4*)&dst[(size_t)(c0 + orow) * R + r0 + wc4] = o;
    }
}

// ---------------- 128x64 transpose-cast tile, 512-thread variant ----------------
__device__ __forceinline__ void tcast_tile512(const float* __restrict__ src,
        unsigned short* __restrict__ dst, int R, int C, int lt,
        unsigned short* __restrict__ tb, int tid) {
    int gx = R >> 7;
    int rt = lt % gx, ct = lt / gx;
    int r0 = rt * 128, c0 = ct * 64;
    int lr = tid >> 4;               // 0..31
    int lc4 = (tid & 15) << 2;       // 0..60
    #pragma unroll
    for (int p = 0; p < 4; ++p) {
        int row = lr + 32 * p;       // 0..127
        float4 v = *(const float4*)&src[(size_t)(r0 + row) * C + c0 + lc4];
        ushort4 h; h.x = f2bf(v.x); h.y = f2bf(v.y); h.z = f2bf(v.z); h.w = f2bf(v.w);
        *(ushort4*)&tb[row * 70 + lc4] = h;
    }
    __syncthreads();
    int wr = tid >> 5;               // 0..15
    int wc4 = (tid & 31) << 2;       // 0..124
    #pragma unroll
    for (int p = 0; p < 4; ++p) {
        int orow = wr + 16 * p;      // 0..63
        ushort4 o;
        o.x = tb[(wc4 + 0) * 70 + orow];
        o.y = tb[(wc4 + 1) * 70 + orow];
        o.z = tb[(wc4 + 2) * 70 + orow];
        o.w = tb[(wc4 + 3) * 70 + orow];
        *(ushort4*)&dst[(size_t)(c0 + orow) * R + r0 + wc4] = o;
    }
}

// ---------------- minimal upfront prep: q/k/v weight transposes + bias concat ----------------
// [0,384): qw/kw/vw tiles (128 each). [384,404): biascat.
__global__ __launch_bounds__(256) void prep_all(
        const float* __restrict__ qw, const float* __restrict__ kw, const float* __restrict__ vw,
        const float* __restrict__ qb, const float* __restrict__ kb, const float* __restrict__ vb,
        const float* __restrict__ ckb, const float* __restrict__ cvb,
        unsigned short* __restrict__ qkvwT, float* __restrict__ qkvb, float* __restrict__ ckvb) {
    __shared__ unsigned short tb[128 * 70];
    int bid = blockIdx.x;
    int tid = threadIdx.x;
    if (bid < 384) {
        int seg = bid >> 7;
        int lt = bid & 127;
        const float* src = (seg == 0) ? qw : (seg == 1 ? kw : vw);
        unsigned short* dst = qkvwT + (size_t)seg * 1024 * 1024;
        tcast_tile(src, dst, 1024, 1024, lt, tb, tid);
        return;
    }
    int i = (bid - 384) * 256 + tid;      // 5120
    if (i < 1024) qkvb[i] = qb[i];
    else if (i < 2048) qkvb[i] = kb[i - 1024];
    else if (i < 3072) qkvb[i] = vb[i - 2048];
    else if (i < 4096) ckvb[i - 3072] = ckb[i - 3072];
    else if (i < 5120) ckvb[i - 3072] = cvb[i - 4096];
}

// ---------------- bf16 [bh][S][64] -> bf16 [bh][64][S] transpose (for V) ----------------
__global__ __launch_bounds__(256) void vtrans16(const unsigned short* __restrict__ in,
        unsigned short* __restrict__ out, int S) {
    __shared__ unsigned short sm[32][36];
    int bh = blockIdx.z;
    int s0 = blockIdx.x * 32, d0 = blockIdx.y * 32;
    int lr = threadIdx.x >> 3, lc = (threadIdx.x & 7) << 2;
    ushort4 v = *(const ushort4*)&in[((size_t)bh * S + s0 + lr) * 64 + d0 + lc];
    sm[lr][lc] = v.x; sm[lr][lc + 1] = v.y; sm[lr][lc + 2] = v.z; sm[lr][lc + 3] = v.w;
    __syncthreads();
    ushort4 o;
    o.x = sm[lc + 0][lr]; o.y = sm[lc + 1][lr]; o.z = sm[lc + 2][lr]; o.w = sm[lc + 3][lr];
    *(ushort4*)&out[((size_t)bh * 64 + d0 + lr) * S + s0 + lc] = o;
}

// ---------------- AdaLN modulation ----------------
__global__ __launch_bounds__(256) void adaln_kernel(const float* __restrict__ cond,
        const float* __restrict__ w, const float* __restrict__ b, float* __restrict__ mod) {
    __shared__ float ss[Hh];
    int bi = (blockIdx.x * 256) / (6 * Hh);
    const float* cp = cond + (size_t)bi * Hh;
    for (int i = threadIdx.x; i < Hh; i += 256) {
        float c = cp[i];
        ss[i] = c / (1.0f + expf(-c));
    }
    __syncthreads();
    int idx = blockIdx.x * 256 + threadIdx.x;
    int j = idx % (6 * Hh);
    float acc = b[j];
    for (int i = 0; i < Hh; ++i) acc += ss[i] * w[(size_t)i * (6 * Hh) + j];
    mod[idx] = acc;
}

// ---------------- LayerNorm + affine. OM bit0: fp32 out, bit1: bf16 out ----------------
template<int OM>
__global__ __launch_bounds__(256) void ln_affine(const float* __restrict__ X, float* __restrict__ O32,
        unsigned short* __restrict__ O16,
        const float* __restrict__ scale, const float* __restrict__ shift, int bstride, float add1) {
    int t = blockIdx.x;
    int tid = threadIdx.x;
    const float* xr = X + (size_t)t * Hh;
    float4 xv = *(const float4*)&xr[tid * 4];
    float s = xv.x + xv.y + xv.z + xv.w;
    float q = xv.x * xv.x + xv.y * xv.y + xv.z * xv.z + xv.w * xv.w;
    #pragma unroll
    for (int off = 32; off > 0; off >>= 1) {
        s += __shfl_down(s, off);
        q += __shfl_down(q, off);
    }
    __shared__ float rsum[4], rsq[4];
    __shared__ float smean, srstd;
    int wv = tid >> 6, ln = tid & 63;
    if (ln == 0) { rsum[wv] = s; rsq[wv] = q; }
    __syncthreads();
    if (tid == 0) {
        float ts = rsum[0] + rsum[1] + rsum[2] + rsum[3];
        float tq = rsq[0] + rsq[1] + rsq[2] + rsq[3];
        float mean = ts * (1.0f / Hh);
        float var = tq * (1.0f / Hh) - mean * mean;
        smean = mean; srstd = rsqrtf(var + EPSf);
    }
    __syncthreads();
    float mean = smean, rstd = srstd;
    int bi = t >> 10;
    int j = tid * 4;
    const float* scp = scale + (size_t)bi * bstride;
    const float* shp = shift + (size_t)bi * bstride;
    float4 sc4 = *(const float4*)&scp[j];
    float4 sh4 = *(const float4*)&shp[j];
    float4 o;
    o.x = (xv.x - mean) * rstd * (add1 + sc4.x) + sh4.x;
    o.y = (xv.y - mean) * rstd * (add1 + sc4.y) + sh4.y;
    o.z = (xv.z - mean) * rstd * (add1 + sc4.z) + sh4.z;
    o.w = (xv.w - mean) * rstd * (add1 + sc4.w) + sh4.w;
    if (OM & 1) *(float4*)&O32[(size_t)t * Hh + j] = o;
    if (OM & 2) {
        ushort4 h; h.x = f2bf(o.x); h.y = f2bf(o.y); h.z = f2bf(o.z); h.w = f2bf(o.w);
        *(ushort4*)&O16[(size_t)t * Hh + j] = h;
    }
}

// ---------------- 512-thread qkv GEMM + piggy-backed remaining weight prep ----------------
// Grid (16, 24+88): y<24 = GEMM blocks (M tile = x*128, N tile = y*128).
// y>=24: tile t = x + 16*(y-24) in [0,1408):
//   [0,128) ow  [128,256) cqw  [256,384) cow   (1024x1024)
//   [384,640) ckw -> ckvwT     [640,896) cvw -> ckvwT+2M   (2048x1024)
//   [896,1408): enc vcast (512 float4/block)
__global__ __launch_bounds__(512) void gemm_qkv(const unsigned short* __restrict__ A,
        const unsigned short* __restrict__ Bt, const float* __restrict__ bias,
        unsigned short* __restrict__ P0, unsigned short* __restrict__ P1,
        unsigned short* __restrict__ P2, const float* __restrict__ rc, const float* __restrict__ rsn,
        const float* __restrict__ ow, const float* __restrict__ cqw, const float* __restrict__ cow,
        const float* __restrict__ ckw, const float* __restrict__ cvw, const float* __restrict__ enc,
        unsigned short* __restrict__ owT, unsigned short* __restrict__ cqwT,
        unsigned short* __restrict__ cowT, unsigned short* __restrict__ ckvwT,
        unsigned short* __restrict__ encb, int K) {
    __shared__ unsigned short sh[2 * 128 * 32 * 2];   // 32KB: GEMM As/Bs or prep tile (17.9KB)
    int tid = threadIdx.x;
    if (blockIdx.y >= 24) {
        int t = blockIdx.x + 16 * (blockIdx.y - 24);
        if (t < 384) {
            int seg = t >> 7, lt = t & 127;
            const float* src = (seg == 0) ? ow : (seg == 1 ? cqw : cow);
            unsigned short* dst = (seg == 0) ? owT : (seg == 1 ? cqwT : cowT);
            tcast_tile512(src, dst, 1024, 1024, lt, sh, tid);
        } else if (t < 896) {
            int t2 = t - 384;
            const float* src = (t2 < 256) ? ckw : cvw;
            unsigned short* dst = (t2 < 256) ? ckvwT : (ckvwT + (size_t)1024 * 2048);
            tcast_tile512(src, dst, 2048, 1024, t2 & 255, sh, tid);
        } else {
            int i = (t - 896) * 512 + tid;
            float4 v = ((const float4*)enc)[i];
            ushort4 o; o.x = f2bf(v.x); o.y = f2bf(v.y); o.z = f2bf(v.z); o.w = f2bf(v.w);
            ((ushort4*)encb)[i] = o;
        }
        return;
    }
    unsigned short* As0 = sh;
    unsigned short* Bs0 = sh + 2 * 128 * 32;
    int m0 = blockIdx.x * 128, n0 = blockIdx.y * 128;
    int lane = tid & 63;
    int wv = tid >> 6;
    int wm = (wv >> 1) * 32, wn = (wv & 1) * 64;
    f32x4 acc[2][4] = {};
    int r0 = tid >> 2, q8 = (tid & 3) * 8;
    const unsigned short* gA = A + (size_t)(m0 + r0) * K + q8;
    const unsigned short* gB = Bt + (size_t)(n0 + r0) * K + q8;
    int ra = (lane & 15) * 32 + (lane >> 4) * 8;
    auto stage = [&](int kk, int bufi) {
        gload16(gA + kk, &As0[bufi * 128 * 32 + tid * 8]);
        gload16(gB + kk, &Bs0[bufi * 128 * 32 + tid * 8]);
    };
    int nsteps = K / 32;
    stage(0, 0);
    int cur = 0;
    for (int s = 0; s < nsteps; ++s) {
        if (s + 1 < nsteps) {
            stage((s + 1) * 32, cur ^ 1);
            asm volatile("s_waitcnt vmcnt(2)" ::: "memory");
        } else {
            asm volatile("s_waitcnt vmcnt(0)" ::: "memory");
        }
        __builtin_amdgcn_s_barrier();
        bf16x8 af[2], bf[4];
        #pragma unroll
        for (int f = 0; f < 2; ++f) af[f] = *(const bf16x8*)&As0[cur * 128 * 32 + (wm + f * 16) * 32 + ra];
        #pragma unroll
        for (int f = 0; f < 4; ++f) bf[f] = *(const bf16x8*)&Bs0[cur * 128 * 32 + (wn + f * 16) * 32 + ra];
        #pragma unroll
        for (int i = 0; i < 2; ++i)
            #pragma unroll
            for (int j = 0; j < 4; ++j)
                acc[i][j] = __builtin_amdgcn_mfma_f32_16x16x32_bf16(af[i], bf[j], acc[i][j], 0, 0, 0);
        asm volatile("s_waitcnt lgkmcnt(0)" ::: "memory");
        __builtin_amdgcn_s_barrier();
        cur ^= 1;
    }
    int colb = n0 + wn + (lane & 15);
    int rowb = m0 + wm + (lane >> 4) * 4;
    float bv[4];
    #pragma unroll
    for (int j = 0; j < 4; ++j) bv[j] = bias[colb + j * 16];
    int nh = (colb >> 6) & 15;
    int type = colb >> 10;
    float qs = (type == 0) ? 0.125f : 1.0f;   // fold 1/sqrt(HD) into Q
    #pragma unroll
    for (int i = 0; i < 2; ++i) {
        #pragma unroll
        for (int r = 0; r < 4; ++r) {
            int row = rowb + i * 16 + r;
            int b = row >> 10, s = row & 1023;
            unsigned short* dst = (type == 0) ? P0 : (type == 1 ? P1 : P2);
            size_t obase = ((size_t)((b * 16 + nh) * 1024 + s)) * 64;
            if (type < 2) {
                #pragma unroll
                for (int j = 0; j < 2; ++j) {
                    int hd = j * 16 + (lane & 15);
                    float v0 = acc[i][j][r] + bv[j];
                    float v2 = acc[i][j + 2][r] + bv[j + 2];
                    float c1 = rc[s * 64 + hd], s1 = rsn[s * 64 + hd];
                    float c2 = rc[s * 64 + hd + 32], s2 = rsn[s * 64 + hd + 32];
                    dst[obase + hd] = f2bf((v0 * c1 - v2 * s1) * qs);
                    dst[obase + hd + 32] = f2bf((v2 * c2 + v0 * s2) * qs);
                }
            } else {
                #pragma unroll
                for (int j = 0; j < 4; ++j)
                    dst[obase + j * 16 + (lane & 15)] = f2bf(acc[i][j][r] + bv[j]);
            }
        }
    }
}

// ===== 64x64-tile GEMM: 256 threads, 4 waves (2x2) of 32x32, 2-buffer =====
// EP 0: fp32 store. EP 2: ckv pack (rows/batch=256, P0=cK, P1=cV).
// EP 3: cQ pack *0.125 (rows/batch=1024 -> P0). EP 4: Cf=baseb+gate*(acc+bias).
// EP 5: Cf=baseb+(acc+bias) (baseb may alias Cf).
template<int EP>
__global__ __launch_bounds__(256) void gemm64(const unsigned short* __restrict__ A,
        const unsigned short* __restrict__ Bt, const float* __restrict__ bias,
        float* __restrict__ Cf, unsigned short* __restrict__ P0, unsigned short* __restrict__ P1,
        const float* __restrict__ baseb, const float* __restrict__ gatep,
        int M, int N, int K) {
    __shared__ unsigned short As[2][64 * 32];
    __shared__ unsigned short Bs[2][64 * 32];
    int m0 = blockIdx.x * 64, n0 = blockIdx.y * 64;
    int tid = threadIdx.x;
    int lane = tid & 63;
    int wv = tid >> 6;                        // 0..3
    int wm = (wv >> 1) * 32, wn = (wv & 1) * 32;
    f32x4 acc[2][2] = {};
    int r0 = tid >> 2, q8 = (tid & 3) * 8;    // r0 in [0,64)
    const unsigned short* gA = A + (size_t)(m0 + r0) * K + q8;
    const unsigned short* gB = Bt + (size_t)(n0 + r0) * K + q8;
    int ra = (lane & 15) * 32 + (lane >> 4) * 8;
    auto stage = [&](int kk, int bufi) {
        gload16(gA + kk, &As[bufi][tid * 8]);
        gload16(gB + kk, &Bs[bufi][tid * 8]);
    };
    int nsteps = K / 32;
    stage(0, 0);
    int cur = 0;
    for (int s = 0; s < nsteps; ++s) {
        if (s + 1 < nsteps) {
            stage((s + 1) * 32, cur ^ 1);
            asm volatile("s_waitcnt vmcnt(2)" ::: "memory");
        } else {
            asm volatile("s_waitcnt vmcnt(0)" ::: "memory");
        }
        __builtin_amdgcn_s_barrier();
        bf16x8 af[2], bf[2];
        #pragma unroll
        for (int f = 0; f < 2; ++f) {
            af[f] = *(const bf16x8*)&As[cur][(wm + f * 16) * 32 + ra];
            bf[f] = *(const bf16x8*)&Bs[cur][(wn + f * 16) * 32 + ra];
        }
        #pragma unroll
        for (int i = 0; i < 2; ++i)
            #pragma unroll
            for (int j = 0; j < 2; ++j)
                acc[i][j] = __builtin_amdgcn_mfma_f32_16x16x32_bf16(af[i], bf[j], acc[i][j], 0, 0, 0);
        asm volatile("s_waitcnt lgkmcnt(0)" ::: "memory");
        __builtin_amdgcn_s_barrier();
        cur ^= 1;
    }
    // D layout: col = lane&15, row = (lane>>4)*4 + reg
    int colb = n0 + wn + (lane & 15);
    int rowb = m0 + wm + (lane >> 4) * 4;
    float bv[2];
    #pragma unroll
    for (int j = 0; j < 2; ++j) bv[j] = bias[colb + j * 16];
    if (EP == 0 || EP == 4 || EP == 5) {
        #pragma unroll
        for (int j = 0; j < 2; ++j) {
            int col = colb + j * 16;
            #pragma unroll
            for (int i = 0; i < 2; ++i)
                #pragma unroll
                for (int r = 0; r < 4; ++r) {
                    int row = rowb + i * 16 + r;
                    size_t gi = (size_t)row * N + col;
                    float v = acc[i][j][r] + bv[j];
                    if (EP == 0) {
                        Cf[gi] = v;
                    } else if (EP == 4) {
                        float g = gatep[(row >> 10) * (6 * Hh) + col];
                        Cf[gi] = baseb[gi] + g * v;
                    } else {
                        Cf[gi] = baseb[gi] + v;
                    }
                }
        }
        return;
    }
    int nh = (colb >> 6) & 15;
    int type = colb >> 10;
    int hd0 = colb & 63;
    #pragma unroll
    for (int i = 0; i < 2; ++i) {
        #pragma unroll
        for (int r = 0; r < 4; ++r) {
            int row = rowb + i * 16 + r;
            if (EP == 2) {
                int b = row >> 8, s = row & 255;
                unsigned short* dst = (type == 0) ? P0 : P1;
                size_t obase = ((size_t)((b * 16 + nh) * 256 + s)) * 64;
                #pragma unroll
                for (int j = 0; j < 2; ++j)
                    dst[obase + hd0 + j * 16] = f2bf(acc[i][j][r] + bv[j]);
            } else {  // EP == 3: cQ pack, pre-scaled by 1/sqrt(HD)
                int b = row >> 10, s = row & 1023;
                size_t obase = ((size_t)((b * 16 + nh) * 1024 + s)) * 64;
                #pragma unroll
                for (int j = 0; j < 2; ++j)
                    P0[obase + hd0 + j * 16] = f2bf((acc[i][j][r] + bv[j]) * 0.125f);
            }
        }
    }
}

// ---------------- gathered MoE fc1 (64x64 tiles, 256 threads, high-occupancy) ----------------
__global__ __launch_bounds__(256) void gemm_moe1(const unsigned short* __restrict__ A,
        const unsigned short* __restrict__ W, const float* __restrict__ bias,
        unsigned short* __restrict__ Og, const int* __restrict__ cnt,
        const int* __restrict__ offp, const int* __restrict__ gtok) {
    __shared__ unsigned short As[2][64 * 32];
    __shared__ unsigned short Bs[2][64 * 32];
    int m0 = blockIdx.x * 64;
    if (m0 >= offp[Ee]) return;
    int e = 0;
    while (offp[e + 1] <= m0) ++e;
    int base = offp[e], valid = cnt[e];
    int n0 = blockIdx.y * 64;
    int tid = threadIdx.x;
    int lane = tid & 63;
    int wv = tid >> 6;
    int wm = (wv >> 1) * 32, wn = (wv & 1) * 32;
    f32x4 acc[2][2] = {};
    int r0 = tid >> 2, q8 = (tid & 3) * 8;    // r0 in [0,64)
    int lr0 = m0 - base + r0;
    int tok0 = gtok[base + (lr0 < valid ? lr0 : 0)];
    const unsigned short* gA = A + (size_t)tok0 * Hh + q8;
    const unsigned short* Wt = W + (size_t)e * Dd * Hh;
    const unsigned short* gB = Wt + (size_t)(n0 + r0) * Hh + q8;
    int ra = (lane & 15) * 32 + (lane >> 4) * 8;
    auto stage = [&](int kk, int bufi) {
        gload16(gA + kk, &As[bufi][tid * 8]);
        gload16(gB + kk, &Bs[bufi][tid * 8]);
    };
    int nsteps = Hh / 32;
    stage(0, 0);
    int cur = 0;
    for (int s = 0; s < nsteps; ++s) {
        if (s + 1 < nsteps) {
            stage((s + 1) * 32, cur ^ 1);
            asm volatile("s_waitcnt vmcnt(2)" ::: "memory");
        } else {
            asm volatile("s_waitcnt vmcnt(0)" ::: "memory");
        }
        __builtin_amdgcn_s_barrier();
        bf16x8 af[2], bf[2];
        #pragma unroll
        for (int f = 0; f < 2; ++f) {
            af[f] = *(const bf16x8*)&As[cur][(wm + f * 16) * 32 + ra];
            bf[f] = *(const bf16x8*)&Bs[cur][(wn + f * 16) * 32 + ra];
        }
        #pragma unroll
        for (int i = 0; i < 2; ++i)
            #pragma unroll
            for (int j = 0; j < 2; ++j)
                acc[i][j] = __builtin_amdgcn_mfma_f32_16x16x32_bf16(af[i], bf[j], acc[i][j], 0, 0, 0);
        asm volatile("s_waitcnt lgkmcnt(0)" ::: "memory");
        __builtin_amdgcn_s_barrier();
        cur ^= 1;
    }
    int colb = n0 + wn + (lane & 15);
    int rowtb = wm + (lane >> 4) * 4;
    const float* bp = bias + (size_t)e * Dd;
    #pragma unroll
    for (int j = 0; j < 2; ++j) {
        int col = colb + j * 16;
        float bv = bp[col];
        #pragma unroll
        for (int i = 0; i < 2; ++i) {
            #pragma unroll
            for (int r = 0; r < 4; ++r) {
                int rt = rowtb + i * 16 + r;
                if (m0 - base + rt < valid)
                    Og[(size_t)(m0 + rt) * Dd + col] = f2bf(geluf(acc[i][j][r] + bv));
            }
        }
    }
}

// ---------------- gathered MoE fc2 (64x64 tiles, 256 threads): plain stores into y[g][col] ----------------
__global__ __launch_bounds__(256) void gemm_moe2(const unsigned short* __restrict__ A,
        const unsigned short* __restrict__ W, const float* __restrict__ bias,
        float* __restrict__ y, const int* __restrict__ cnt,
        const int* __restrict__ offp) {
    __shared__ unsigned short As[2][64 * 32];
    __shared__ unsigned short Bs[2][64 * 32];
    int m0 = blockIdx.x * 64;
    if (m0 >= offp[Ee]) return;
    int e = 0;
    while (offp[e + 1] <= m0) ++e;
    int base = offp[e], valid = cnt[e];
    int n0 = blockIdx.y * 64;
    int tid = threadIdx.x;
    int lane = tid & 63;
    int wv = tid >> 6;
    int wm = (wv >> 1) * 32, wn = (wv & 1) * 32;
    f32x4 acc[2][2] = {};
    int r0 = tid >> 2, q8 = (tid & 3) * 8;
    const unsigned short* gA = A + (size_t)(m0 + r0) * Dd + q8;
    const unsigned short* Wt = W + (size_t)e * Hh * Dd;
    const unsigned short* gB = Wt + (size_t)(n0 + r0) * Dd + q8;
    int ra = (lane & 15) * 32 + (lane >> 4) * 8;
    auto stage = [&](int kk, int bufi) {
        gload16(gA + kk, &As[bufi][tid * 8]);
        gload16(gB + kk, &Bs[bufi][tid * 8]);
    };
    int nsteps = Dd / 32;
    stage(0, 0);
    int cur = 0;
    for (int s = 0; s < nsteps; ++s) {
        if (s + 1 < nsteps) {
            stage((s + 1) * 32, cur ^ 1);
            asm volatile("s_waitcnt vmcnt(2)" ::: "memory");
        } else {
            asm volatile("s_waitcnt vmcnt(0)" ::: "memory");
        }
        __builtin_amdgcn_s_barrier();
        bf16x8 af[2], bf[2];
        #pragma unroll
        for (int f = 0; f < 2; ++f) {
            af[f] = *(const bf16x8*)&As[cur][(wm + f * 16) * 32 + ra];
            bf[f] = *(const bf16x8*)&Bs[cur][(wn + f * 16) * 32 + ra];
        }
        #pragma unroll
        for (int i = 0; i < 2; ++i)
            #pragma unroll
            for (int j = 0; j < 2; ++j)
                acc[i][j] = __builtin_amdgcn_mfma_f32_16x16x32_bf16(af[i], bf[j], acc[i][j], 0, 0, 0);
        asm volatile("s_waitcnt lgkmcnt(0)" ::: "memory");
        __builtin_amdgcn_s_barrier();
        cur ^= 1;
    }
    int colb = n0 + wn + (lane & 15);
    int rowtb = wm + (lane >> 4) * 4;
    const float* bp = bias + (size_t)e * Hh;
    #pragma unroll
    for (int j = 0; j < 2; ++j) {
        int col = colb + j * 16;
        float bv = bp[col];
        #pragma unroll
        for (int i = 0; i < 2; ++i) {
            #pragma unroll
            for (int r = 0; r < 4; ++r) {
                int rt = rowtb + i * 16 + r;
                int g = m0 + rt;
                if (g - base < valid)
                    y[(size_t)g * Hh + col] = acc[i][j][r] + bv;
            }
        }
    }
}

// ---------------- MoE combine: out[t] += g2 .* (w0*y[g0] + w1*y[g1]) ----------------
__global__ __launch_bounds__(256) void moe_combine(const float* __restrict__ y,
        const int* __restrict__ gpos, const float* __restrict__ gwt,
        const float* __restrict__ gate2, float* __restrict__ outp) {
    int t = blockIdx.x;
    int j = threadIdx.x * 4;
    int g0 = gpos[2 * t], g1 = gpos[2 * t + 1];
    float w0 = gwt[g0], w1 = gwt[g1];
    const float* g2p = gate2 + (size_t)(t >> 10) * (6 * Hh);
    float4 a = *(const float4*)&y[(size_t)g0 * Hh + j];
    float4 b = *(const float4*)&y[(size_t)g1 * Hh + j];
    float4 g2 = *(const float4*)&g2p[j];
    float4 o = *(const float4*)&outp[(size_t)t * Hh + j];
    o.x += g2.x * (w0 * a.x + w1 * b.x);
    o.y += g2.y * (w0 * a.y + w1 * b.y);
    o.z += g2.z * (w0 * a.z + w1 * b.z);
    o.w += g2.w * (w0 * a.w + w1 * b.w);
    *(float4*)&outp[(size_t)t * Hh + j] = o;
}

// ---------------- MFMA flash attention + piggy-backed MoE weight transposes ----------------
__global__ __launch_bounds__(256) void fattn_m(const unsigned short* __restrict__ Qp,
        const unsigned short* __restrict__ Kp, const unsigned short* __restrict__ Vtp,
        unsigned short* __restrict__ O, int Skv,
        const float* __restrict__ ew1, const float* __restrict__ ew2,
        unsigned short* __restrict__ ew1T, unsigned short* __restrict__ ew2T) {
    __shared__ unsigned short shbuf[4 * 64 * 72];   // 36,864B; prep tile needs 8,960 shorts
    int tid = threadIdx.x;
    if (blockIdx.y >= 32) {
        int tile = blockIdx.x + 16 * (blockIdx.y - 32);   // 0..4095
        if (tile < 2048) {
            int e = tile >> 8, lt = tile & 255;           // ew1[e]: 1024x2048, 8x32 tiles
            tcast_tile(ew1 + (size_t)e * 1024 * 2048, ew1T + (size_t)e * 2048 * 1024,
                       1024, 2048, lt, shbuf, tid);
        } else {
            int t2 = tile - 2048;
            int e = t2 >> 8, lt = t2 & 255;               // ew2[e]: 2048x1024, 16x16 tiles
            tcast_tile(ew2 + (size_t)e * 2048 * 1024, ew2T + (size_t)e * 1024 * 2048,
                       2048, 1024, lt, shbuf, tid);
        }
        return;
    }
    unsigned short* Qs  = shbuf;
    unsigned short* Ks  = shbuf + 64 * 72;
    unsigned short* Vts = shbuf + 2 * 64 * 72;
    unsigned short* Ps  = shbuf + 3 * 64 * 72;
    int q0 = blockIdx.x * 64;
    int bh = blockIdx.y;
    int b = bh >> 4, nh = bh & 15;
    int lane = tid & 63, w = tid >> 6;
    int sr = tid >> 2, sp = (tid & 3) * 16;   // staging: row, 16-elem chunk
    {
        const unsigned short* src = &Qp[((size_t)bh * 1024 + q0 + sr) * 64 + sp];
        *(ushort8*)&Qs[sr * 72 + sp] = *(const ushort8*)&src[0];
        *(ushort8*)&Qs[sr * 72 + sp + 8] = *(const ushort8*)&src[8];
    }
    f32x4 acc[4] = {};
    float m_old[4], l_run[4];
    #pragma unroll
    for (int r = 0; r < 4; ++r) { m_old[r] = -1e30f; l_run[r] = 0.0f; }
    int wrow = w * 16;
    int k8 = (lane >> 4) * 8;
    ushort8 pkA, pkB, pvA, pvB;
    {
        const unsigned short* ksrc = &Kp[((size_t)bh * Skv + sr) * 64 + sp];
        pkA = *(const ushort8*)&ksrc[0];
        pkB = *(const ushort8*)&ksrc[8];
        const unsigned short* vsrc = &Vtp[((size_t)bh * 64 + sr) * Skv + sp];
        pvA = *(const ushort8*)&vsrc[0];
        pvB = *(const ushort8*)&vsrc[8];
    }
    for (int k0 = 0; k0 < Skv; k0 += 64) {
        asm volatile("s_waitcnt lgkmcnt(0)" ::: "memory");
        __builtin_amdgcn_s_barrier();                  // Ks/Vts free (prev PV reads done)
        *(ushort8*)&Ks[sr * 72 + sp] = pkA;
        *(ushort8*)&Ks[sr * 72 + sp + 8] = pkB;
        *(ushort8*)&Vts[sr * 72 + sp] = pvA;
        *(ushort8*)&Vts[sr * 72 + sp + 8] = pvB;
        if (k0 + 64 < Skv) {
            const unsigned short* ksrc = &Kp[((size_t)bh * Skv + k0 + 64 + sr) * 64 + sp];
            pkA = *(const ushort8*)&ksrc[0];
            pkB = *(const ushort8*)&ksrc[8];
            const unsigned short* vsrc = &Vtp[((size_t)bh * 64 + sr) * Skv + k0 + 64 + sp];
            pvA = *(const ushort8*)&vsrc[0];
            pvB = *(const ushort8*)&vsrc[8];
        }
        asm volatile("s_waitcnt lgkmcnt(0)" ::: "memory");
        __builtin_amdgcn_s_barrier();                  // staging (and iter-0 Qs) visible
        bf16x8 aq0 = *(const bf16x8*)&Qs[(wrow + (lane & 15)) * 72 + k8];
        bf16x8 aq1 = *(const bf16x8*)&Qs[(wrow + (lane & 15)) * 72 + 32 + k8];
        f32x4 sf[4];
        __builtin_amdgcn_s_setprio(1);
        #pragma unroll
        for (int j = 0; j < 4; ++j) {
            bf16x8 bk0 = *(const bf16x8*)&Ks[(j * 16 + (lane & 15)) * 72 + k8];
            bf16x8 bk1 = *(const bf16x8*)&Ks[(j * 16 + (lane & 15)) * 72 + 32 + k8];
            f32x4 z = {};
            z = __builtin_amdgcn_mfma_f32_16x16x32_bf16(aq0, bk0, z, 0, 0, 0);
            z = __builtin_amdgcn_mfma_f32_16x16x32_bf16(aq1, bk1, z, 0, 0, 0);
            sf[j] = z;
        }
        __builtin_amdgcn_s_setprio(0);
        float p[4][4];
        float fsc[4];
        #pragma unroll
        for (int r = 0; r < 4; ++r) {
            float mx = fmaxf(fmaxf(sf[0][r], sf[1][r]), fmaxf(sf[2][r], sf[3][r]));
            #pragma unroll
            for (int mk = 1; mk < 16; mk <<= 1) mx = fmaxf(mx, __shfl_xor(mx, mk));
            float mn = fmaxf(m_old[r], mx);
            float f = __expf(m_old[r] - mn);
            float rs = 0.0f;
            #pragma unroll
            for (int j = 0; j < 4; ++j) {
                p[j][r] = __expf(sf[j][r] - mn);
                rs += p[j][r];
            }
            #pragma unroll
            for (int mk = 1; mk < 16; mk <<= 1) rs += __shfl_xor(rs, mk);
            l_run[r] = l_run[r] * f + rs;
            m_old[r] = mn;
            fsc[r] = f;
        }
        #pragma unroll
        for (int jd = 0; jd < 4; ++jd)
            #pragma unroll
            for (int r = 0; r < 4; ++r) acc[jd][r] *= fsc[r];
        #pragma unroll
        for (int j = 0; j < 4; ++j)
            #pragma unroll
            for (int r = 0; r < 4; ++r)
                Ps[(wrow + (lane >> 4) * 4 + r) * 72 + j * 16 + (lane & 15)] = f2bf(p[j][r]);
        asm volatile("s_waitcnt lgkmcnt(0)" ::: "memory");
        __builtin_amdgcn_s_barrier();                  // Ps visible
        bf16x8 ap0 = *(const bf16x8*)&Ps[(wrow + (lane & 15)) * 72 + k8];
        bf16x8 ap1 = *(const bf16x8*)&Ps[(wrow + (lane & 15)) * 72 + 32 + k8];
        __builtin_amdgcn_s_setprio(1);
        #pragma unroll
        for (int jd = 0; jd < 4; ++jd) {
            bf16x8 bv0 = *(const bf16x8*)&Vts[(jd * 16 + (lane & 15)) * 72 + k8];
            bf16x8 bv1 = *(const bf16x8*)&Vts[(jd * 16 + (lane & 15)) * 72 + 32 + k8];
            acc[jd] = __builtin_amdgcn_mfma_f32_16x16x32_bf16(ap0, bv0, acc[jd], 0, 0, 0);
            acc[jd] = __builtin_amdgcn_mfma_f32_16x16x32_bf16(ap1, bv1, acc[jd], 0, 0, 0);
        }
        __builtin_amdgcn_s_setprio(0);
    }
    float inv[4];
    #pragma unroll
    for (int r = 0; r < 4; ++r) inv[r] = 1.0f / l_run[r];
    #pragma unroll
    for (int jd = 0; jd < 4; ++jd)
        #pragma unroll
        for (int r = 0; r < 4; ++r)
            O[((size_t)(b * Ss + q0 + wrow + (lane >> 4) * 4 + r)) * Hh + nh * 64 + jd * 16 + (lane & 15)]
                = f2bf(acc[jd][r] * inv[r]);
}

// ---------------- MoE gate: one wave per token, coalesced ----------------
__global__ __launch_bounds__(256) void gate_kernel(const float* __restrict__ h,
        const float* __restrict__ gw, float* __restrict__ probs, int* __restrict__ topi,
        float* __restrict__ topw) {
    int t = blockIdx.x * 4 + (threadIdx.x >> 6);
    int lane = threadIdx.x & 63;
    const float* hp = h + (size_t)t * Hh;
    float lg[Ee] = {};
    #pragma unroll
    for (int s = 0; s < 4; ++s) {
        int d0 = s * 256 + lane * 4;
        float4 hv = *(const float4*)&hp[d0];
        float hv4[4] = {hv.x, hv.y, hv.z, hv.w};
        #pragma unroll
        for (int c = 0; c < 4; ++c) {
            float hx = hv4[c];
            const float* g0 = &gw[(size_t)(d0 + c) * Ee];
            #pragma unroll
            for (int e = 0; e < Ee; ++e) lg[e] += hx * g0[e];
        }
    }
    #pragma unroll
    for (int e = 0; e < Ee; ++e)
        #pragma unroll
        for (int mk = 1; mk < 64; mk <<= 1) lg[e] += __shfl_xor(lg[e], mk);
    if (lane == 0) {
        float m = lg[0];
        #pragma unroll
        for (int e = 1; e < Ee; ++e) m = fmaxf(m, lg[e]);
        float ssum = 0;
        #pragma unroll
        for (int e = 0; e < Ee; ++e) { lg[e] = expf(lg[e] - m); ssum += lg[e]; }
        float inv = 1.0f / ssum;
        #pragma unroll
        for (int e = 0; e < Ee; ++e) { lg[e] *= inv; probs[t * Ee + e] = lg[e]; }
        int i0 = 0;
        #pragma unroll
        for (int e = 1; e < Ee; ++e) if (lg[e] > lg[i0]) i0 = e;
        int i1 = (i0 == 0) ? 1 : 0;
        #pragma unroll
        for (int e = 0; e < Ee; ++e) if (e != i1 && e != i0 && lg[e] > lg[i1]) i1 = e;
        float w0 = lg[i0], w1 = lg[i1];
        float inv2 = 1.0f / (w0 + w1);
        topi[t * 2] = i0; topi[t * 2 + 1] = i1;
        topw[t * 2] = w0 * inv2; topw[t * 2 + 1] = w1 * inv2;
    }
}

// ---------------- fused MoE prep: count + scan + scatter + aux (single 1024-thread block) ----------------
__global__ __launch_bounds__(1024) void moe_prep(const float* __restrict__ probs,
        const int* __restrict__ topi, const float* __restrict__ topw,
        int* __restrict__ cnt, int* __restrict__ offp,
        int* __restrict__ gtok, float* __restrict__ gwt, int* __restrict__ gpos,
        float* __restrict__ auxout) {
    __shared__ int scnt[Ee], spos[Ee], soff[Ee + 1];
    __shared__ float sS[Ee], sC[Ee];
    int tid = threadIdx.x;
    if (tid < Ee) { scnt[tid] = 0; spos[tid] = 0; sS[tid] = 0.0f; sC[tid] = 0.0f; }
    __syncthreads();
    float lp[Ee] = {};
    float lc[Ee] = {};
    for (int t = tid; t < Tt; t += 1024) {
        int a0 = topi[2 * t], a1 = topi[2 * t + 1];
        atomicAdd(&scnt[a0], 1);
        atomicAdd(&scnt[a1], 1);
        #pragma unroll
        for (int e = 0; e < Ee; ++e) lp[e] += probs[t * Ee + e];
        lc[a0] += 1.0f; lc[a1] += 1.0f;
    }
    #pragma unroll
    for (int e = 0; e < Ee; ++e) {
        atomicAdd(&sS[e], lp[e]);
        atomicAdd(&sC[e], lc[e]);
    }
    __syncthreads();
    if (tid == 0) {
        int acc = 0;
        for (int e = 0; e < Ee; ++e) { soff[e] = acc; acc += (scnt[e] + 127) & ~127; }
        soff[Ee] = acc;
        float aux = 0.0f;
        for (int e = 0; e < Ee; ++e) aux += sS[e] * sC[e];
        auxout[0] = aux * (8.0f / 4096.0f);   // E/(B*B*S)
    }
    if (tid < Ee) cnt[tid] = scnt[tid];
    __syncthreads();
    if (tid <= Ee) offp[tid] = soff[tid];
    for (int t = tid; t < Tt; t += 1024) {
        #pragma unroll
        for (int s = 0; s < 2; ++s) {
            int e = topi[2 * t + s];
            int pos = atomicAdd(&spos[e], 1);
            int g = soff[e] + pos;
            gtok[g] = t;
            gwt[g] = topw[2 * t + s];
            gpos[2 * t + s] = g;
        }
    }
}

extern "C" void kernel_launch(void* const* d_in, const int* in_sizes, int n_in,
                              void* d_out, int out_size, void* d_ws, size_t ws_size,
                              hipStream_t stream) {
    (void)in_sizes; (void)n_in; (void)out_size; (void)ws_size;
    const float* x    = (const float*)d_in[0];
    const float* cond = (const float*)d_in[1];
    const float* enc  = (const float*)d_in[2];
    const float* rc   = (const float*)d_in[3];
    const float* rsn  = (const float*)d_in[4];
    const float* adw  = (const float*)d_in[5];
    const float* adb  = (const float*)d_in[6];
    const float* qw  = (const float*)d_in[7];  const float* qb  = (const float*)d_in[8];
    const float* kw  = (const float*)d_in[9];  const float* kb2 = (const float*)d_in[10];
    const float* vw  = (const float*)d_in[11]; const float* vb  = (const float*)d_in[12];
    const float* ow  = (const float*)d_in[13]; const float* ob  = (const float*)d_in[14];
    const float* cqw = (const float*)d_in[15]; const float* cqb = (const float*)d_in[16];
    const float* ckw = (const float*)d_in[17]; const float* ckb = (const float*)d_in[18];
    const float* cvw = (const float*)d_in[19]; const float* cvb = (const float*)d_in[20];
    const float* cow = (const float*)d_in[21]; const float* cob = (const float*)d_in[22];
    const float* cng = (const float*)d_in[23]; const float* cnb = (const float*)d_in[24];
    const float* gatew = (const float*)d_in[25];
    const float* ew1 = (const float*)d_in[26]; const float* eb1 = (const float*)d_in[27];
    const float* ew2 = (const float*)d_in[28]; const float* eb2 = (const float*)d_in[29];
    float* out = (float*)d_out;

    char* ws = (char*)d_ws;
    size_t off = 0;
    auto alloc = [&](size_t bytes) {
        char* p = ws + off;
        off += (bytes + 255) & ~(size_t)255;
        return (void*)p;
    };
    // fp32 buffers
    float* hbuf   = (float*)alloc((size_t)Tt * Hh * 4);
    float* mod    = (float*)alloc((size_t)Bb * 6 * Hh * 4);
    float* probs  = (float*)alloc((size_t)Tt * Ee * 4);
    float* topw   = (float*)alloc((size_t)Tt * 2 * 4);
    int*   topi   = (int*)alloc((size_t)Tt * 2 * 4);
    float* qkvb   = (float*)alloc(3072 * 4);
    float* ckvb   = (float*)alloc(2048 * 4);
    int*   cntbuf = (int*)alloc(16 * 4);
    int*   offp   = (int*)alloc(16 * 4);
    int*   gtok   = (int*)alloc((size_t)PADROWS * 4);
    float* gwt    = (float*)alloc((size_t)PADROWS * 4);
    int*   gpos   = (int*)alloc((size_t)Tt * 2 * 4);
    // bf16 buffers
    typedef unsigned short u16;
    u16* h1b   = (u16*)alloc((size_t)Tt * Hh * 2);
    u16* hcb   = (u16*)alloc((size_t)Tt * Hh * 2);
    u16* h2b   = (u16*)alloc((size_t)Tt * Hh * 2);
    u16* abb   = (u16*)alloc((size_t)Tt * Hh * 2);
    u16* encb  = (u16*)alloc((size_t)Bb * Ll * Cc * 2);
    u16* actg  = (u16*)alloc((size_t)PADROWS * Dd * 2);
    // packed attention operands
    u16* Qb16  = (u16*)alloc((size_t)32 * 1024 * 64 * 2);
    u16* Kb16  = (u16*)alloc((size_t)32 * 1024 * 64 * 2);
    u16* Vb16  = (u16*)alloc((size_t)32 * 1024 * 64 * 2);
    u16* Vt16  = (u16*)alloc((size_t)32 * 64 * 1024 * 2);
    u16* cQ16  = (u16*)alloc((size_t)32 * 1024 * 64 * 2);
    u16* cK16  = (u16*)alloc((size_t)32 * 256 * 64 * 2);
    u16* cV16  = (u16*)alloc((size_t)32 * 256 * 64 * 2);
    u16* cVt16 = (u16*)alloc((size_t)32 * 64 * 256 * 2);
    // bf16 transposed weights [N][K]
    u16* qkvwT = (u16*)alloc((size_t)3072 * 1024 * 2);
    u16* owT   = (u16*)alloc((size_t)1024 * 1024 * 2);
    u16* cqwT  = (u16*)alloc((size_t)1024 * 1024 * 2);
    u16* ckvwT = (u16*)alloc((size_t)2048 * 2048 * 2);
    u16* cowT  = (u16*)alloc((size_t)1024 * 1024 * 2);
    u16* ew1T  = (u16*)alloc((size_t)Ee * Hh * Dd * 2);
    u16* ew2T  = (u16*)alloc((size_t)Ee * Dd * Hh * 2);
    // MoE fc2 gathered output y[PADROWS][Hh] fp32 (20.97 MB), aliased over the
    // Qb16..cQ16 span (5 x 4 MB, dead after cross-attention).
    float* ybuf = (float*)Qb16;

    dim3 blk(256);
    dim3 blk512(512);
    // --- minimal upfront prep: q/k/v transposes + biascat ---
    prep_all<<<dim3(404), blk, 0, stream>>>(qw, kw, vw, qb, kb2, vb, ckb, cvb,
        qkvwT, qkvb, ckvb);
    // 1. AdaLN modulation
    adaln_kernel<<<dim3(Bb * 6 * Hh / 256), blk, 0, stream>>>(cond, adw, adb, mod);
    // 2. h1 = ln(x)*(1+sc1)+sh1  -> bf16
    ln_affine<2><<<dim3(Tt), blk, 0, stream>>>(x, nullptr, h1b, mod + Hh, mod + 0, 6 * Hh, 1.0f);
    // 3. fused qkv projection + rope + pack (+1408 piggy-backed prep blocks)
    gemm_qkv<<<dim3(16, 24 + 88), blk512, 0, stream>>>(h1b, qkvwT, qkvb,
        Qb16, Kb16, Vb16, rc, rsn,
        ow, cqw, cow, ckw, cvw, enc, owT, cqwT, cowT, ckvwT, encb, 1024);
    // 4. V transpose [bh][64][1024]
    vtrans16<<<dim3(32, 2, 32), blk, 0, stream>>>(Vb16, Vt16, 1024);
    // 5. MFMA self-attention (+4096 piggy-backed ew1/ew2 transpose tiles)
    fattn_m<<<dim3(16, 32 + 256), blk, 0, stream>>>(Qb16, Kb16, Vt16, abb, 1024,
        ew1, ew2, ew1T, ew2T);
    // 6+7. output projection fused with residual: out = x + g1*(a@ow+ob)
    gemm64<4><<<dim3(Tt / 64, Hh / 64), blk, 0, stream>>>(abb, owT, ob, out,
        nullptr, nullptr, x, mod + 2 * Hh, Tt, Hh, 1024);
    // 8. hc = ln(x1)*cn_g + cn_b -> bf16
    ln_affine<2><<<dim3(Tt), blk, 0, stream>>>(out, nullptr, hcb, cng, cnb, 0, 0.0f);
    // 9. cross q (packed, pre-scaled) + fused ck/cv (packed)
    gemm64<3><<<dim3(Tt / 64, Hh / 64), blk, 0, stream>>>(hcb, cqwT, cqb, nullptr,
        cQ16, nullptr, nullptr, nullptr, Tt, Hh, 1024);
    gemm64<2><<<dim3(Bb * Ll / 64, 2048 / 64), blk, 0, stream>>>(encb, ckvwT, ckvb, nullptr,
        cK16, cV16, nullptr, nullptr, Bb * Ll, 2048, Cc);
    vtrans16<<<dim3(8, 2, 32), blk, 0, stream>>>(cV16, cVt16, 256);
    // 10. MFMA cross-attention (kv 256; no piggy-back blocks)
    fattn_m<<<dim3(16, 32), blk, 0, stream>>>(cQ16, cK16, cVt16, abb, 256,
        ew1, ew2, ew1T, ew2T);
    // 11+12. cross output projection fused with residual: out += ca@cow+cob (in place)
    gemm64<5><<<dim3(Tt / 64, Hh / 64), blk, 0, stream>>>(abb, cowT, cob, out,
        nullptr, nullptr, out, nullptr, Tt, Hh, 1024);
    // 13. h2 = ln(x2)*(1+sc2)+sh2 -> fp32 + bf16
    ln_affine<3><<<dim3(Tt), blk, 0, stream>>>(out, hbuf, h2b, mod + 4 * Hh, mod + 3 * Hh, 6 * Hh, 1.0f);
    // 14. gate + fused prep (count/scan/scatter/aux)
    gate_kernel<<<dim3(Tt / 4), blk, 0, stream>>>(hbuf, gatew, probs, topi, topw);
    moe_prep<<<dim3(1), dim3(1024), 0, stream>>>(probs, topi, topw, cntbuf, offp, gtok, gwt,
        gpos, out + (size_t)Tt * Hh);
    // 16+17. gathered MoE (64x64 tiles, high-occupancy); fc2 stores y; combine folds residual
    gemm_moe1<<<dim3(PADROWS / 64, Dd / 64), blk, 0, stream>>>(h2b, ew1T, eb1, actg, cntbuf, offp, gtok);
    gemm_moe2<<<dim3(PADROWS / 64, Hh / 64), blk, 0, stream>>>(actg, ew2T, eb2, ybuf, cntbuf, offp);
    moe_combine<<<dim3(Tt), blk, 0, stream>>>(ybuf, gpos, gwt, mod + 5 * Hh, out);
}

// Round 23
// 390.931 us; speedup vs baseline: 1.0881x; 1.0881x over previous
//
#include <hip/hip_runtime.h>
#include <math.h>

// Shapes (compile-time constants from the reference)
#define Hh 1024
#define Ss 1024
#define Bb 2
#define NHh 16
#define HDd 64
#define Tt 2048   // B*S
#define Ll 256
#define Cc 2048
#define Ee 8
#define Dd 2048
#define EPSf 1e-5f
#define PADROWS 5120

using bf16x8 = __attribute__((ext_vector_type(8))) short;
using f32x4  = __attribute__((ext_vector_type(4))) float;
using ushort8 = __attribute__((ext_vector_type(8))) unsigned short;

__device__ __forceinline__ float geluf(float x) {
    return 0.5f * x * (1.0f + erff(x * 0.70710678118654752f));
}

__device__ __forceinline__ unsigned short f2bf(float x) {
    union { float f; unsigned int u; } c; c.f = x;
    unsigned int r = (c.u + 0x7fffu + ((c.u >> 16) & 1u)) >> 16;
    return (unsigned short)r;
}

__device__ __forceinline__ void gload16(const void* g, void* l) {
    __builtin_amdgcn_global_load_lds(
        (const __attribute__((address_space(1))) void*)g,
        (__attribute__((address_space(3))) void*)l, 16, 0, 0);
}

// ---------------- 128x64 transpose-cast tile, 256-thread variant ----------------
__device__ __forceinline__ void tcast_tile(const float* __restrict__ src,
        unsigned short* __restrict__ dst, int R, int C, int lt,
        unsigned short* __restrict__ tb, int tid) {
    int gx = R >> 7;
    int rt = lt % gx, ct = lt / gx;
    int r0 = rt * 128, c0 = ct * 64;
    int lr = tid >> 4;               // 0..15
    int lc4 = (tid & 15) << 2;       // 0..60
    #pragma unroll
    for (int p = 0; p < 8; ++p) {
        int row = lr + 16 * p;       // 0..127
        float4 v = *(const float4*)&src[(size_t)(r0 + row) * C + c0 + lc4];
        ushort4 h; h.x = f2bf(v.x); h.y = f2bf(v.y); h.z = f2bf(v.z); h.w = f2bf(v.w);
        *(ushort4*)&tb[row * 70 + lc4] = h;
    }
    __syncthreads();
    int wr = tid >> 5;               // 0..7
    int wc4 = (tid & 31) << 2;       // 0..124
    #pragma unroll
    for (int p = 0; p < 8; ++p) {
        int orow = wr + 8 * p;       // 0..63
        ushort4 o;
        o.x = tb[(wc4 + 0) * 70 + orow];
        o.y = tb[(wc4 + 1) * 70 + orow];
        o.z = tb[(wc4 + 2) * 70 + orow];
        o.w = tb[(wc4 + 3) * 70 + orow];
        *(ushort4*)&dst[(size_t)(c0 + orow) * R + r0 + wc4] = o;
    }
}

// ---------------- 128x64 transpose-cast tile, 512-thread variant ----------------
__device__ __forceinline__ void tcast_tile512(const float* __restrict__ src,
        unsigned short* __restrict__ dst, int R, int C, int lt,
        unsigned short* __restrict__ tb, int tid) {
    int gx = R >> 7;
    int rt = lt % gx, ct = lt / gx;
    int r0 = rt * 128, c0 = ct * 64;
    int lr = tid >> 4;               // 0..31
    int lc4 = (tid & 15) << 2;       // 0..60
    #pragma unroll
    for (int p = 0; p < 4; ++p) {
        int row = lr + 32 * p;       // 0..127
        float4 v = *(const float4*)&src[(size_t)(r0 + row) * C + c0 + lc4];
        ushort4 h; h.x = f2bf(v.x); h.y = f2bf(v.y); h.z = f2bf(v.z); h.w = f2bf(v.w);
        *(ushort4*)&tb[row * 70 + lc4] = h;
    }
    __syncthreads();
    int wr = tid >> 5;               // 0..15
    int wc4 = (tid & 31) << 2;       // 0..124
    #pragma unroll
    for (int p = 0; p < 4; ++p) {
        int orow = wr + 16 * p;      // 0..63
        ushort4 o;
        o.x = tb[(wc4 + 0) * 70 + orow];
        o.y = tb[(wc4 + 1) * 70 + orow];
        o.z = tb[(wc4 + 2) * 70 + orow];
        o.w = tb[(wc4 + 3) * 70 + orow];
        *(ushort4*)&dst[(size_t)(c0 + orow) * R + r0 + wc4] = o;
    }
}

// ---------------- minimal upfront prep: q/k/v weight transposes + bias concat ----------------
// [0,384): qw/kw/vw tiles (128 each). [384,404): biascat.
__global__ __launch_bounds__(256) void prep_all(
        const float* __restrict__ qw, const float* __restrict__ kw, const float* __restrict__ vw,
        const float* __restrict__ qb, const float* __restrict__ kb, const float* __restrict__ vb,
        const float* __restrict__ ckb, const float* __restrict__ cvb,
        unsigned short* __restrict__ qkvwT, float* __restrict__ qkvb, float* __restrict__ ckvb) {
    __shared__ unsigned short tb[128 * 70];
    int bid = blockIdx.x;
    int tid = threadIdx.x;
    if (bid < 384) {
        int seg = bid >> 7;
        int lt = bid & 127;
        const float* src = (seg == 0) ? qw : (seg == 1 ? kw : vw);
        unsigned short* dst = qkvwT + (size_t)seg * 1024 * 1024;
        tcast_tile(src, dst, 1024, 1024, lt, tb, tid);
        return;
    }
    int i = (bid - 384) * 256 + tid;      // 5120
    if (i < 1024) qkvb[i] = qb[i];
    else if (i < 2048) qkvb[i] = kb[i - 1024];
    else if (i < 3072) qkvb[i] = vb[i - 2048];
    else if (i < 4096) ckvb[i - 3072] = ckb[i - 3072];
    else if (i < 5120) ckvb[i - 3072] = cvb[i - 4096];
}

// ---------------- bf16 [bh][S][64] -> bf16 [bh][64][S] transpose (for V) ----------------
__global__ __launch_bounds__(256) void vtrans16(const unsigned short* __restrict__ in,
        unsigned short* __restrict__ out, int S) {
    __shared__ unsigned short sm[32][36];
    int bh = blockIdx.z;
    int s0 = blockIdx.x * 32, d0 = blockIdx.y * 32;
    int lr = threadIdx.x >> 3, lc = (threadIdx.x & 7) << 2;
    ushort4 v = *(const ushort4*)&in[((size_t)bh * S + s0 + lr) * 64 + d0 + lc];
    sm[lr][lc] = v.x; sm[lr][lc + 1] = v.y; sm[lr][lc + 2] = v.z; sm[lr][lc + 3] = v.w;
    __syncthreads();
    ushort4 o;
    o.x = sm[lc + 0][lr]; o.y = sm[lc + 1][lr]; o.z = sm[lc + 2][lr]; o.w = sm[lc + 3][lr];
    *(ushort4*)&out[((size_t)bh * 64 + d0 + lr) * S + s0 + lc] = o;
}

// ---------------- AdaLN modulation ----------------
__global__ __launch_bounds__(256) void adaln_kernel(const float* __restrict__ cond,
        const float* __restrict__ w, const float* __restrict__ b, float* __restrict__ mod) {
    __shared__ float ss[Hh];
    int bi = (blockIdx.x * 256) / (6 * Hh);
    const float* cp = cond + (size_t)bi * Hh;
    for (int i = threadIdx.x; i < Hh; i += 256) {
        float c = cp[i];
        ss[i] = c / (1.0f + expf(-c));
    }
    __syncthreads();
    int idx = blockIdx.x * 256 + threadIdx.x;
    int j = idx % (6 * Hh);
    float acc = b[j];
    for (int i = 0; i < Hh; ++i) acc += ss[i] * w[(size_t)i * (6 * Hh) + j];
    mod[idx] = acc;
}

// ---------------- LayerNorm + affine. OM bit0: fp32 out, bit1: bf16 out ----------------
template<int OM>
__global__ __launch_bounds__(256) void ln_affine(const float* __restrict__ X, float* __restrict__ O32,
        unsigned short* __restrict__ O16,
        const float* __restrict__ scale, const float* __restrict__ shift, int bstride, float add1) {
    int t = blockIdx.x;
    int tid = threadIdx.x;
    const float* xr = X + (size_t)t * Hh;
    float4 xv = *(const float4*)&xr[tid * 4];
    float s = xv.x + xv.y + xv.z + xv.w;
    float q = xv.x * xv.x + xv.y * xv.y + xv.z * xv.z + xv.w * xv.w;
    #pragma unroll
    for (int off = 32; off > 0; off >>= 1) {
        s += __shfl_down(s, off);
        q += __shfl_down(q, off);
    }
    __shared__ float rsum[4], rsq[4];
    __shared__ float smean, srstd;
    int wv = tid >> 6, ln = tid & 63;
    if (ln == 0) { rsum[wv] = s; rsq[wv] = q; }
    __syncthreads();
    if (tid == 0) {
        float ts = rsum[0] + rsum[1] + rsum[2] + rsum[3];
        float tq = rsq[0] + rsq[1] + rsq[2] + rsq[3];
        float mean = ts * (1.0f / Hh);
        float var = tq * (1.0f / Hh) - mean * mean;
        smean = mean; srstd = rsqrtf(var + EPSf);
    }
    __syncthreads();
    float mean = smean, rstd = srstd;
    int bi = t >> 10;
    int j = tid * 4;
    const float* scp = scale + (size_t)bi * bstride;
    const float* shp = shift + (size_t)bi * bstride;
    float4 sc4 = *(const float4*)&scp[j];
    float4 sh4 = *(const float4*)&shp[j];
    float4 o;
    o.x = (xv.x - mean) * rstd * (add1 + sc4.x) + sh4.x;
    o.y = (xv.y - mean) * rstd * (add1 + sc4.y) + sh4.y;
    o.z = (xv.z - mean) * rstd * (add1 + sc4.z) + sh4.z;
    o.w = (xv.w - mean) * rstd * (add1 + sc4.w) + sh4.w;
    if (OM & 1) *(float4*)&O32[(size_t)t * Hh + j] = o;
    if (OM & 2) {
        ushort4 h; h.x = f2bf(o.x); h.y = f2bf(o.y); h.z = f2bf(o.z); h.w = f2bf(o.w);
        *(ushort4*)&O16[(size_t)t * Hh + j] = h;
    }
}

// ---------------- 512-thread qkv GEMM + piggy-backed remaining weight prep ----------------
// Grid (16, 24+88): y<24 = GEMM blocks (M tile = x*128, N tile = y*128).
// y>=24: tile t = x + 16*(y-24) in [0,1408):
//   [0,128) ow  [128,256) cqw  [256,384) cow   (1024x1024)
//   [384,640) ckw -> ckvwT     [640,896) cvw -> ckvwT+2M   (2048x1024)
//   [896,1408): enc vcast (512 float4/block)
__global__ __launch_bounds__(512) void gemm_qkv(const unsigned short* __restrict__ A,
        const unsigned short* __restrict__ Bt, const float* __restrict__ bias,
        unsigned short* __restrict__ P0, unsigned short* __restrict__ P1,
        unsigned short* __restrict__ P2, const float* __restrict__ rc, const float* __restrict__ rsn,
        const float* __restrict__ ow, const float* __restrict__ cqw, const float* __restrict__ cow,
        const float* __restrict__ ckw, const float* __restrict__ cvw, const float* __restrict__ enc,
        unsigned short* __restrict__ owT, unsigned short* __restrict__ cqwT,
        unsigned short* __restrict__ cowT, unsigned short* __restrict__ ckvwT,
        unsigned short* __restrict__ encb, int K) {
    __shared__ unsigned short sh[2 * 128 * 32 * 2];   // 32KB: GEMM As/Bs or prep tile (17.9KB)
    int tid = threadIdx.x;
    if (blockIdx.y >= 24) {
        int t = blockIdx.x + 16 * (blockIdx.y - 24);
        if (t < 384) {
            int seg = t >> 7, lt = t & 127;
            const float* src = (seg == 0) ? ow : (seg == 1 ? cqw : cow);
            unsigned short* dst = (seg == 0) ? owT : (seg == 1 ? cqwT : cowT);
            tcast_tile512(src, dst, 1024, 1024, lt, sh, tid);
        } else if (t < 896) {
            int t2 = t - 384;
            const float* src = (t2 < 256) ? ckw : cvw;
            unsigned short* dst = (t2 < 256) ? ckvwT : (ckvwT + (size_t)1024 * 2048);
            tcast_tile512(src, dst, 2048, 1024, t2 & 255, sh, tid);
        } else {
            int i = (t - 896) * 512 + tid;
            float4 v = ((const float4*)enc)[i];
            ushort4 o; o.x = f2bf(v.x); o.y = f2bf(v.y); o.z = f2bf(v.z); o.w = f2bf(v.w);
            ((ushort4*)encb)[i] = o;
        }
        return;
    }
    unsigned short* As0 = sh;
    unsigned short* Bs0 = sh + 2 * 128 * 32;
    int m0 = blockIdx.x * 128, n0 = blockIdx.y * 128;
    int lane = tid & 63;
    int wv = tid >> 6;
    int wm = (wv >> 1) * 32, wn = (wv & 1) * 64;
    f32x4 acc[2][4] = {};
    int r0 = tid >> 2, q8 = (tid & 3) * 8;
    const unsigned short* gA = A + (size_t)(m0 + r0) * K + q8;
    const unsigned short* gB = Bt + (size_t)(n0 + r0) * K + q8;
    int ra = (lane & 15) * 32 + (lane >> 4) * 8;
    auto stage = [&](int kk, int bufi) {
        gload16(gA + kk, &As0[bufi * 128 * 32 + tid * 8]);
        gload16(gB + kk, &Bs0[bufi * 128 * 32 + tid * 8]);
    };
    int nsteps = K / 32;
    stage(0, 0);
    int cur = 0;
    for (int s = 0; s < nsteps; ++s) {
        if (s + 1 < nsteps) {
            stage((s + 1) * 32, cur ^ 1);
            asm volatile("s_waitcnt vmcnt(2)" ::: "memory");
        } else {
            asm volatile("s_waitcnt vmcnt(0)" ::: "memory");
        }
        __builtin_amdgcn_s_barrier();
        bf16x8 af[2], bf[4];
        #pragma unroll
        for (int f = 0; f < 2; ++f) af[f] = *(const bf16x8*)&As0[cur * 128 * 32 + (wm + f * 16) * 32 + ra];
        #pragma unroll
        for (int f = 0; f < 4; ++f) bf[f] = *(const bf16x8*)&Bs0[cur * 128 * 32 + (wn + f * 16) * 32 + ra];
        #pragma unroll
        for (int i = 0; i < 2; ++i)
            #pragma unroll
            for (int j = 0; j < 4; ++j)
                acc[i][j] = __builtin_amdgcn_mfma_f32_16x16x32_bf16(af[i], bf[j], acc[i][j], 0, 0, 0);
        asm volatile("s_waitcnt lgkmcnt(0)" ::: "memory");
        __builtin_amdgcn_s_barrier();
        cur ^= 1;
    }
    int colb = n0 + wn + (lane & 15);
    int rowb = m0 + wm + (lane >> 4) * 4;
    float bv[4];
    #pragma unroll
    for (int j = 0; j < 4; ++j) bv[j] = bias[colb + j * 16];
    int nh = (colb >> 6) & 15;
    int type = colb >> 10;
    float qs = (type == 0) ? 0.125f : 1.0f;   // fold 1/sqrt(HD) into Q
    #pragma unroll
    for (int i = 0; i < 2; ++i) {
        #pragma unroll
        for (int r = 0; r < 4; ++r) {
            int row = rowb + i * 16 + r;
            int b = row >> 10, s = row & 1023;
            unsigned short* dst = (type == 0) ? P0 : (type == 1 ? P1 : P2);
            size_t obase = ((size_t)((b * 16 + nh) * 1024 + s)) * 64;
            if (type < 2) {
                #pragma unroll
                for (int j = 0; j < 2; ++j) {
                    int hd = j * 16 + (lane & 15);
                    float v0 = acc[i][j][r] + bv[j];
                    float v2 = acc[i][j + 2][r] + bv[j + 2];
                    float c1 = rc[s * 64 + hd], s1 = rsn[s * 64 + hd];
                    float c2 = rc[s * 64 + hd + 32], s2 = rsn[s * 64 + hd + 32];
                    dst[obase + hd] = f2bf((v0 * c1 - v2 * s1) * qs);
                    dst[obase + hd + 32] = f2bf((v2 * c2 + v0 * s2) * qs);
                }
            } else {
                #pragma unroll
                for (int j = 0; j < 4; ++j)
                    dst[obase + j * 16 + (lane & 15)] = f2bf(acc[i][j][r] + bv[j]);
            }
        }
    }
}

// ===== 64x64-tile GEMM: 256 threads, 4 waves (2x2) of 32x32, 2-buffer =====
// EP 0: fp32 store. EP 2: ckv pack (rows/batch=256, P0=cK, P1=cV).
// EP 3: cQ pack *0.125 (rows/batch=1024 -> P0). EP 4: Cf=baseb+gate*(acc+bias).
// EP 5: Cf=baseb+(acc+bias) (baseb may alias Cf).
template<int EP>
__global__ __launch_bounds__(256) void gemm64(const unsigned short* __restrict__ A,
        const unsigned short* __restrict__ Bt, const float* __restrict__ bias,
        float* __restrict__ Cf, unsigned short* __restrict__ P0, unsigned short* __restrict__ P1,
        const float* __restrict__ baseb, const float* __restrict__ gatep,
        int M, int N, int K) {
    __shared__ unsigned short As[2][64 * 32];
    __shared__ unsigned short Bs[2][64 * 32];
    int m0 = blockIdx.x * 64, n0 = blockIdx.y * 64;
    int tid = threadIdx.x;
    int lane = tid & 63;
    int wv = tid >> 6;                        // 0..3
    int wm = (wv >> 1) * 32, wn = (wv & 1) * 32;
    f32x4 acc[2][2] = {};
    int r0 = tid >> 2, q8 = (tid & 3) * 8;    // r0 in [0,64)
    const unsigned short* gA = A + (size_t)(m0 + r0) * K + q8;
    const unsigned short* gB = Bt + (size_t)(n0 + r0) * K + q8;
    int ra = (lane & 15) * 32 + (lane >> 4) * 8;
    auto stage = [&](int kk, int bufi) {
        gload16(gA + kk, &As[bufi][tid * 8]);
        gload16(gB + kk, &Bs[bufi][tid * 8]);
    };
    int nsteps = K / 32;
    stage(0, 0);
    int cur = 0;
    for (int s = 0; s < nsteps; ++s) {
        if (s + 1 < nsteps) {
            stage((s + 1) * 32, cur ^ 1);
            asm volatile("s_waitcnt vmcnt(2)" ::: "memory");
        } else {
            asm volatile("s_waitcnt vmcnt(0)" ::: "memory");
        }
        __builtin_amdgcn_s_barrier();
        bf16x8 af[2], bf[2];
        #pragma unroll
        for (int f = 0; f < 2; ++f) {
            af[f] = *(const bf16x8*)&As[cur][(wm + f * 16) * 32 + ra];
            bf[f] = *(const bf16x8*)&Bs[cur][(wn + f * 16) * 32 + ra];
        }
        #pragma unroll
        for (int i = 0; i < 2; ++i)
            #pragma unroll
            for (int j = 0; j < 2; ++j)
                acc[i][j] = __builtin_amdgcn_mfma_f32_16x16x32_bf16(af[i], bf[j], acc[i][j], 0, 0, 0);
        asm volatile("s_waitcnt lgkmcnt(0)" ::: "memory");
        __builtin_amdgcn_s_barrier();
        cur ^= 1;
    }
    // D layout: col = lane&15, row = (lane>>4)*4 + reg
    int colb = n0 + wn + (lane & 15);
    int rowb = m0 + wm + (lane >> 4) * 4;
    float bv[2];
    #pragma unroll
    for (int j = 0; j < 2; ++j) bv[j] = bias[colb + j * 16];
    if (EP == 0 || EP == 4 || EP == 5) {
        #pragma unroll
        for (int j = 0; j < 2; ++j) {
            int col = colb + j * 16;
            #pragma unroll
            for (int i = 0; i < 2; ++i)
                #pragma unroll
                for (int r = 0; r < 4; ++r) {
                    int row = rowb + i * 16 + r;
                    size_t gi = (size_t)row * N + col;
                    float v = acc[i][j][r] + bv[j];
                    if (EP == 0) {
                        Cf[gi] = v;
                    } else if (EP == 4) {
                        float g = gatep[(row >> 10) * (6 * Hh) + col];
                        Cf[gi] = baseb[gi] + g * v;
                    } else {
                        Cf[gi] = baseb[gi] + v;
                    }
                }
        }
        return;
    }
    int nh = (colb >> 6) & 15;
    int type = colb >> 10;
    int hd0 = colb & 63;
    #pragma unroll
    for (int i = 0; i < 2; ++i) {
        #pragma unroll
        for (int r = 0; r < 4; ++r) {
            int row = rowb + i * 16 + r;
            if (EP == 2) {
                int b = row >> 8, s = row & 255;
                unsigned short* dst = (type == 0) ? P0 : P1;
                size_t obase = ((size_t)((b * 16 + nh) * 256 + s)) * 64;
                #pragma unroll
                for (int j = 0; j < 2; ++j)
                    dst[obase + hd0 + j * 16] = f2bf(acc[i][j][r] + bv[j]);
            } else {  // EP == 3: cQ pack, pre-scaled by 1/sqrt(HD)
                int b = row >> 10, s = row & 1023;
                size_t obase = ((size_t)((b * 16 + nh) * 1024 + s)) * 64;
                #pragma unroll
                for (int j = 0; j < 2; ++j)
                    P0[obase + hd0 + j * 16] = f2bf((acc[i][j][r] + bv[j]) * 0.125f);
            }
        }
    }
}

// ---------------- gathered MoE fc1 (512-thread / 8-wave, 128x128, 2-buf) ----------------
__global__ __launch_bounds__(512) void gemm_moe1(const unsigned short* __restrict__ A,
        const unsigned short* __restrict__ W, const float* __restrict__ bias,
        unsigned short* __restrict__ Og, const int* __restrict__ cnt,
        const int* __restrict__ offp, const int* __restrict__ gtok) {
    __shared__ unsigned short As[2][128 * 32];
    __shared__ unsigned short Bs[2][128 * 32];
    int m0 = blockIdx.x * 128;
    if (m0 >= offp[Ee]) return;
    int e = 0;
    while (offp[e + 1] <= m0) ++e;
    int base = offp[e], valid = cnt[e];
    int n0 = blockIdx.y * 128;
    int tid = threadIdx.x;
    int lane = tid & 63;
    int wv = tid >> 6;
    int wm = (wv >> 1) * 32, wn = (wv & 1) * 64;
    f32x4 acc[2][4] = {};
    int r0 = tid >> 2, q8 = (tid & 3) * 8;
    int lr0 = m0 - base + r0;
    int tok0 = gtok[base + (lr0 < valid ? lr0 : 0)];
    const unsigned short* gA = A + (size_t)tok0 * Hh + q8;
    const unsigned short* Wt = W + (size_t)e * Dd * Hh;
    const unsigned short* gB = Wt + (size_t)(n0 + r0) * Hh + q8;
    int ra = (lane & 15) * 32 + (lane >> 4) * 8;
    auto stage = [&](int kk, int bufi) {
        gload16(gA + kk, &As[bufi][tid * 8]);
        gload16(gB + kk, &Bs[bufi][tid * 8]);
    };
    int nsteps = Hh / 32;
    stage(0, 0);
    int cur = 0;
    for (int s = 0; s < nsteps; ++s) {
        if (s + 1 < nsteps) {
            stage((s + 1) * 32, cur ^ 1);
            asm volatile("s_waitcnt vmcnt(2)" ::: "memory");
        } else {
            asm volatile("s_waitcnt vmcnt(0)" ::: "memory");
        }
        __builtin_amdgcn_s_barrier();
        bf16x8 af[2], bf[4];
        #pragma unroll
        for (int f = 0; f < 2; ++f) af[f] = *(const bf16x8*)&As[cur][(wm + f * 16) * 32 + ra];
        #pragma unroll
        for (int f = 0; f < 4; ++f) bf[f] = *(const bf16x8*)&Bs[cur][(wn + f * 16) * 32 + ra];
        #pragma unroll
        for (int i = 0; i < 2; ++i)
            #pragma unroll
            for (int j = 0; j < 4; ++j)
                acc[i][j] = __builtin_amdgcn_mfma_f32_16x16x32_bf16(af[i], bf[j], acc[i][j], 0, 0, 0);
        asm volatile("s_waitcnt lgkmcnt(0)" ::: "memory");
        __builtin_amdgcn_s_barrier();
        cur ^= 1;
    }
    int colb = n0 + wn + (lane & 15);
    int rowtb = wm + (lane >> 4) * 4;
    const float* bp = bias + (size_t)e * Dd;
    #pragma unroll
    for (int j = 0; j < 4; ++j) {
        int col = colb + j * 16;
        float bv = bp[col];
        #pragma unroll
        for (int i = 0; i < 2; ++i) {
            #pragma unroll
            for (int r = 0; r < 4; ++r) {
                int rt = rowtb + i * 16 + r;
                if (m0 - base + rt < valid)
                    Og[(size_t)(m0 + rt) * Dd + col] = f2bf(geluf(acc[i][j][r] + bv));
            }
        }
    }
}

// ---------------- gathered MoE fc2 (512-thread, 128x128, split-K=2): stores y[z][g][col] ----------------
// blockIdx.z selects K half; bias folded into z==0 slab; moe_combine sums slabs.
__global__ __launch_bounds__(512) void gemm_moe2(const unsigned short* __restrict__ A,
        const unsigned short* __restrict__ W, const float* __restrict__ bias,
        float* __restrict__ y, const int* __restrict__ cnt,
        const int* __restrict__ offp) {
    __shared__ unsigned short As[2][128 * 32];
    __shared__ unsigned short Bs[2][128 * 32];
    int m0 = blockIdx.x * 128;
    if (m0 >= offp[Ee]) return;
    int e = 0;
    while (offp[e + 1] <= m0) ++e;
    int base = offp[e], valid = cnt[e];
    int n0 = blockIdx.y * 128;
    int kz = blockIdx.z;                      // 0 or 1: K half
    int k0 = kz * (Dd / 2);
    int tid = threadIdx.x;
    int lane = tid & 63;
    int wv = tid >> 6;
    int wm = (wv >> 1) * 32, wn = (wv & 1) * 64;
    f32x4 acc[2][4] = {};
    int r0 = tid >> 2, q8 = (tid & 3) * 8;
    const unsigned short* gA = A + (size_t)(m0 + r0) * Dd + k0 + q8;
    const unsigned short* Wt = W + (size_t)e * Hh * Dd;
    const unsigned short* gB = Wt + (size_t)(n0 + r0) * Dd + k0 + q8;
    int ra = (lane & 15) * 32 + (lane >> 4) * 8;
    auto stage = [&](int kk, int bufi) {
        gload16(gA + kk, &As[bufi][tid * 8]);
        gload16(gB + kk, &Bs[bufi][tid * 8]);
    };
    int nsteps = (Dd / 2) / 32;
    stage(0, 0);
    int cur = 0;
    for (int s = 0; s < nsteps; ++s) {
        if (s + 1 < nsteps) {
            stage((s + 1) * 32, cur ^ 1);
            asm volatile("s_waitcnt vmcnt(2)" ::: "memory");
        } else {
            asm volatile("s_waitcnt vmcnt(0)" ::: "memory");
        }
        __builtin_amdgcn_s_barrier();
        bf16x8 af[2], bf[4];
        #pragma unroll
        for (int f = 0; f < 2; ++f) af[f] = *(const bf16x8*)&As[cur][(wm + f * 16) * 32 + ra];
        #pragma unroll
        for (int f = 0; f < 4; ++f) bf[f] = *(const bf16x8*)&Bs[cur][(wn + f * 16) * 32 + ra];
        #pragma unroll
        for (int i = 0; i < 2; ++i)
            #pragma unroll
            for (int j = 0; j < 4; ++j)
                acc[i][j] = __builtin_amdgcn_mfma_f32_16x16x32_bf16(af[i], bf[j], acc[i][j], 0, 0, 0);
        asm volatile("s_waitcnt lgkmcnt(0)" ::: "memory");
        __builtin_amdgcn_s_barrier();
        cur ^= 1;
    }
    int colb = n0 + wn + (lane & 15);
    int rowtb = wm + (lane >> 4) * 4;
    const float* bp = bias + (size_t)e * Hh;
    float* yz = y + (size_t)kz * PADROWS * Hh;
    #pragma unroll
    for (int j = 0; j < 4; ++j) {
        int col = colb + j * 16;
        float bv = (kz == 0) ? bp[col] : 0.0f;
        #pragma unroll
        for (int i = 0; i < 2; ++i) {
            #pragma unroll
            for (int r = 0; r < 4; ++r) {
                int rt = rowtb + i * 16 + r;
                int g = m0 + rt;
                if (g - base < valid)
                    yz[(size_t)g * Hh + col] = acc[i][j][r] + bv;
            }
        }
    }
}

// ---------------- MoE combine: out[t] += g2 .* (w0*(y0+y1)[g0] + w1*(y0+y1)[g1]) ----------------
__global__ __launch_bounds__(256) void moe_combine(const float* __restrict__ y,
        const int* __restrict__ gpos, const float* __restrict__ gwt,
        const float* __restrict__ gate2, float* __restrict__ outp) {
    int t = blockIdx.x;
    int j = threadIdx.x * 4;
    int g0 = gpos[2 * t], g1 = gpos[2 * t + 1];
    float w0 = gwt[g0], w1 = gwt[g1];
    const float* g2p = gate2 + (size_t)(t >> 10) * (6 * Hh);
    const size_t soff = (size_t)PADROWS * Hh;
    float4 a0 = *(const float4*)&y[(size_t)g0 * Hh + j];
    float4 a1 = *(const float4*)&y[soff + (size_t)g0 * Hh + j];
    float4 b0 = *(const float4*)&y[(size_t)g1 * Hh + j];
    float4 b1 = *(const float4*)&y[soff + (size_t)g1 * Hh + j];
    float4 g2 = *(const float4*)&g2p[j];
    float4 o = *(const float4*)&outp[(size_t)t * Hh + j];
    o.x += g2.x * (w0 * (a0.x + a1.x) + w1 * (b0.x + b1.x));
    o.y += g2.y * (w0 * (a0.y + a1.y) + w1 * (b0.y + b1.y));
    o.z += g2.z * (w0 * (a0.z + a1.z) + w1 * (b0.z + b1.z));
    o.w += g2.w * (w0 * (a0.w + a1.w) + w1 * (b0.w + b1.w));
    *(float4*)&outp[(size_t)t * Hh + j] = o;
}

// ---------------- MFMA flash attention + piggy-backed MoE weight transposes ----------------
__global__ __launch_bounds__(256) void fattn_m(const unsigned short* __restrict__ Qp,
        const unsigned short* __restrict__ Kp, const unsigned short* __restrict__ Vtp,
        unsigned short* __restrict__ O, int Skv,
        const float* __restrict__ ew1, const float* __restrict__ ew2,
        unsigned short* __restrict__ ew1T, unsigned short* __restrict__ ew2T) {
    __shared__ unsigned short shbuf[4 * 64 * 72];   // 36,864B; prep tile needs 8,960 shorts
    int tid = threadIdx.x;
    if (blockIdx.y >= 32) {
        int tile = blockIdx.x + 16 * (blockIdx.y - 32);   // 0..4095
        if (tile < 2048) {
            int e = tile >> 8, lt = tile & 255;           // ew1[e]: 1024x2048, 8x32 tiles
            tcast_tile(ew1 + (size_t)e * 1024 * 2048, ew1T + (size_t)e * 2048 * 1024,
                       1024, 2048, lt, shbuf, tid);
        } else {
            int t2 = tile - 2048;
            int e = t2 >> 8, lt = t2 & 255;               // ew2[e]: 2048x1024, 16x16 tiles
            tcast_tile(ew2 + (size_t)e * 2048 * 1024, ew2T + (size_t)e * 1024 * 2048,
                       2048, 1024, lt, shbuf, tid);
        }
        return;
    }
    unsigned short* Qs  = shbuf;
    unsigned short* Ks  = shbuf + 64 * 72;
    unsigned short* Vts = shbuf + 2 * 64 * 72;
    unsigned short* Ps  = shbuf + 3 * 64 * 72;
    int q0 = blockIdx.x * 64;
    int bh = blockIdx.y;
    int b = bh >> 4, nh = bh & 15;
    int lane = tid & 63, w = tid >> 6;
    int sr = tid >> 2, sp = (tid & 3) * 16;   // staging: row, 16-elem chunk
    {
        const unsigned short* src = &Qp[((size_t)bh * 1024 + q0 + sr) * 64 + sp];
        *(ushort8*)&Qs[sr * 72 + sp] = *(const ushort8*)&src[0];
        *(ushort8*)&Qs[sr * 72 + sp + 8] = *(const ushort8*)&src[8];
    }
    f32x4 acc[4] = {};
    float m_old[4], l_run[4];
    #pragma unroll
    for (int r = 0; r < 4; ++r) { m_old[r] = -1e30f; l_run[r] = 0.0f; }
    int wrow = w * 16;
    int k8 = (lane >> 4) * 8;
    ushort8 pkA, pkB, pvA, pvB;
    {
        const unsigned short* ksrc = &Kp[((size_t)bh * Skv + sr) * 64 + sp];
        pkA = *(const ushort8*)&ksrc[0];
        pkB = *(const ushort8*)&ksrc[8];
        const unsigned short* vsrc = &Vtp[((size_t)bh * 64 + sr) * Skv + sp];
        pvA = *(const ushort8*)&vsrc[0];
        pvB = *(const ushort8*)&vsrc[8];
    }
    for (int k0 = 0; k0 < Skv; k0 += 64) {
        asm volatile("s_waitcnt lgkmcnt(0)" ::: "memory");
        __builtin_amdgcn_s_barrier();                  // Ks/Vts free (prev PV reads done)
        *(ushort8*)&Ks[sr * 72 + sp] = pkA;
        *(ushort8*)&Ks[sr * 72 + sp + 8] = pkB;
        *(ushort8*)&Vts[sr * 72 + sp] = pvA;
        *(ushort8*)&Vts[sr * 72 + sp + 8] = pvB;
        if (k0 + 64 < Skv) {
            const unsigned short* ksrc = &Kp[((size_t)bh * Skv + k0 + 64 + sr) * 64 + sp];
            pkA = *(const ushort8*)&ksrc[0];
            pkB = *(const ushort8*)&ksrc[8];
            const unsigned short* vsrc = &Vtp[((size_t)bh * 64 + sr) * Skv + k0 + 64 + sp];
            pvA = *(const ushort8*)&vsrc[0];
            pvB = *(const ushort8*)&vsrc[8];
        }
        asm volatile("s_waitcnt lgkmcnt(0)" ::: "memory");
        __builtin_amdgcn_s_barrier();                  // staging (and iter-0 Qs) visible
        bf16x8 aq0 = *(const bf16x8*)&Qs[(wrow + (lane & 15)) * 72 + k8];
        bf16x8 aq1 = *(const bf16x8*)&Qs[(wrow + (lane & 15)) * 72 + 32 + k8];
        f32x4 sf[4];
        __builtin_amdgcn_s_setprio(1);
        #pragma unroll
        for (int j = 0; j < 4; ++j) {
            bf16x8 bk0 = *(const bf16x8*)&Ks[(j * 16 + (lane & 15)) * 72 + k8];
            bf16x8 bk1 = *(const bf16x8*)&Ks[(j * 16 + (lane & 15)) * 72 + 32 + k8];
            f32x4 z = {};
            z = __builtin_amdgcn_mfma_f32_16x16x32_bf16(aq0, bk0, z, 0, 0, 0);
            z = __builtin_amdgcn_mfma_f32_16x16x32_bf16(aq1, bk1, z, 0, 0, 0);
            sf[j] = z;
        }
        __builtin_amdgcn_s_setprio(0);
        float p[4][4];
        float fsc[4];
        #pragma unroll
        for (int r = 0; r < 4; ++r) {
            float mx = fmaxf(fmaxf(sf[0][r], sf[1][r]), fmaxf(sf[2][r], sf[3][r]));
            #pragma unroll
            for (int mk = 1; mk < 16; mk <<= 1) mx = fmaxf(mx, __shfl_xor(mx, mk));
            float mn = fmaxf(m_old[r], mx);
            float f = __expf(m_old[r] - mn);
            float rs = 0.0f;
            #pragma unroll
            for (int j = 0; j < 4; ++j) {
                p[j][r] = __expf(sf[j][r] - mn);
                rs += p[j][r];
            }
            #pragma unroll
            for (int mk = 1; mk < 16; mk <<= 1) rs += __shfl_xor(rs, mk);
            l_run[r] = l_run[r] * f + rs;
            m_old[r] = mn;
            fsc[r] = f;
        }
        #pragma unroll
        for (int jd = 0; jd < 4; ++jd)
            #pragma unroll
            for (int r = 0; r < 4; ++r) acc[jd][r] *= fsc[r];
        #pragma unroll
        for (int j = 0; j < 4; ++j)
            #pragma unroll
            for (int r = 0; r < 4; ++r)
                Ps[(wrow + (lane >> 4) * 4 + r) * 72 + j * 16 + (lane & 15)] = f2bf(p[j][r]);
        asm volatile("s_waitcnt lgkmcnt(0)" ::: "memory");
        __builtin_amdgcn_s_barrier();                  // Ps visible
        bf16x8 ap0 = *(const bf16x8*)&Ps[(wrow + (lane & 15)) * 72 + k8];
        bf16x8 ap1 = *(const bf16x8*)&Ps[(wrow + (lane & 15)) * 72 + 32 + k8];
        __builtin_amdgcn_s_setprio(1);
        #pragma unroll
        for (int jd = 0; jd < 4; ++jd) {
            bf16x8 bv0 = *(const bf16x8*)&Vts[(jd * 16 + (lane & 15)) * 72 + k8];
            bf16x8 bv1 = *(const bf16x8*)&Vts[(jd * 16 + (lane & 15)) * 72 + 32 + k8];
            acc[jd] = __builtin_amdgcn_mfma_f32_16x16x32_bf16(ap0, bv0, acc[jd], 0, 0, 0);
            acc[jd] = __builtin_amdgcn_mfma_f32_16x16x32_bf16(ap1, bv1, acc[jd], 0, 0, 0);
        }
        __builtin_amdgcn_s_setprio(0);
    }
    float inv[4];
    #pragma unroll
    for (int r = 0; r < 4; ++r) inv[r] = 1.0f / l_run[r];
    #pragma unroll
    for (int jd = 0; jd < 4; ++jd)
        #pragma unroll
        for (int r = 0; r < 4; ++r)
            O[((size_t)(b * Ss + q0 + wrow + (lane >> 4) * 4 + r)) * Hh + nh * 64 + jd * 16 + (lane & 15)]
                = f2bf(acc[jd][r] * inv[r]);
}

// ---------------- MoE gate: one wave per token, coalesced ----------------
__global__ __launch_bounds__(256) void gate_kernel(const float* __restrict__ h,
        const float* __restrict__ gw, float* __restrict__ probs, int* __restrict__ topi,
        float* __restrict__ topw) {
    int t = blockIdx.x * 4 + (threadIdx.x >> 6);
    int lane = threadIdx.x & 63;
    const float* hp = h + (size_t)t * Hh;
    float lg[Ee] = {};
    #pragma unroll
    for (int s = 0; s < 4; ++s) {
        int d0 = s * 256 + lane * 4;
        float4 hv = *(const float4*)&hp[d0];
        float hv4[4] = {hv.x, hv.y, hv.z, hv.w};
        #pragma unroll
        for (int c = 0; c < 4; ++c) {
            float hx = hv4[c];
            const float* g0 = &gw[(size_t)(d0 + c) * Ee];
            #pragma unroll
            for (int e = 0; e < Ee; ++e) lg[e] += hx * g0[e];
        }
    }
    #pragma unroll
    for (int e = 0; e < Ee; ++e)
        #pragma unroll
        for (int mk = 1; mk < 64; mk <<= 1) lg[e] += __shfl_xor(lg[e], mk);
    if (lane == 0) {
        float m = lg[0];
        #pragma unroll
        for (int e = 1; e < Ee; ++e) m = fmaxf(m, lg[e]);
        float ssum = 0;
        #pragma unroll
        for (int e = 0; e < Ee; ++e) { lg[e] = expf(lg[e] - m); ssum += lg[e]; }
        float inv = 1.0f / ssum;
        #pragma unroll
        for (int e = 0; e < Ee; ++e) { lg[e] *= inv; probs[t * Ee + e] = lg[e]; }
        int i0 = 0;
        #pragma unroll
        for (int e = 1; e < Ee; ++e) if (lg[e] > lg[i0]) i0 = e;
        int i1 = (i0 == 0) ? 1 : 0;
        #pragma unroll
        for (int e = 0; e < Ee; ++e) if (e != i1 && e != i0 && lg[e] > lg[i1]) i1 = e;
        float w0 = lg[i0], w1 = lg[i1];
        float inv2 = 1.0f / (w0 + w1);
        topi[t * 2] = i0; topi[t * 2 + 1] = i1;
        topw[t * 2] = w0 * inv2; topw[t * 2 + 1] = w1 * inv2;
    }
}

// ---------------- fused MoE prep: count + scan + scatter + aux (single 1024-thread block) ----------------
__global__ __launch_bounds__(1024) void moe_prep(const float* __restrict__ probs,
        const int* __restrict__ topi, const float* __restrict__ topw,
        int* __restrict__ cnt, int* __restrict__ offp,
        int* __restrict__ gtok, float* __restrict__ gwt, int* __restrict__ gpos,
        float* __restrict__ auxout) {
    __shared__ int scnt[Ee], spos[Ee], soff[Ee + 1];
    __shared__ float sS[Ee], sC[Ee];
    int tid = threadIdx.x;
    if (tid < Ee) { scnt[tid] = 0; spos[tid] = 0; sS[tid] = 0.0f; sC[tid] = 0.0f; }
    __syncthreads();
    float lp[Ee] = {};
    float lc[Ee] = {};
    for (int t = tid; t < Tt; t += 1024) {
        int a0 = topi[2 * t], a1 = topi[2 * t + 1];
        atomicAdd(&scnt[a0], 1);
        atomicAdd(&scnt[a1], 1);
        #pragma unroll
        for (int e = 0; e < Ee; ++e) lp[e] += probs[t * Ee + e];
        lc[a0] += 1.0f; lc[a1] += 1.0f;
    }
    #pragma unroll
    for (int e = 0; e < Ee; ++e) {
        atomicAdd(&sS[e], lp[e]);
        atomicAdd(&sC[e], lc[e]);
    }
    __syncthreads();
    if (tid == 0) {
        int acc = 0;
        for (int e = 0; e < Ee; ++e) { soff[e] = acc; acc += (scnt[e] + 127) & ~127; }
        soff[Ee] = acc;
        float aux = 0.0f;
        for (int e = 0; e < Ee; ++e) aux += sS[e] * sC[e];
        auxout[0] = aux * (8.0f / 4096.0f);   // E/(B*B*S)
    }
    if (tid < Ee) cnt[tid] = scnt[tid];
    __syncthreads();
    if (tid <= Ee) offp[tid] = soff[tid];
    for (int t = tid; t < Tt; t += 1024) {
        #pragma unroll
        for (int s = 0; s < 2; ++s) {
            int e = topi[2 * t + s];
            int pos = atomicAdd(&spos[e], 1);
            int g = soff[e] + pos;
            gtok[g] = t;
            gwt[g] = topw[2 * t + s];
            gpos[2 * t + s] = g;
        }
    }
}

extern "C" void kernel_launch(void* const* d_in, const int* in_sizes, int n_in,
                              void* d_out, int out_size, void* d_ws, size_t ws_size,
                              hipStream_t stream) {
    (void)in_sizes; (void)n_in; (void)out_size; (void)ws_size;
    const float* x    = (const float*)d_in[0];
    const float* cond = (const float*)d_in[1];
    const float* enc  = (const float*)d_in[2];
    const float* rc   = (const float*)d_in[3];
    const float* rsn  = (const float*)d_in[4];
    const float* adw  = (const float*)d_in[5];
    const float* adb  = (const float*)d_in[6];
    const float* qw  = (const float*)d_in[7];  const float* qb  = (const float*)d_in[8];
    const float* kw  = (const float*)d_in[9];  const float* kb2 = (const float*)d_in[10];
    const float* vw  = (const float*)d_in[11]; const float* vb  = (const float*)d_in[12];
    const float* ow  = (const float*)d_in[13]; const float* ob  = (const float*)d_in[14];
    const float* cqw = (const float*)d_in[15]; const float* cqb = (const float*)d_in[16];
    const float* ckw = (const float*)d_in[17]; const float* ckb = (const float*)d_in[18];
    const float* cvw = (const float*)d_in[19]; const float* cvb = (const float*)d_in[20];
    const float* cow = (const float*)d_in[21]; const float* cob = (const float*)d_in[22];
    const float* cng = (const float*)d_in[23]; const float* cnb = (const float*)d_in[24];
    const float* gatew = (const float*)d_in[25];
    const float* ew1 = (const float*)d_in[26]; const float* eb1 = (const float*)d_in[27];
    const float* ew2 = (const float*)d_in[28]; const float* eb2 = (const float*)d_in[29];
    float* out = (float*)d_out;

    char* ws = (char*)d_ws;
    size_t off = 0;
    auto alloc = [&](size_t bytes) {
        char* p = ws + off;
        off += (bytes + 255) & ~(size_t)255;
        return (void*)p;
    };
    // fp32 buffers
    float* hbuf   = (float*)alloc((size_t)Tt * Hh * 4);
    float* mod    = (float*)alloc((size_t)Bb * 6 * Hh * 4);
    float* probs  = (float*)alloc((size_t)Tt * Ee * 4);
    float* topw   = (float*)alloc((size_t)Tt * 2 * 4);
    int*   topi   = (int*)alloc((size_t)Tt * 2 * 4);
    float* qkvb   = (float*)alloc(3072 * 4);
    float* ckvb   = (float*)alloc(2048 * 4);
    int*   cntbuf = (int*)alloc(16 * 4);
    int*   offp   = (int*)alloc(16 * 4);
    int*   gtok   = (int*)alloc((size_t)PADROWS * 4);
    float* gwt    = (float*)alloc((size_t)PADROWS * 4);
    int*   gpos   = (int*)alloc((size_t)Tt * 2 * 4);
    // bf16 buffers
    typedef unsigned short u16;
    u16* h1b   = (u16*)alloc((size_t)Tt * Hh * 2);
    u16* hcb   = (u16*)alloc((size_t)Tt * Hh * 2);
    u16* h2b   = (u16*)alloc((size_t)Tt * Hh * 2);
    u16* abb   = (u16*)alloc((size_t)Tt * Hh * 2);
    u16* encb  = (u16*)alloc((size_t)Bb * Ll * Cc * 2);
    u16* actg  = (u16*)alloc((size_t)PADROWS * Dd * 2);
    // packed attention operands
    u16* Qb16  = (u16*)alloc((size_t)32 * 1024 * 64 * 2);
    u16* Kb16  = (u16*)alloc((size_t)32 * 1024 * 64 * 2);
    u16* Vb16  = (u16*)alloc((size_t)32 * 1024 * 64 * 2);
    u16* Vt16  = (u16*)alloc((size_t)32 * 64 * 1024 * 2);
    u16* cQ16  = (u16*)alloc((size_t)32 * 1024 * 64 * 2);
    u16* cK16  = (u16*)alloc((size_t)32 * 256 * 64 * 2);
    u16* cV16  = (u16*)alloc((size_t)32 * 256 * 64 * 2);
    u16* cVt16 = (u16*)alloc((size_t)32 * 64 * 256 * 2);
    // bf16 transposed weights [N][K]
    u16* qkvwT = (u16*)alloc((size_t)3072 * 1024 * 2);
    u16* owT   = (u16*)alloc((size_t)1024 * 1024 * 2);
    u16* cqwT  = (u16*)alloc((size_t)1024 * 1024 * 2);
    u16* ckvwT = (u16*)alloc((size_t)2048 * 2048 * 2);
    u16* cowT  = (u16*)alloc((size_t)1024 * 1024 * 2);
    u16* ew1T  = (u16*)alloc((size_t)Ee * Hh * Dd * 2);
    u16* ew2T  = (u16*)alloc((size_t)Ee * Dd * Hh * 2);
    // MoE fc2 split-K partials y[2][PADROWS][Hh] fp32 (41.9 MB), aliased over the
    // Qb16..ckvwT span (~43 MB, all dead after step 11). ew1T/ew2T untouched.
    float* ybuf = (float*)Qb16;

    dim3 blk(256);
    dim3 blk512(512);
    // --- minimal upfront prep: q/k/v transposes + biascat ---
    prep_all<<<dim3(404), blk, 0, stream>>>(qw, kw, vw, qb, kb2, vb, ckb, cvb,
        qkvwT, qkvb, ckvb);
    // 1. AdaLN modulation
    adaln_kernel<<<dim3(Bb * 6 * Hh / 256), blk, 0, stream>>>(cond, adw, adb, mod);
    // 2. h1 = ln(x)*(1+sc1)+sh1  -> bf16
    ln_affine<2><<<dim3(Tt), blk, 0, stream>>>(x, nullptr, h1b, mod + Hh, mod + 0, 6 * Hh, 1.0f);
    // 3. fused qkv projection + rope + pack (+1408 piggy-backed prep blocks)
    gemm_qkv<<<dim3(16, 24 + 88), blk512, 0, stream>>>(h1b, qkvwT, qkvb,
        Qb16, Kb16, Vb16, rc, rsn,
        ow, cqw, cow, ckw, cvw, enc, owT, cqwT, cowT, ckvwT, encb, 1024);
    // 4. V transpose [bh][64][1024]
    vtrans16<<<dim3(32, 2, 32), blk, 0, stream>>>(Vb16, Vt16, 1024);
    // 5. MFMA self-attention (+4096 piggy-backed ew1/ew2 transpose tiles)
    fattn_m<<<dim3(16, 32 + 256), blk, 0, stream>>>(Qb16, Kb16, Vt16, abb, 1024,
        ew1, ew2, ew1T, ew2T);
    // 6+7. output projection fused with residual: out = x + g1*(a@ow+ob)
    gemm64<4><<<dim3(Tt / 64, Hh / 64), blk, 0, stream>>>(abb, owT, ob, out,
        nullptr, nullptr, x, mod + 2 * Hh, Tt, Hh, 1024);
    // 8. hc = ln(x1)*cn_g + cn_b -> bf16
    ln_affine<2><<<dim3(Tt), blk, 0, stream>>>(out, nullptr, hcb, cng, cnb, 0, 0.0f);
    // 9. cross q (packed, pre-scaled) + fused ck/cv (packed)
    gemm64<3><<<dim3(Tt / 64, Hh / 64), blk, 0, stream>>>(hcb, cqwT, cqb, nullptr,
        cQ16, nullptr, nullptr, nullptr, Tt, Hh, 1024);
    gemm64<2><<<dim3(Bb * Ll / 64, 2048 / 64), blk, 0, stream>>>(encb, ckvwT, ckvb, nullptr,
        cK16, cV16, nullptr, nullptr, Bb * Ll, 2048, Cc);
    vtrans16<<<dim3(8, 2, 32), blk, 0, stream>>>(cV16, cVt16, 256);
    // 10. MFMA cross-attention (kv 256; no piggy-back blocks)
    fattn_m<<<dim3(16, 32), blk, 0, stream>>>(cQ16, cK16, cVt16, abb, 256,
        ew1, ew2, ew1T, ew2T);
    // 11+12. cross output projection fused with residual: out += ca@cow+cob (in place)
    gemm64<5><<<dim3(Tt / 64, Hh / 64), blk, 0, stream>>>(abb, cowT, cob, out,
        nullptr, nullptr, out, nullptr, Tt, Hh, 1024);
    // 13. h2 = ln(x2)*(1+sc2)+sh2 -> fp32 + bf16
    ln_affine<3><<<dim3(Tt), blk, 0, stream>>>(out, hbuf, h2b, mod + 4 * Hh, mod + 3 * Hh, 6 * Hh, 1.0f);
    // 14. gate + fused prep (count/scan/scatter/aux)
    gate_kernel<<<dim3(Tt / 4), blk, 0, stream>>>(hbuf, gatew, probs, topi, topw);
    moe_prep<<<dim3(1), dim3(1024), 0, stream>>>(probs, topi, topw, cntbuf, offp, gtok, gwt,
        gpos, out + (size_t)Tt * Hh);
    // 16+17. gathered MoE (128x128); fc2 split-K=2 -> y partials; combine folds residual
    gemm_moe1<<<dim3(PADROWS / 128, Dd / 128), blk512, 0, stream>>>(h2b, ew1T, eb1, actg, cntbuf, offp, gtok);
    gemm_moe2<<<dim3(PADROWS / 128, Hh / 128, 2), blk512, 0, stream>>>(actg, ew2T, eb2, ybuf, cntbuf, offp);
    moe_combine<<<dim3(Tt), blk, 0, stream>>>(ybuf, gpos, gwt, mod + 5 * Hh, out);
}

// Round 24
// 388.830 us; speedup vs baseline: 1.0940x; 1.0054x over previous
//
#include <hip/hip_runtime.h>
#include <math.h>

// Shapes (compile-time constants from the reference)
#define Hh 1024
#define Ss 1024
#define Bb 2
#define NHh 16
#define HDd 64
#define Tt 2048   // B*S
#define Ll 256
#define Cc 2048
#define Ee 8
#define Dd 2048
#define EPSf 1e-5f
#define PADROWS 5120
#define ESZ ((size_t)1024 * 2048)

using bf16x8 = __attribute__((ext_vector_type(8))) short;
using f32x4  = __attribute__((ext_vector_type(4))) float;
using ushort8 = __attribute__((ext_vector_type(8))) unsigned short;

__device__ __forceinline__ float geluf(float x) {
    return 0.5f * x * (1.0f + erff(x * 0.70710678118654752f));
}

__device__ __forceinline__ unsigned short f2bf(float x) {
    union { float f; unsigned int u; } c; c.f = x;
    unsigned int r = (c.u + 0x7fffu + ((c.u >> 16) & 1u)) >> 16;
    return (unsigned short)r;
}

__device__ __forceinline__ void gload16(const void* g, void* l) {
    __builtin_amdgcn_global_load_lds(
        (const __attribute__((address_space(1))) void*)g,
        (__attribute__((address_space(3))) void*)l, 16, 0, 0);
}

// ---------------- 128x64 transpose-cast tile, 256-thread variant ----------------
__device__ __forceinline__ void tcast_tile(const float* __restrict__ src,
        unsigned short* __restrict__ dst, int R, int C, int lt,
        unsigned short* __restrict__ tb, int tid) {
    int gx = R >> 7;
    int rt = lt % gx, ct = lt / gx;
    int r0 = rt * 128, c0 = ct * 64;
    int lr = tid >> 4;               // 0..15
    int lc4 = (tid & 15) << 2;       // 0..60
    #pragma unroll
    for (int p = 0; p < 8; ++p) {
        int row = lr + 16 * p;       // 0..127
        float4 v = *(const float4*)&src[(size_t)(r0 + row) * C + c0 + lc4];
        ushort4 h; h.x = f2bf(v.x); h.y = f2bf(v.y); h.z = f2bf(v.z); h.w = f2bf(v.w);
        *(ushort4*)&tb[row * 70 + lc4] = h;
    }
    __syncthreads();
    int wr = tid >> 5;               // 0..7
    int wc4 = (tid & 31) << 2;       // 0..124
    #pragma unroll
    for (int p = 0; p < 8; ++p) {
        int orow = wr + 8 * p;       // 0..63
        ushort4 o;
        o.x = tb[(wc4 + 0) * 70 + orow];
        o.y = tb[(wc4 + 1) * 70 + orow];
        o.z = tb[(wc4 + 2) * 70 + orow];
        o.w = tb[(wc4 + 3) * 70 + orow];
        *(ushort4*)&dst[(size_t)(c0 + orow) * R + r0 + wc4] = o;
    }
}

// ---------------- 128x64 transpose-cast tile, 512-thread variant ----------------
__device__ __forceinline__ void tcast_tile512(const float* __restrict__ src,
        unsigned short* __restrict__ dst, int R, int C, int lt,
        unsigned short* __restrict__ tb, int tid) {
    int gx = R >> 7;
    int rt = lt % gx, ct = lt / gx;
    int r0 = rt * 128, c0 = ct * 64;
    int lr = tid >> 4;               // 0..31
    int lc4 = (tid & 15) << 2;       // 0..60
    #pragma unroll
    for (int p = 0; p < 4; ++p) {
        int row = lr + 32 * p;       // 0..127
        float4 v = *(const float4*)&src[(size_t)(r0 + row) * C + c0 + lc4];
        ushort4 h; h.x = f2bf(v.x); h.y = f2bf(v.y); h.z = f2bf(v.z); h.w = f2bf(v.w);
        *(ushort4*)&tb[row * 70 + lc4] = h;
    }
    __syncthreads();
    int wr = tid >> 5;               // 0..15
    int wc4 = (tid & 31) << 2;       // 0..124
    #pragma unroll
    for (int p = 0; p < 4; ++p) {
        int orow = wr + 16 * p;      // 0..63
        ushort4 o;
        o.x = tb[(wc4 + 0) * 70 + orow];
        o.y = tb[(wc4 + 1) * 70 + orow];
        o.z = tb[(wc4 + 2) * 70 + orow];
        o.w = tb[(wc4 + 3) * 70 + orow];
        *(ushort4*)&dst[(size_t)(c0 + orow) * R + r0 + wc4] = o;
    }
}

// ---------------- minimal upfront prep: q/k/v weight transposes + bias concat ----------------
// [0,384): qw/kw/vw tiles (128 each). [384,404): biascat.
__global__ __launch_bounds__(256) void prep_all(
        const float* __restrict__ qw, const float* __restrict__ kw, const float* __restrict__ vw,
        const float* __restrict__ qb, const float* __restrict__ kb, const float* __restrict__ vb,
        const float* __restrict__ ckb, const float* __restrict__ cvb,
        unsigned short* __restrict__ qkvwT, float* __restrict__ qkvb, float* __restrict__ ckvb) {
    __shared__ unsigned short tb[128 * 70];
    int bid = blockIdx.x;
    int tid = threadIdx.x;
    if (bid < 384) {
        int seg = bid >> 7;
        int lt = bid & 127;
        const float* src = (seg == 0) ? qw : (seg == 1 ? kw : vw);
        unsigned short* dst = qkvwT + (size_t)seg * 1024 * 1024;
        tcast_tile(src, dst, 1024, 1024, lt, tb, tid);
        return;
    }
    int i = (bid - 384) * 256 + tid;      // 5120
    if (i < 1024) qkvb[i] = qb[i];
    else if (i < 2048) qkvb[i] = kb[i - 1024];
    else if (i < 3072) qkvb[i] = vb[i - 2048];
    else if (i < 4096) ckvb[i - 3072] = ckb[i - 3072];
    else if (i < 5120) ckvb[i - 3072] = cvb[i - 4096];
}

// ---------------- bf16 [bh][S][64] -> bf16 [bh][64][S] transpose (for V) ----------------
__global__ __launch_bounds__(256) void vtrans16(const unsigned short* __restrict__ in,
        unsigned short* __restrict__ out, int S) {
    __shared__ unsigned short sm[32][36];
    int bh = blockIdx.z;
    int s0 = blockIdx.x * 32, d0 = blockIdx.y * 32;
    int lr = threadIdx.x >> 3, lc = (threadIdx.x & 7) << 2;
    ushort4 v = *(const ushort4*)&in[((size_t)bh * S + s0 + lr) * 64 + d0 + lc];
    sm[lr][lc] = v.x; sm[lr][lc + 1] = v.y; sm[lr][lc + 2] = v.z; sm[lr][lc + 3] = v.w;
    __syncthreads();
    ushort4 o;
    o.x = sm[lc + 0][lr]; o.y = sm[lc + 1][lr]; o.z = sm[lc + 2][lr]; o.w = sm[lc + 3][lr];
    *(ushort4*)&out[((size_t)bh * 64 + d0 + lr) * S + s0 + lc] = o;
}

// ---------------- AdaLN modulation ----------------
__global__ __launch_bounds__(256) void adaln_kernel(const float* __restrict__ cond,
        const float* __restrict__ w, const float* __restrict__ b, float* __restrict__ mod) {
    __shared__ float ss[Hh];
    int bi = (blockIdx.x * 256) / (6 * Hh);
    const float* cp = cond + (size_t)bi * Hh;
    for (int i = threadIdx.x; i < Hh; i += 256) {
        float c = cp[i];
        ss[i] = c / (1.0f + expf(-c));
    }
    __syncthreads();
    int idx = blockIdx.x * 256 + threadIdx.x;
    int j = idx % (6 * Hh);
    float acc = b[j];
    for (int i = 0; i < Hh; ++i) acc += ss[i] * w[(size_t)i * (6 * Hh) + j];
    mod[idx] = acc;
}

// ---------------- LayerNorm + affine. OM bit0: fp32 out, bit1: bf16 out ----------------
template<int OM>
__global__ __launch_bounds__(256) void ln_affine(const float* __restrict__ X, float* __restrict__ O32,
        unsigned short* __restrict__ O16,
        const float* __restrict__ scale, const float* __restrict__ shift, int bstride, float add1) {
    int t = blockIdx.x;
    int tid = threadIdx.x;
    const float* xr = X + (size_t)t * Hh;
    float4 xv = *(const float4*)&xr[tid * 4];
    float s = xv.x + xv.y + xv.z + xv.w;
    float q = xv.x * xv.x + xv.y * xv.y + xv.z * xv.z + xv.w * xv.w;
    #pragma unroll
    for (int off = 32; off > 0; off >>= 1) {
        s += __shfl_down(s, off);
        q += __shfl_down(q, off);
    }
    __shared__ float rsum[4], rsq[4];
    __shared__ float smean, srstd;
    int wv = tid >> 6, ln = tid & 63;
    if (ln == 0) { rsum[wv] = s; rsq[wv] = q; }
    __syncthreads();
    if (tid == 0) {
        float ts = rsum[0] + rsum[1] + rsum[2] + rsum[3];
        float tq = rsq[0] + rsq[1] + rsq[2] + rsq[3];
        float mean = ts * (1.0f / Hh);
        float var = tq * (1.0f / Hh) - mean * mean;
        smean = mean; srstd = rsqrtf(var + EPSf);
    }
    __syncthreads();
    float mean = smean, rstd = srstd;
    int bi = t >> 10;
    int j = tid * 4;
    const float* scp = scale + (size_t)bi * bstride;
    const float* shp = shift + (size_t)bi * bstride;
    float4 sc4 = *(const float4*)&scp[j];
    float4 sh4 = *(const float4*)&shp[j];
    float4 o;
    o.x = (xv.x - mean) * rstd * (add1 + sc4.x) + sh4.x;
    o.y = (xv.y - mean) * rstd * (add1 + sc4.y) + sh4.y;
    o.z = (xv.z - mean) * rstd * (add1 + sc4.z) + sh4.z;
    o.w = (xv.w - mean) * rstd * (add1 + sc4.w) + sh4.w;
    if (OM & 1) *(float4*)&O32[(size_t)t * Hh + j] = o;
    if (OM & 2) {
        ushort4 h; h.x = f2bf(o.x); h.y = f2bf(o.y); h.z = f2bf(o.z); h.w = f2bf(o.w);
        *(ushort4*)&O16[(size_t)t * Hh + j] = h;
    }
}

// ---------------- 512-thread qkv GEMM + piggy-backed remaining weight prep ----------------
__global__ __launch_bounds__(512) void gemm_qkv(const unsigned short* __restrict__ A,
        const unsigned short* __restrict__ Bt, const float* __restrict__ bias,
        unsigned short* __restrict__ P0, unsigned short* __restrict__ P1,
        unsigned short* __restrict__ P2, const float* __restrict__ rc, const float* __restrict__ rsn,
        const float* __restrict__ ow, const float* __restrict__ cqw, const float* __restrict__ cow,
        const float* __restrict__ ckw, const float* __restrict__ cvw, const float* __restrict__ enc,
        unsigned short* __restrict__ owT, unsigned short* __restrict__ cqwT,
        unsigned short* __restrict__ cowT, unsigned short* __restrict__ ckvwT,
        unsigned short* __restrict__ encb, int K) {
    __shared__ unsigned short sh[2 * 128 * 32 * 2];   // 32KB: GEMM As/Bs or prep tile (17.9KB)
    int tid = threadIdx.x;
    if (blockIdx.y >= 24) {
        int t = blockIdx.x + 16 * (blockIdx.y - 24);
        if (t < 384) {
            int seg = t >> 7, lt = t & 127;
            const float* src = (seg == 0) ? ow : (seg == 1 ? cqw : cow);
            unsigned short* dst = (seg == 0) ? owT : (seg == 1 ? cqwT : cowT);
            tcast_tile512(src, dst, 1024, 1024, lt, sh, tid);
        } else if (t < 896) {
            int t2 = t - 384;
            const float* src = (t2 < 256) ? ckw : cvw;
            unsigned short* dst = (t2 < 256) ? ckvwT : (ckvwT + (size_t)1024 * 2048);
            tcast_tile512(src, dst, 2048, 1024, t2 & 255, sh, tid);
        } else {
            int i = (t - 896) * 512 + tid;
            float4 v = ((const float4*)enc)[i];
            ushort4 o; o.x = f2bf(v.x); o.y = f2bf(v.y); o.z = f2bf(v.z); o.w = f2bf(v.w);
            ((ushort4*)encb)[i] = o;
        }
        return;
    }
    unsigned short* As0 = sh;
    unsigned short* Bs0 = sh + 2 * 128 * 32;
    int m0 = blockIdx.x * 128, n0 = blockIdx.y * 128;
    int lane = tid & 63;
    int wv = tid >> 6;
    int wm = (wv >> 1) * 32, wn = (wv & 1) * 64;
    f32x4 acc[2][4] = {};
    int r0 = tid >> 2, q8 = (tid & 3) * 8;
    const unsigned short* gA = A + (size_t)(m0 + r0) * K + q8;
    const unsigned short* gB = Bt + (size_t)(n0 + r0) * K + q8;
    int ra = (lane & 15) * 32 + (lane >> 4) * 8;
    auto stage = [&](int kk, int bufi) {
        gload16(gA + kk, &As0[bufi * 128 * 32 + tid * 8]);
        gload16(gB + kk, &Bs0[bufi * 128 * 32 + tid * 8]);
    };
    int nsteps = K / 32;
    stage(0, 0);
    int cur = 0;
    for (int s = 0; s < nsteps; ++s) {
        if (s + 1 < nsteps) {
            stage((s + 1) * 32, cur ^ 1);
            asm volatile("s_waitcnt vmcnt(2)" ::: "memory");
        } else {
            asm volatile("s_waitcnt vmcnt(0)" ::: "memory");
        }
        __builtin_amdgcn_s_barrier();
        bf16x8 af[2], bf[4];
        #pragma unroll
        for (int f = 0; f < 2; ++f) af[f] = *(const bf16x8*)&As0[cur * 128 * 32 + (wm + f * 16) * 32 + ra];
        #pragma unroll
        for (int f = 0; f < 4; ++f) bf[f] = *(const bf16x8*)&Bs0[cur * 128 * 32 + (wn + f * 16) * 32 + ra];
        #pragma unroll
        for (int i = 0; i < 2; ++i)
            #pragma unroll
            for (int j = 0; j < 4; ++j)
                acc[i][j] = __builtin_amdgcn_mfma_f32_16x16x32_bf16(af[i], bf[j], acc[i][j], 0, 0, 0);
        asm volatile("s_waitcnt lgkmcnt(0)" ::: "memory");
        __builtin_amdgcn_s_barrier();
        cur ^= 1;
    }
    int colb = n0 + wn + (lane & 15);
    int rowb = m0 + wm + (lane >> 4) * 4;
    float bv[4];
    #pragma unroll
    for (int j = 0; j < 4; ++j) bv[j] = bias[colb + j * 16];
    int nh = (colb >> 6) & 15;
    int type = colb >> 10;
    float qs = (type == 0) ? 0.125f : 1.0f;   // fold 1/sqrt(HD) into Q
    #pragma unroll
    for (int i = 0; i < 2; ++i) {
        #pragma unroll
        for (int r = 0; r < 4; ++r) {
            int row = rowb + i * 16 + r;
            int b = row >> 10, s = row & 1023;
            unsigned short* dst = (type == 0) ? P0 : (type == 1 ? P1 : P2);
            size_t obase = ((size_t)((b * 16 + nh) * 1024 + s)) * 64;
            if (type < 2) {
                #pragma unroll
                for (int j = 0; j < 2; ++j) {
                    int hd = j * 16 + (lane & 15);
                    float v0 = acc[i][j][r] + bv[j];
                    float v2 = acc[i][j + 2][r] + bv[j + 2];
                    float c1 = rc[s * 64 + hd], s1 = rsn[s * 64 + hd];
                    float c2 = rc[s * 64 + hd + 32], s2 = rsn[s * 64 + hd + 32];
                    dst[obase + hd] = f2bf((v0 * c1 - v2 * s1) * qs);
                    dst[obase + hd + 32] = f2bf((v2 * c2 + v0 * s2) * qs);
                }
            } else {
                #pragma unroll
                for (int j = 0; j < 4; ++j)
                    dst[obase + j * 16 + (lane & 15)] = f2bf(acc[i][j][r] + bv[j]);
            }
        }
    }
}

// ===== 64x64-tile GEMM: 256 threads, 4 waves (2x2) of 32x32, 2-buffer =====
// EP 0: fp32 store. EP 2: ckv pack. EP 3: cQ pack *0.125. EP 4: Cf=baseb+gate*(acc+bias).
// EP 5: Cf=baseb+(acc+bias). Piggyback: blocks with y*64 >= N transpose one 128x64 tile
// of pw (4 experts' worth: tile t in [0,1024), e=t>>8) into pwT.
template<int EP>
__global__ __launch_bounds__(256) void gemm64(const unsigned short* __restrict__ A,
        const unsigned short* __restrict__ Bt, const float* __restrict__ bias,
        float* __restrict__ Cf, unsigned short* __restrict__ P0, unsigned short* __restrict__ P1,
        const float* __restrict__ baseb, const float* __restrict__ gatep,
        int M, int N, int K,
        const float* __restrict__ pw, unsigned short* __restrict__ pwT, int pR, int pC) {
    __shared__ unsigned short sh[8960];   // 17.9KB: GEMM As/Bs (8192 shorts) or prep tile
    int tid = threadIdx.x;
    if (pw != nullptr && (int)blockIdx.y * 64 >= N) {
        int t = blockIdx.x + gridDim.x * (blockIdx.y - (unsigned)(N / 64));
        int e = t >> 8, lt = t & 255;
        tcast_tile(pw + (size_t)e * ESZ, pwT + (size_t)e * ESZ, pR, pC, lt, sh, tid);
        return;
    }
    int m0 = blockIdx.x * 64, n0 = blockIdx.y * 64;
    int lane = tid & 63;
    int wv = tid >> 6;                        // 0..3
    int wm = (wv >> 1) * 32, wn = (wv & 1) * 32;
    f32x4 acc[2][2] = {};
    int r0 = tid >> 2, q8 = (tid & 3) * 8;    // r0 in [0,64)
    const unsigned short* gA = A + (size_t)(m0 + r0) * K + q8;
    const unsigned short* gB = Bt + (size_t)(n0 + r0) * K + q8;
    int ra = (lane & 15) * 32 + (lane >> 4) * 8;
    auto stage = [&](int kk, int bufi) {
        gload16(gA + kk, &sh[bufi * 2048 + tid * 8]);
        gload16(gB + kk, &sh[4096 + bufi * 2048 + tid * 8]);
    };
    int nsteps = K / 32;
    stage(0, 0);
    int cur = 0;
    for (int s = 0; s < nsteps; ++s) {
        if (s + 1 < nsteps) {
            stage((s + 1) * 32, cur ^ 1);
            asm volatile("s_waitcnt vmcnt(2)" ::: "memory");
        } else {
            asm volatile("s_waitcnt vmcnt(0)" ::: "memory");
        }
        __builtin_amdgcn_s_barrier();
        bf16x8 af[2], bf[2];
        #pragma unroll
        for (int f = 0; f < 2; ++f) {
            af[f] = *(const bf16x8*)&sh[cur * 2048 + (wm + f * 16) * 32 + ra];
            bf[f] = *(const bf16x8*)&sh[4096 + cur * 2048 + (wn + f * 16) * 32 + ra];
        }
        #pragma unroll
        for (int i = 0; i < 2; ++i)
            #pragma unroll
            for (int j = 0; j < 2; ++j)
                acc[i][j] = __builtin_amdgcn_mfma_f32_16x16x32_bf16(af[i], bf[j], acc[i][j], 0, 0, 0);
        asm volatile("s_waitcnt lgkmcnt(0)" ::: "memory");
        __builtin_amdgcn_s_barrier();
        cur ^= 1;
    }
    // D layout: col = lane&15, row = (lane>>4)*4 + reg
    int colb = n0 + wn + (lane & 15);
    int rowb = m0 + wm + (lane >> 4) * 4;
    float bv[2];
    #pragma unroll
    for (int j = 0; j < 2; ++j) bv[j] = bias[colb + j * 16];
    if (EP == 0 || EP == 4 || EP == 5) {
        #pragma unroll
        for (int j = 0; j < 2; ++j) {
            int col = colb + j * 16;
            #pragma unroll
            for (int i = 0; i < 2; ++i)
                #pragma unroll
                for (int r = 0; r < 4; ++r) {
                    int row = rowb + i * 16 + r;
                    size_t gi = (size_t)row * N + col;
                    float v = acc[i][j][r] + bv[j];
                    if (EP == 0) {
                        Cf[gi] = v;
                    } else if (EP == 4) {
                        float g = gatep[(row >> 10) * (6 * Hh) + col];
                        Cf[gi] = baseb[gi] + g * v;
                    } else {
                        Cf[gi] = baseb[gi] + v;
                    }
                }
        }
        return;
    }
    int nh = (colb >> 6) & 15;
    int type = colb >> 10;
    int hd0 = colb & 63;
    #pragma unroll
    for (int i = 0; i < 2; ++i) {
        #pragma unroll
        for (int r = 0; r < 4; ++r) {
            int row = rowb + i * 16 + r;
            if (EP == 2) {
                int b = row >> 8, s = row & 255;
                unsigned short* dst = (type == 0) ? P0 : P1;
                size_t obase = ((size_t)((b * 16 + nh) * 256 + s)) * 64;
                #pragma unroll
                for (int j = 0; j < 2; ++j)
                    dst[obase + hd0 + j * 16] = f2bf(acc[i][j][r] + bv[j]);
            } else {  // EP == 3: cQ pack, pre-scaled by 1/sqrt(HD)
                int b = row >> 10, s = row & 1023;
                size_t obase = ((size_t)((b * 16 + nh) * 1024 + s)) * 64;
                #pragma unroll
                for (int j = 0; j < 2; ++j)
                    P0[obase + hd0 + j * 16] = f2bf((acc[i][j][r] + bv[j]) * 0.125f);
            }
        }
    }
}

// ---------------- gathered MoE fc1 (512-thread / 8-wave, 128x128, 2-buf) ----------------
__global__ __launch_bounds__(512) void gemm_moe1(const unsigned short* __restrict__ A,
        const unsigned short* __restrict__ W, const float* __restrict__ bias,
        unsigned short* __restrict__ Og, const int* __restrict__ cnt,
        const int* __restrict__ offp, const int* __restrict__ gtok) {
    __shared__ unsigned short As[2][128 * 32];
    __shared__ unsigned short Bs[2][128 * 32];
    int m0 = blockIdx.x * 128;
    if (m0 >= offp[Ee]) return;
    int e = 0;
    while (offp[e + 1] <= m0) ++e;
    int base = offp[e], valid = cnt[e];
    int n0 = blockIdx.y * 128;
    int tid = threadIdx.x;
    int lane = tid & 63;
    int wv = tid >> 6;
    int wm = (wv >> 1) * 32, wn = (wv & 1) * 64;
    f32x4 acc[2][4] = {};
    int r0 = tid >> 2, q8 = (tid & 3) * 8;
    int lr0 = m0 - base + r0;
    int tok0 = gtok[base + (lr0 < valid ? lr0 : 0)];
    const unsigned short* gA = A + (size_t)tok0 * Hh + q8;
    const unsigned short* Wt = W + (size_t)e * Dd * Hh;
    const unsigned short* gB = Wt + (size_t)(n0 + r0) * Hh + q8;
    int ra = (lane & 15) * 32 + (lane >> 4) * 8;
    auto stage = [&](int kk, int bufi) {
        gload16(gA + kk, &As[bufi][tid * 8]);
        gload16(gB + kk, &Bs[bufi][tid * 8]);
    };
    int nsteps = Hh / 32;
    stage(0, 0);
    int cur = 0;
    for (int s = 0; s < nsteps; ++s) {
        if (s + 1 < nsteps) {
            stage((s + 1) * 32, cur ^ 1);
            asm volatile("s_waitcnt vmcnt(2)" ::: "memory");
        } else {
            asm volatile("s_waitcnt vmcnt(0)" ::: "memory");
        }
        __builtin_amdgcn_s_barrier();
        bf16x8 af[2], bf[4];
        #pragma unroll
        for (int f = 0; f < 2; ++f) af[f] = *(const bf16x8*)&As[cur][(wm + f * 16) * 32 + ra];
        #pragma unroll
        for (int f = 0; f < 4; ++f) bf[f] = *(const bf16x8*)&Bs[cur][(wn + f * 16) * 32 + ra];
        #pragma unroll
        for (int i = 0; i < 2; ++i)
            #pragma unroll
            for (int j = 0; j < 4; ++j)
                acc[i][j] = __builtin_amdgcn_mfma_f32_16x16x32_bf16(af[i], bf[j], acc[i][j], 0, 0, 0);
        asm volatile("s_waitcnt lgkmcnt(0)" ::: "memory");
        __builtin_amdgcn_s_barrier();
        cur ^= 1;
    }
    int colb = n0 + wn + (lane & 15);
    int rowtb = wm + (lane >> 4) * 4;
    const float* bp = bias + (size_t)e * Dd;
    #pragma unroll
    for (int j = 0; j < 4; ++j) {
        int col = colb + j * 16;
        float bv = bp[col];
        #pragma unroll
        for (int i = 0; i < 2; ++i) {
            #pragma unroll
            for (int r = 0; r < 4; ++r) {
                int rt = rowtb + i * 16 + r;
                if (m0 - base + rt < valid)
                    Og[(size_t)(m0 + rt) * Dd + col] = f2bf(geluf(acc[i][j][r] + bv));
            }
        }
    }
}

// ---------------- gathered MoE fc2 (512-thread, 128x128, split-K=2): stores y[z][g][col] ----------------
__global__ __launch_bounds__(512) void gemm_moe2(const unsigned short* __restrict__ A,
        const unsigned short* __restrict__ W, const float* __restrict__ bias,
        float* __restrict__ y, const int* __restrict__ cnt,
        const int* __restrict__ offp) {
    __shared__ unsigned short As[2][128 * 32];
    __shared__ unsigned short Bs[2][128 * 32];
    int m0 = blockIdx.x * 128;
    if (m0 >= offp[Ee]) return;
    int e = 0;
    while (offp[e + 1] <= m0) ++e;
    int base = offp[e], valid = cnt[e];
    int n0 = blockIdx.y * 128;
    int kz = blockIdx.z;                      // 0 or 1: K half
    int k0 = kz * (Dd / 2);
    int tid = threadIdx.x;
    int lane = tid & 63;
    int wv = tid >> 6;
    int wm = (wv >> 1) * 32, wn = (wv & 1) * 64;
    f32x4 acc[2][4] = {};
    int r0 = tid >> 2, q8 = (tid & 3) * 8;
    const unsigned short* gA = A + (size_t)(m0 + r0) * Dd + k0 + q8;
    const unsigned short* Wt = W + (size_t)e * Hh * Dd;
    const unsigned short* gB = Wt + (size_t)(n0 + r0) * Dd + k0 + q8;
    int ra = (lane & 15) * 32 + (lane >> 4) * 8;
    auto stage = [&](int kk, int bufi) {
        gload16(gA + kk, &As[bufi][tid * 8]);
        gload16(gB + kk, &Bs[bufi][tid * 8]);
    };
    int nsteps = (Dd / 2) / 32;
    stage(0, 0);
    int cur = 0;
    for (int s = 0; s < nsteps; ++s) {
        if (s + 1 < nsteps) {
            stage((s + 1) * 32, cur ^ 1);
            asm volatile("s_waitcnt vmcnt(2)" ::: "memory");
        } else {
            asm volatile("s_waitcnt vmcnt(0)" ::: "memory");
        }
        __builtin_amdgcn_s_barrier();
        bf16x8 af[2], bf[4];
        #pragma unroll
        for (int f = 0; f < 2; ++f) af[f] = *(const bf16x8*)&As[cur][(wm + f * 16) * 32 + ra];
        #pragma unroll
        for (int f = 0; f < 4; ++f) bf[f] = *(const bf16x8*)&Bs[cur][(wn + f * 16) * 32 + ra];
        #pragma unroll
        for (int i = 0; i < 2; ++i)
            #pragma unroll
            for (int j = 0; j < 4; ++j)
                acc[i][j] = __builtin_amdgcn_mfma_f32_16x16x32_bf16(af[i], bf[j], acc[i][j], 0, 0, 0);
        asm volatile("s_waitcnt lgkmcnt(0)" ::: "memory");
        __builtin_amdgcn_s_barrier();
        cur ^= 1;
    }
    int colb = n0 + wn + (lane & 15);
    int rowtb = wm + (lane >> 4) * 4;
    const float* bp = bias + (size_t)e * Hh;
    float* yz = y + (size_t)kz * PADROWS * Hh;
    #pragma unroll
    for (int j = 0; j < 4; ++j) {
        int col = colb + j * 16;
        float bv = (kz == 0) ? bp[col] : 0.0f;
        #pragma unroll
        for (int i = 0; i < 2; ++i) {
            #pragma unroll
            for (int r = 0; r < 4; ++r) {
                int rt = rowtb + i * 16 + r;
                int g = m0 + rt;
                if (g - base < valid)
                    yz[(size_t)g * Hh + col] = acc[i][j][r] + bv;
            }
        }
    }
}

// ---------------- MoE combine: out[t] += g2 .* (w0*(y0+y1)[g0] + w1*(y0+y1)[g1]) ----------------
__global__ __launch_bounds__(256) void moe_combine(const float* __restrict__ y,
        const int* __restrict__ gpos, const float* __restrict__ gwt,
        const float* __restrict__ gate2, float* __restrict__ outp) {
    int t = blockIdx.x;
    int j = threadIdx.x * 4;
    int g0 = gpos[2 * t], g1 = gpos[2 * t + 1];
    float w0 = gwt[g0], w1 = gwt[g1];
    const float* g2p = gate2 + (size_t)(t >> 10) * (6 * Hh);
    const size_t soff = (size_t)PADROWS * Hh;
    float4 a0 = *(const float4*)&y[(size_t)g0 * Hh + j];
    float4 a1 = *(const float4*)&y[soff + (size_t)g0 * Hh + j];
    float4 b0 = *(const float4*)&y[(size_t)g1 * Hh + j];
    float4 b1 = *(const float4*)&y[soff + (size_t)g1 * Hh + j];
    float4 g2 = *(const float4*)&g2p[j];
    float4 o = *(const float4*)&outp[(size_t)t * Hh + j];
    o.x += g2.x * (w0 * (a0.x + a1.x) + w1 * (b0.x + b1.x));
    o.y += g2.y * (w0 * (a0.y + a1.y) + w1 * (b0.y + b1.y));
    o.z += g2.z * (w0 * (a0.z + a1.z) + w1 * (b0.z + b1.z));
    o.w += g2.w * (w0 * (a0.w + a1.w) + w1 * (b0.w + b1.w));
    *(float4*)&outp[(size_t)t * Hh + j] = o;
}

// ---------------- MFMA flash attention + piggy-backed ew1 transposes (experts 0-3) --------
__global__ __launch_bounds__(256) void fattn_m(const unsigned short* __restrict__ Qp,
        const unsigned short* __restrict__ Kp, const unsigned short* __restrict__ Vtp,
        unsigned short* __restrict__ O, int Skv,
        const float* __restrict__ ew1, unsigned short* __restrict__ ew1T) {
    __shared__ unsigned short shbuf[4 * 64 * 72];   // 36,864B; prep tile needs 8,960 shorts
    int tid = threadIdx.x;
    if (blockIdx.y >= 32) {
        int tile = blockIdx.x + 16 * (blockIdx.y - 32);   // 0..1023 (ew1 experts 0-3)
        int e = tile >> 8, lt = tile & 255;
        tcast_tile(ew1 + (size_t)e * ESZ, ew1T + (size_t)e * ESZ, 1024, 2048, lt, shbuf, tid);
        return;
    }
    unsigned short* Qs  = shbuf;
    unsigned short* Ks  = shbuf + 64 * 72;
    unsigned short* Vts = shbuf + 2 * 64 * 72;
    unsigned short* Ps  = shbuf + 3 * 64 * 72;
    int q0 = blockIdx.x * 64;
    int bh = blockIdx.y;
    int b = bh >> 4, nh = bh & 15;
    int lane = tid & 63, w = tid >> 6;
    int sr = tid >> 2, sp = (tid & 3) * 16;   // staging: row, 16-elem chunk
    {
        const unsigned short* src = &Qp[((size_t)bh * 1024 + q0 + sr) * 64 + sp];
        *(ushort8*)&Qs[sr * 72 + sp] = *(const ushort8*)&src[0];
        *(ushort8*)&Qs[sr * 72 + sp + 8] = *(const ushort8*)&src[8];
    }
    f32x4 acc[4] = {};
    float m_old[4], l_run[4];
    #pragma unroll
    for (int r = 0; r < 4; ++r) { m_old[r] = -1e30f; l_run[r] = 0.0f; }
    int wrow = w * 16;
    int k8 = (lane >> 4) * 8;
    ushort8 pkA, pkB, pvA, pvB;
    {
        const unsigned short* ksrc = &Kp[((size_t)bh * Skv + sr) * 64 + sp];
        pkA = *(const ushort8*)&ksrc[0];
        pkB = *(const ushort8*)&ksrc[8];
        const unsigned short* vsrc = &Vtp[((size_t)bh * 64 + sr) * Skv + sp];
        pvA = *(const ushort8*)&vsrc[0];
        pvB = *(const ushort8*)&vsrc[8];
    }
    for (int k0 = 0; k0 < Skv; k0 += 64) {
        asm volatile("s_waitcnt lgkmcnt(0)" ::: "memory");
        __builtin_amdgcn_s_barrier();                  // Ks/Vts free (prev PV reads done)
        *(ushort8*)&Ks[sr * 72 + sp] = pkA;
        *(ushort8*)&Ks[sr * 72 + sp + 8] = pkB;
        *(ushort8*)&Vts[sr * 72 + sp] = pvA;
        *(ushort8*)&Vts[sr * 72 + sp + 8] = pvB;
        if (k0 + 64 < Skv) {
            const unsigned short* ksrc = &Kp[((size_t)bh * Skv + k0 + 64 + sr) * 64 + sp];
            pkA = *(const ushort8*)&ksrc[0];
            pkB = *(const ushort8*)&ksrc[8];
            const unsigned short* vsrc = &Vtp[((size_t)bh * 64 + sr) * Skv + k0 + 64 + sp];
            pvA = *(const ushort8*)&vsrc[0];
            pvB = *(const ushort8*)&vsrc[8];
        }
        asm volatile("s_waitcnt lgkmcnt(0)" ::: "memory");
        __builtin_amdgcn_s_barrier();                  // staging (and iter-0 Qs) visible
        bf16x8 aq0 = *(const bf16x8*)&Qs[(wrow + (lane & 15)) * 72 + k8];
        bf16x8 aq1 = *(const bf16x8*)&Qs[(wrow + (lane & 15)) * 72 + 32 + k8];
        f32x4 sf[4];
        __builtin_amdgcn_s_setprio(1);
        #pragma unroll
        for (int j = 0; j < 4; ++j) {
            bf16x8 bk0 = *(const bf16x8*)&Ks[(j * 16 + (lane & 15)) * 72 + k8];
            bf16x8 bk1 = *(const bf16x8*)&Ks[(j * 16 + (lane & 15)) * 72 + 32 + k8];
            f32x4 z = {};
            z = __builtin_amdgcn_mfma_f32_16x16x32_bf16(aq0, bk0, z, 0, 0, 0);
            z = __builtin_amdgcn_mfma_f32_16x16x32_bf16(aq1, bk1, z, 0, 0, 0);
            sf[j] = z;
        }
        __builtin_amdgcn_s_setprio(0);
        float p[4][4];
        float fsc[4];
        #pragma unroll
        for (int r = 0; r < 4; ++r) {
            float mx = fmaxf(fmaxf(sf[0][r], sf[1][r]), fmaxf(sf[2][r], sf[3][r]));
            #pragma unroll
            for (int mk = 1; mk < 16; mk <<= 1) mx = fmaxf(mx, __shfl_xor(mx, mk));
            float mn = fmaxf(m_old[r], mx);
            float f = __expf(m_old[r] - mn);
            float rs = 0.0f;
            #pragma unroll
            for (int j = 0; j < 4; ++j) {
                p[j][r] = __expf(sf[j][r] - mn);
                rs += p[j][r];
            }
            #pragma unroll
            for (int mk = 1; mk < 16; mk <<= 1) rs += __shfl_xor(rs, mk);
            l_run[r] = l_run[r] * f + rs;
            m_old[r] = mn;
            fsc[r] = f;
        }
        #pragma unroll
        for (int jd = 0; jd < 4; ++jd)
            #pragma unroll
            for (int r = 0; r < 4; ++r) acc[jd][r] *= fsc[r];
        #pragma unroll
        for (int j = 0; j < 4; ++j)
            #pragma unroll
            for (int r = 0; r < 4; ++r)
                Ps[(wrow + (lane >> 4) * 4 + r) * 72 + j * 16 + (lane & 15)] = f2bf(p[j][r]);
        asm volatile("s_waitcnt lgkmcnt(0)" ::: "memory");
        __builtin_amdgcn_s_barrier();                  // Ps visible
        bf16x8 ap0 = *(const bf16x8*)&Ps[(wrow + (lane & 15)) * 72 + k8];
        bf16x8 ap1 = *(const bf16x8*)&Ps[(wrow + (lane & 15)) * 72 + 32 + k8];
        __builtin_amdgcn_s_setprio(1);
        #pragma unroll
        for (int jd = 0; jd < 4; ++jd) {
            bf16x8 bv0 = *(const bf16x8*)&Vts[(jd * 16 + (lane & 15)) * 72 + k8];
            bf16x8 bv1 = *(const bf16x8*)&Vts[(jd * 16 + (lane & 15)) * 72 + 32 + k8];
            acc[jd] = __builtin_amdgcn_mfma_f32_16x16x32_bf16(ap0, bv0, acc[jd], 0, 0, 0);
            acc[jd] = __builtin_amdgcn_mfma_f32_16x16x32_bf16(ap1, bv1, acc[jd], 0, 0, 0);
        }
        __builtin_amdgcn_s_setprio(0);
    }
    float inv[4];
    #pragma unroll
    for (int r = 0; r < 4; ++r) inv[r] = 1.0f / l_run[r];
    #pragma unroll
    for (int jd = 0; jd < 4; ++jd)
        #pragma unroll
        for (int r = 0; r < 4; ++r)
            O[((size_t)(b * Ss + q0 + wrow + (lane >> 4) * 4 + r)) * Hh + nh * 64 + jd * 16 + (lane & 15)]
                = f2bf(acc[jd][r] * inv[r]);
}

// ---------------- MoE gate: one wave per token, coalesced ----------------
__global__ __launch_bounds__(256) void gate_kernel(const float* __restrict__ h,
        const float* __restrict__ gw, float* __restrict__ probs, int* __restrict__ topi,
        float* __restrict__ topw) {
    int t = blockIdx.x * 4 + (threadIdx.x >> 6);
    int lane = threadIdx.x & 63;
    const float* hp = h + (size_t)t * Hh;
    float lg[Ee] = {};
    #pragma unroll
    for (int s = 0; s < 4; ++s) {
        int d0 = s * 256 + lane * 4;
        float4 hv = *(const float4*)&hp[d0];
        float hv4[4] = {hv.x, hv.y, hv.z, hv.w};
        #pragma unroll
        for (int c = 0; c < 4; ++c) {
            float hx = hv4[c];
            const float* g0 = &gw[(size_t)(d0 + c) * Ee];
            #pragma unroll
            for (int e = 0; e < Ee; ++e) lg[e] += hx * g0[e];
        }
    }
    #pragma unroll
    for (int e = 0; e < Ee; ++e)
        #pragma unroll
        for (int mk = 1; mk < 64; mk <<= 1) lg[e] += __shfl_xor(lg[e], mk);
    if (lane == 0) {
        float m = lg[0];
        #pragma unroll
        for (int e = 1; e < Ee; ++e) m = fmaxf(m, lg[e]);
        float ssum = 0;
        #pragma unroll
        for (int e = 0; e < Ee; ++e) { lg[e] = expf(lg[e] - m); ssum += lg[e]; }
        float inv = 1.0f / ssum;
        #pragma unroll
        for (int e = 0; e < Ee; ++e) { lg[e] *= inv; probs[t * Ee + e] = lg[e]; }
        int i0 = 0;
        #pragma unroll
        for (int e = 1; e < Ee; ++e) if (lg[e] > lg[i0]) i0 = e;
        int i1 = (i0 == 0) ? 1 : 0;
        #pragma unroll
        for (int e = 0; e < Ee; ++e) if (e != i1 && e != i0 && lg[e] > lg[i1]) i1 = e;
        float w0 = lg[i0], w1 = lg[i1];
        float inv2 = 1.0f / (w0 + w1);
        topi[t * 2] = i0; topi[t * 2 + 1] = i1;
        topw[t * 2] = w0 * inv2; topw[t * 2 + 1] = w1 * inv2;
    }
}

// ---------------- fused MoE prep: count + scan + scatter + aux (single 1024-thread block) ----------------
__global__ __launch_bounds__(1024) void moe_prep(const float* __restrict__ probs,
        const int* __restrict__ topi, const float* __restrict__ topw,
        int* __restrict__ cnt, int* __restrict__ offp,
        int* __restrict__ gtok, float* __restrict__ gwt, int* __restrict__ gpos,
        float* __restrict__ auxout) {
    __shared__ int scnt[Ee], spos[Ee], soff[Ee + 1];
    __shared__ float sS[Ee], sC[Ee];
    int tid = threadIdx.x;
    if (tid < Ee) { scnt[tid] = 0; spos[tid] = 0; sS[tid] = 0.0f; sC[tid] = 0.0f; }
    __syncthreads();
    float lp[Ee] = {};
    float lc[Ee] = {};
    for (int t = tid; t < Tt; t += 1024) {
        int a0 = topi[2 * t], a1 = topi[2 * t + 1];
        atomicAdd(&scnt[a0], 1);
        atomicAdd(&scnt[a1], 1);
        #pragma unroll
        for (int e = 0; e < Ee; ++e) lp[e] += probs[t * Ee + e];
        lc[a0] += 1.0f; lc[a1] += 1.0f;
    }
    #pragma unroll
    for (int e = 0; e < Ee; ++e) {
        atomicAdd(&sS[e], lp[e]);
        atomicAdd(&sC[e], lc[e]);
    }
    __syncthreads();
    if (tid == 0) {
        int acc = 0;
        for (int e = 0; e < Ee; ++e) { soff[e] = acc; acc += (scnt[e] + 127) & ~127; }
        soff[Ee] = acc;
        float aux = 0.0f;
        for (int e = 0; e < Ee; ++e) aux += sS[e] * sC[e];
        auxout[0] = aux * (8.0f / 4096.0f);   // E/(B*B*S)
    }
    if (tid < Ee) cnt[tid] = scnt[tid];
    __syncthreads();
    if (tid <= Ee) offp[tid] = soff[tid];
    for (int t = tid; t < Tt; t += 1024) {
        #pragma unroll
        for (int s = 0; s < 2; ++s) {
            int e = topi[2 * t + s];
            int pos = atomicAdd(&spos[e], 1);
            int g = soff[e] + pos;
            gtok[g] = t;
            gwt[g] = topw[2 * t + s];
            gpos[2 * t + s] = g;
        }
    }
}

extern "C" void kernel_launch(void* const* d_in, const int* in_sizes, int n_in,
                              void* d_out, int out_size, void* d_ws, size_t ws_size,
                              hipStream_t stream) {
    (void)in_sizes; (void)n_in; (void)out_size; (void)ws_size;
    const float* x    = (const float*)d_in[0];
    const float* cond = (const float*)d_in[1];
    const float* enc  = (const float*)d_in[2];
    const float* rc   = (const float*)d_in[3];
    const float* rsn  = (const float*)d_in[4];
    const float* adw  = (const float*)d_in[5];
    const float* adb  = (const float*)d_in[6];
    const float* qw  = (const float*)d_in[7];  const float* qb  = (const float*)d_in[8];
    const float* kw  = (const float*)d_in[9];  const float* kb2 = (const float*)d_in[10];
    const float* vw  = (const float*)d_in[11]; const float* vb  = (const float*)d_in[12];
    const float* ow  = (const float*)d_in[13]; const float* ob  = (const float*)d_in[14];
    const float* cqw = (const float*)d_in[15]; const float* cqb = (const float*)d_in[16];
    const float* ckw = (const float*)d_in[17]; const float* ckb = (const float*)d_in[18];
    const float* cvw = (const float*)d_in[19]; const float* cvb = (const float*)d_in[20];
    const float* cow = (const float*)d_in[21]; const float* cob = (const float*)d_in[22];
    const float* cng = (const float*)d_in[23]; const float* cnb = (const float*)d_in[24];
    const float* gatew = (const float*)d_in[25];
    const float* ew1 = (const float*)d_in[26]; const float* eb1 = (const float*)d_in[27];
    const float* ew2 = (const float*)d_in[28]; const float* eb2 = (const float*)d_in[29];
    float* out = (float*)d_out;

    char* ws = (char*)d_ws;
    size_t off = 0;
    auto alloc = [&](size_t bytes) {
        char* p = ws + off;
        off += (bytes + 255) & ~(size_t)255;
        return (void*)p;
    };
    // fp32 buffers
    float* hbuf   = (float*)alloc((size_t)Tt * Hh * 4);
    float* mod    = (float*)alloc((size_t)Bb * 6 * Hh * 4);
    float* probs  = (float*)alloc((size_t)Tt * Ee * 4);
    float* topw   = (float*)alloc((size_t)Tt * 2 * 4);
    int*   topi   = (int*)alloc((size_t)Tt * 2 * 4);
    float* qkvb   = (float*)alloc(3072 * 4);
    float* ckvb   = (float*)alloc(2048 * 4);
    int*   cntbuf = (int*)alloc(16 * 4);
    int*   offp   = (int*)alloc(16 * 4);
    int*   gtok   = (int*)alloc((size_t)PADROWS * 4);
    float* gwt    = (float*)alloc((size_t)PADROWS * 4);
    int*   gpos   = (int*)alloc((size_t)Tt * 2 * 4);
    // bf16 buffers
    typedef unsigned short u16;
    u16* h1b   = (u16*)alloc((size_t)Tt * Hh * 2);
    u16* hcb   = (u16*)alloc((size_t)Tt * Hh * 2);
    u16* h2b   = (u16*)alloc((size_t)Tt * Hh * 2);
    u16* abb   = (u16*)alloc((size_t)Tt * Hh * 2);
    u16* encb  = (u16*)alloc((size_t)Bb * Ll * Cc * 2);
    u16* actg  = (u16*)alloc((size_t)PADROWS * Dd * 2);
    // packed attention operands
    u16* Qb16  = (u16*)alloc((size_t)32 * 1024 * 64 * 2);
    u16* Kb16  = (u16*)alloc((size_t)32 * 1024 * 64 * 2);
    u16* Vb16  = (u16*)alloc((size_t)32 * 1024 * 64 * 2);
    u16* Vt16  = (u16*)alloc((size_t)32 * 64 * 1024 * 2);
    u16* cQ16  = (u16*)alloc((size_t)32 * 1024 * 64 * 2);
    u16* cK16  = (u16*)alloc((size_t)32 * 256 * 64 * 2);
    u16* cV16  = (u16*)alloc((size_t)32 * 256 * 64 * 2);
    u16* cVt16 = (u16*)alloc((size_t)32 * 64 * 256 * 2);
    // bf16 transposed weights [N][K]
    u16* qkvwT = (u16*)alloc((size_t)3072 * 1024 * 2);
    u16* owT   = (u16*)alloc((size_t)1024 * 1024 * 2);
    u16* cqwT  = (u16*)alloc((size_t)1024 * 1024 * 2);
    u16* ckvwT = (u16*)alloc((size_t)2048 * 2048 * 2);
    u16* cowT  = (u16*)alloc((size_t)1024 * 1024 * 2);
    u16* ew1T  = (u16*)alloc((size_t)Ee * Hh * Dd * 2);
    u16* ew2T  = (u16*)alloc((size_t)Ee * Dd * Hh * 2);
    // MoE fc2 split-K partials y[2][PADROWS][Hh] fp32 (41.9 MB), aliased over the
    // Qb16..ckvwT span (~43 MB, all dead after step 11). ew1T/ew2T untouched.
    float* ybuf = (float*)Qb16;

    dim3 blk(256);
    dim3 blk512(512);
    // --- minimal upfront prep: q/k/v transposes + biascat ---
    prep_all<<<dim3(404), blk, 0, stream>>>(qw, kw, vw, qb, kb2, vb, ckb, cvb,
        qkvwT, qkvb, ckvb);
    // 1. AdaLN modulation
    adaln_kernel<<<dim3(Bb * 6 * Hh / 256), blk, 0, stream>>>(cond, adw, adb, mod);
    // 2. h1 = ln(x)*(1+sc1)+sh1  -> bf16
    ln_affine<2><<<dim3(Tt), blk, 0, stream>>>(x, nullptr, h1b, mod + Hh, mod + 0, 6 * Hh, 1.0f);
    // 3. fused qkv projection + rope + pack (+1408 piggy-backed prep blocks)
    gemm_qkv<<<dim3(16, 24 + 88), blk512, 0, stream>>>(h1b, qkvwT, qkvb,
        Qb16, Kb16, Vb16, rc, rsn,
        ow, cqw, cow, ckw, cvw, enc, owT, cqwT, cowT, ckvwT, encb, 1024);
    // 4. V transpose [bh][64][1024]
    vtrans16<<<dim3(32, 2, 32), blk, 0, stream>>>(Vb16, Vt16, 1024);
    // 5. MFMA self-attention (+1024 ew1 expert-0..3 transpose tiles)
    fattn_m<<<dim3(16, 32 + 64), blk, 0, stream>>>(Qb16, Kb16, Vt16, abb, 1024,
        ew1, ew1T);
    // 6+7. output projection fused with residual (+1024 ew1 expert-4..7 tiles)
    gemm64<4><<<dim3(Tt / 64, Hh / 64 + 32), blk, 0, stream>>>(abb, owT, ob, out,
        nullptr, nullptr, x, mod + 2 * Hh, Tt, Hh, 1024,
        ew1 + 4 * ESZ, ew1T + 4 * ESZ, 1024, 2048);
    // 8. hc = ln(x1)*cn_g + cn_b -> bf16
    ln_affine<2><<<dim3(Tt), blk, 0, stream>>>(out, nullptr, hcb, cng, cnb, 0, 0.0f);
    // 9. cross q (packed, pre-scaled) (+1024 ew2 expert-0..3 tiles) + fused ck/cv (packed)
    gemm64<3><<<dim3(Tt / 64, Hh / 64 + 32), blk, 0, stream>>>(hcb, cqwT, cqb, nullptr,
        cQ16, nullptr, nullptr, nullptr, Tt, Hh, 1024,
        ew2, ew2T, 2048, 1024);
    gemm64<2><<<dim3(Bb * Ll / 64, 2048 / 64), blk, 0, stream>>>(encb, ckvwT, ckvb, nullptr,
        cK16, cV16, nullptr, nullptr, Bb * Ll, 2048, Cc,
        nullptr, nullptr, 0, 0);
    vtrans16<<<dim3(8, 2, 32), blk, 0, stream>>>(cV16, cVt16, 256);
    // 10. MFMA cross-attention (kv 256; no piggy-back blocks)
    fattn_m<<<dim3(16, 32), blk, 0, stream>>>(cQ16, cK16, cVt16, abb, 256,
        ew1, ew1T);
    // 11+12. cross output projection fused with residual (+1024 ew2 expert-4..7 tiles)
    gemm64<5><<<dim3(Tt / 64, Hh / 64 + 32), blk, 0, stream>>>(abb, cowT, cob, out,
        nullptr, nullptr, out, nullptr, Tt, Hh, 1024,
        ew2 + 4 * ESZ, ew2T + 4 * ESZ, 2048, 1024);
    // 13. h2 = ln(x2)*(1+sc2)+sh2 -> fp32 + bf16
    ln_affine<3><<<dim3(Tt), blk, 0, stream>>>(out, hbuf, h2b, mod + 4 * Hh, mod + 3 * Hh, 6 * Hh, 1.0f);
    // 14. gate + fused prep (count/scan/scatter/aux)
    gate_kernel<<<dim3(Tt / 4), blk, 0, stream>>>(hbuf, gatew, probs, topi, topw);
    moe_prep<<<dim3(1), dim3(1024), 0, stream>>>(probs, topi, topw, cntbuf, offp, gtok, gwt,
        gpos, out + (size_t)Tt * Hh);
    // 16+17. gathered MoE (128x128); fc2 split-K=2 -> y partials; combine folds residual
    gemm_moe1<<<dim3(PADROWS / 128, Dd / 128), blk512, 0, stream>>>(h2b, ew1T, eb1, actg, cntbuf, offp, gtok);
    gemm_moe2<<<dim3(PADROWS / 128, Hh / 128, 2), blk512, 0, stream>>>(actg, ew2T, eb2, ybuf, cntbuf, offp);
    moe_combine<<<dim3(Tt), blk, 0, stream>>>(ybuf, gpos, gwt, mod + 5 * Hh, out);
}

// Round 25
// 348.525 us; speedup vs baseline: 1.2205x; 1.1156x over previous
//
#include <hip/hip_runtime.h>
#include <math.h>

// Shapes (compile-time constants from the reference)
#define Hh 1024
#define Ss 1024
#define Bb 2
#define NHh 16
#define HDd 64
#define Tt 2048   // B*S
#define Ll 256
#define Cc 2048
#define Ee 8
#define Dd 2048
#define EPSf 1e-5f
#define PADROWS 5120
#define ESZ ((size_t)1024 * 2048)

using bf16x8 = __attribute__((ext_vector_type(8))) short;
using f32x4  = __attribute__((ext_vector_type(4))) float;
using ushort8 = __attribute__((ext_vector_type(8))) unsigned short;

__device__ __forceinline__ float geluf(float x) {
    return 0.5f * x * (1.0f + erff(x * 0.70710678118654752f));
}

__device__ __forceinline__ unsigned short f2bf(float x) {
    union { float f; unsigned int u; } c; c.f = x;
    unsigned int r = (c.u + 0x7fffu + ((c.u >> 16) & 1u)) >> 16;
    return (unsigned short)r;
}

__device__ __forceinline__ void gload16(const void* g, void* l) {
    __builtin_amdgcn_global_load_lds(
        (const __attribute__((address_space(1))) void*)g,
        (__attribute__((address_space(3))) void*)l, 16, 0, 0);
}

// ---------------- 128x64 transpose-cast tile, 256-thread variant ----------------
__device__ __forceinline__ void tcast_tile(const float* __restrict__ src,
        unsigned short* __restrict__ dst, int R, int C, int lt,
        unsigned short* __restrict__ tb, int tid) {
    int gx = R >> 7;
    int rt = lt % gx, ct = lt / gx;
    int r0 = rt * 128, c0 = ct * 64;
    int lr = tid >> 4;               // 0..15
    int lc4 = (tid & 15) << 2;       // 0..60
    #pragma unroll
    for (int p = 0; p < 8; ++p) {
        int row = lr + 16 * p;       // 0..127
        float4 v = *(const float4*)&src[(size_t)(r0 + row) * C + c0 + lc4];
        ushort4 h; h.x = f2bf(v.x); h.y = f2bf(v.y); h.z = f2bf(v.z); h.w = f2bf(v.w);
        *(ushort4*)&tb[row * 70 + lc4] = h;
    }
    __syncthreads();
    int wr = tid >> 5;               // 0..7
    int wc4 = (tid & 31) << 2;       // 0..124
    #pragma unroll
    for (int p = 0; p < 8; ++p) {
        int orow = wr + 8 * p;       // 0..63
        ushort4 o;
        o.x = tb[(wc4 + 0) * 70 + orow];
        o.y = tb[(wc4 + 1) * 70 + orow];
        o.z = tb[(wc4 + 2) * 70 + orow];
        o.w = tb[(wc4 + 3) * 70 + orow];
        *(ushort4*)&dst[(size_t)(c0 + orow) * R + r0 + wc4] = o;
    }
}

// ---------------- 128x64 transpose-cast tile, 512-thread variant ----------------
__device__ __forceinline__ void tcast_tile512(const float* __restrict__ src,
        unsigned short* __restrict__ dst, int R, int C, int lt,
        unsigned short* __restrict__ tb, int tid) {
    int gx = R >> 7;
    int rt = lt % gx, ct = lt / gx;
    int r0 = rt * 128, c0 = ct * 64;
    int lr = tid >> 4;               // 0..31
    int lc4 = (tid & 15) << 2;       // 0..60
    #pragma unroll
    for (int p = 0; p < 4; ++p) {
        int row = lr + 32 * p;       // 0..127
        float4 v = *(const float4*)&src[(size_t)(r0 + row) * C + c0 + lc4];
        ushort4 h; h.x = f2bf(v.x); h.y = f2bf(v.y); h.z = f2bf(v.z); h.w = f2bf(v.w);
        *(ushort4*)&tb[row * 70 + lc4] = h;
    }
    __syncthreads();
    int wr = tid >> 5;               // 0..15
    int wc4 = (tid & 31) << 2;       // 0..124
    #pragma unroll
    for (int p = 0; p < 4; ++p) {
        int orow = wr + 16 * p;      // 0..63
        ushort4 o;
        o.x = tb[(wc4 + 0) * 70 + orow];
        o.y = tb[(wc4 + 1) * 70 + orow];
        o.z = tb[(wc4 + 2) * 70 + orow];
        o.w = tb[(wc4 + 3) * 70 + orow];
        *(ushort4*)&dst[(size_t)(c0 + orow) * R + r0 + wc4] = o;
    }
}

// ---------------- upfront prep: q/k/v weight transposes + bias concat + AdaLN matvec ----------
// [0,384): qw/kw/vw tiles (128 each). [384,404): biascat.
// [404,1172): AdaLN K-split matvec: t = bid-404; jc = t%24 (256 cols), u = t/24 in [0,32):
//   bi = u>>4, ks = u&15 (K slice of 64). atomicAdd partials into mod (pre-zeroed).
__global__ __launch_bounds__(256) void prep_all(
        const float* __restrict__ qw, const float* __restrict__ kw, const float* __restrict__ vw,
        const float* __restrict__ qb, const float* __restrict__ kb, const float* __restrict__ vb,
        const float* __restrict__ ckb, const float* __restrict__ cvb,
        const float* __restrict__ cond, const float* __restrict__ adw, const float* __restrict__ adb,
        unsigned short* __restrict__ qkvwT, float* __restrict__ qkvb, float* __restrict__ ckvb,
        float* __restrict__ mod) {
    __shared__ unsigned short tb[128 * 70];
    __shared__ float ssf[64];
    int bid = blockIdx.x;
    int tid = threadIdx.x;
    if (bid < 384) {
        int seg = bid >> 7;
        int lt = bid & 127;
        const float* src = (seg == 0) ? qw : (seg == 1 ? kw : vw);
        unsigned short* dst = qkvwT + (size_t)seg * 1024 * 1024;
        tcast_tile(src, dst, 1024, 1024, lt, tb, tid);
        return;
    }
    if (bid < 404) {
        int i = (bid - 384) * 256 + tid;      // 5120
        if (i < 1024) qkvb[i] = qb[i];
        else if (i < 2048) qkvb[i] = kb[i - 1024];
        else if (i < 3072) qkvb[i] = vb[i - 2048];
        else if (i < 4096) ckvb[i - 3072] = ckb[i - 3072];
        else if (i < 5120) ckvb[i - 3072] = cvb[i - 4096];
        return;
    }
    // AdaLN partial matvec
    int t = bid - 404;                // 0..767
    int jc = t % 24;
    int u = t / 24;                   // 0..31
    int bi = u >> 4, ks = u & 15;
    int k0 = ks * 64;
    if (tid < 64) {
        float c = cond[(size_t)bi * Hh + k0 + tid];
        ssf[tid] = c / (1.0f + expf(-c));
    }
    __syncthreads();
    int j = jc * 256 + tid;
    float acc = (ks == 0) ? adb[j] : 0.0f;
    const float* wp = adw + (size_t)k0 * (6 * Hh) + j;
    #pragma unroll 8
    for (int i = 0; i < 64; ++i)
        acc += ssf[i] * wp[(size_t)i * (6 * Hh)];
    atomicAdd(&mod[(size_t)bi * (6 * Hh) + j], acc);
}

// ---------------- bf16 [bh][S][64] -> bf16 [bh][64][S] transpose (for V) ----------------
__global__ __launch_bounds__(256) void vtrans16(const unsigned short* __restrict__ in,
        unsigned short* __restrict__ out, int S) {
    __shared__ unsigned short sm[32][36];
    int bh = blockIdx.z;
    int s0 = blockIdx.x * 32, d0 = blockIdx.y * 32;
    int lr = threadIdx.x >> 3, lc = (threadIdx.x & 7) << 2;
    ushort4 v = *(const ushort4*)&in[((size_t)bh * S + s0 + lr) * 64 + d0 + lc];
    sm[lr][lc] = v.x; sm[lr][lc + 1] = v.y; sm[lr][lc + 2] = v.z; sm[lr][lc + 3] = v.w;
    __syncthreads();
    ushort4 o;
    o.x = sm[lc + 0][lr]; o.y = sm[lc + 1][lr]; o.z = sm[lc + 2][lr]; o.w = sm[lc + 3][lr];
    *(ushort4*)&out[((size_t)bh * 64 + d0 + lr) * S + s0 + lc] = o;
}

// ---------------- LayerNorm + affine. OM bit0: fp32 out, bit1: bf16 out ----------------
template<int OM>
__global__ __launch_bounds__(256) void ln_affine(const float* __restrict__ X, float* __restrict__ O32,
        unsigned short* __restrict__ O16,
        const float* __restrict__ scale, const float* __restrict__ shift, int bstride, float add1) {
    int t = blockIdx.x;
    int tid = threadIdx.x;
    const float* xr = X + (size_t)t * Hh;
    float4 xv = *(const float4*)&xr[tid * 4];
    float s = xv.x + xv.y + xv.z + xv.w;
    float q = xv.x * xv.x + xv.y * xv.y + xv.z * xv.z + xv.w * xv.w;
    #pragma unroll
    for (int off = 32; off > 0; off >>= 1) {
        s += __shfl_down(s, off);
        q += __shfl_down(q, off);
    }
    __shared__ float rsum[4], rsq[4];
    __shared__ float smean, srstd;
    int wv = tid >> 6, ln = tid & 63;
    if (ln == 0) { rsum[wv] = s; rsq[wv] = q; }
    __syncthreads();
    if (tid == 0) {
        float ts = rsum[0] + rsum[1] + rsum[2] + rsum[3];
        float tq = rsq[0] + rsq[1] + rsq[2] + rsq[3];
        float mean = ts * (1.0f / Hh);
        float var = tq * (1.0f / Hh) - mean * mean;
        smean = mean; srstd = rsqrtf(var + EPSf);
    }
    __syncthreads();
    float mean = smean, rstd = srstd;
    int bi = t >> 10;
    int j = tid * 4;
    const float* scp = scale + (size_t)bi * bstride;
    const float* shp = shift + (size_t)bi * bstride;
    float4 sc4 = *(const float4*)&scp[j];
    float4 sh4 = *(const float4*)&shp[j];
    float4 o;
    o.x = (xv.x - mean) * rstd * (add1 + sc4.x) + sh4.x;
    o.y = (xv.y - mean) * rstd * (add1 + sc4.y) + sh4.y;
    o.z = (xv.z - mean) * rstd * (add1 + sc4.z) + sh4.z;
    o.w = (xv.w - mean) * rstd * (add1 + sc4.w) + sh4.w;
    if (OM & 1) *(float4*)&O32[(size_t)t * Hh + j] = o;
    if (OM & 2) {
        ushort4 h; h.x = f2bf(o.x); h.y = f2bf(o.y); h.z = f2bf(o.z); h.w = f2bf(o.w);
        *(ushort4*)&O16[(size_t)t * Hh + j] = h;
    }
}

// ---------------- 512-thread qkv GEMM + piggy-backed remaining weight prep ----------------
__global__ __launch_bounds__(512) void gemm_qkv(const unsigned short* __restrict__ A,
        const unsigned short* __restrict__ Bt, const float* __restrict__ bias,
        unsigned short* __restrict__ P0, unsigned short* __restrict__ P1,
        unsigned short* __restrict__ P2, const float* __restrict__ rc, const float* __restrict__ rsn,
        const float* __restrict__ ow, const float* __restrict__ cqw, const float* __restrict__ cow,
        const float* __restrict__ ckw, const float* __restrict__ cvw, const float* __restrict__ enc,
        unsigned short* __restrict__ owT, unsigned short* __restrict__ cqwT,
        unsigned short* __restrict__ cowT, unsigned short* __restrict__ ckvwT,
        unsigned short* __restrict__ encb, int K) {
    __shared__ unsigned short sh[2 * 128 * 32 * 2];   // 32KB: GEMM As/Bs or prep tile (17.9KB)
    int tid = threadIdx.x;
    if (blockIdx.y >= 24) {
        int t = blockIdx.x + 16 * (blockIdx.y - 24);
        if (t < 384) {
            int seg = t >> 7, lt = t & 127;
            const float* src = (seg == 0) ? ow : (seg == 1 ? cqw : cow);
            unsigned short* dst = (seg == 0) ? owT : (seg == 1 ? cqwT : cowT);
            tcast_tile512(src, dst, 1024, 1024, lt, sh, tid);
        } else if (t < 896) {
            int t2 = t - 384;
            const float* src = (t2 < 256) ? ckw : cvw;
            unsigned short* dst = (t2 < 256) ? ckvwT : (ckvwT + (size_t)1024 * 2048);
            tcast_tile512(src, dst, 2048, 1024, t2 & 255, sh, tid);
        } else {
            int i = (t - 896) * 512 + tid;
            float4 v = ((const float4*)enc)[i];
            ushort4 o; o.x = f2bf(v.x); o.y = f2bf(v.y); o.z = f2bf(v.z); o.w = f2bf(v.w);
            ((ushort4*)encb)[i] = o;
        }
        return;
    }
    unsigned short* As0 = sh;
    unsigned short* Bs0 = sh + 2 * 128 * 32;
    int m0 = blockIdx.x * 128, n0 = blockIdx.y * 128;
    int lane = tid & 63;
    int wv = tid >> 6;
    int wm = (wv >> 1) * 32, wn = (wv & 1) * 64;
    f32x4 acc[2][4] = {};
    int r0 = tid >> 2, q8 = (tid & 3) * 8;
    const unsigned short* gA = A + (size_t)(m0 + r0) * K + q8;
    const unsigned short* gB = Bt + (size_t)(n0 + r0) * K + q8;
    int ra = (lane & 15) * 32 + (lane >> 4) * 8;
    auto stage = [&](int kk, int bufi) {
        gload16(gA + kk, &As0[bufi * 128 * 32 + tid * 8]);
        gload16(gB + kk, &Bs0[bufi * 128 * 32 + tid * 8]);
    };
    int nsteps = K / 32;
    stage(0, 0);
    int cur = 0;
    for (int s = 0; s < nsteps; ++s) {
        if (s + 1 < nsteps) {
            stage((s + 1) * 32, cur ^ 1);
            asm volatile("s_waitcnt vmcnt(2)" ::: "memory");
        } else {
            asm volatile("s_waitcnt vmcnt(0)" ::: "memory");
        }
        __builtin_amdgcn_s_barrier();
        bf16x8 af[2], bf[4];
        #pragma unroll
        for (int f = 0; f < 2; ++f) af[f] = *(const bf16x8*)&As0[cur * 128 * 32 + (wm + f * 16) * 32 + ra];
        #pragma unroll
        for (int f = 0; f < 4; ++f) bf[f] = *(const bf16x8*)&Bs0[cur * 128 * 32 + (wn + f * 16) * 32 + ra];
        #pragma unroll
        for (int i = 0; i < 2; ++i)
            #pragma unroll
            for (int j = 0; j < 4; ++j)
                acc[i][j] = __builtin_amdgcn_mfma_f32_16x16x32_bf16(af[i], bf[j], acc[i][j], 0, 0, 0);
        asm volatile("s_waitcnt lgkmcnt(0)" ::: "memory");
        __builtin_amdgcn_s_barrier();
        cur ^= 1;
    }
    int colb = n0 + wn + (lane & 15);
    int rowb = m0 + wm + (lane >> 4) * 4;
    float bv[4];
    #pragma unroll
    for (int j = 0; j < 4; ++j) bv[j] = bias[colb + j * 16];
    int nh = (colb >> 6) & 15;
    int type = colb >> 10;
    float qs = (type == 0) ? 0.125f : 1.0f;   // fold 1/sqrt(HD) into Q
    #pragma unroll
    for (int i = 0; i < 2; ++i) {
        #pragma unroll
        for (int r = 0; r < 4; ++r) {
            int row = rowb + i * 16 + r;
            int b = row >> 10, s = row & 1023;
            unsigned short* dst = (type == 0) ? P0 : (type == 1 ? P1 : P2);
            size_t obase = ((size_t)((b * 16 + nh) * 1024 + s)) * 64;
            if (type < 2) {
                #pragma unroll
                for (int j = 0; j < 2; ++j) {
                    int hd = j * 16 + (lane & 15);
                    float v0 = acc[i][j][r] + bv[j];
                    float v2 = acc[i][j + 2][r] + bv[j + 2];
                    float c1 = rc[s * 64 + hd], s1 = rsn[s * 64 + hd];
                    float c2 = rc[s * 64 + hd + 32], s2 = rsn[s * 64 + hd + 32];
                    dst[obase + hd] = f2bf((v0 * c1 - v2 * s1) * qs);
                    dst[obase + hd + 32] = f2bf((v2 * c2 + v0 * s2) * qs);
                }
            } else {
                #pragma unroll
                for (int j = 0; j < 4; ++j)
                    dst[obase + j * 16 + (lane & 15)] = f2bf(acc[i][j][r] + bv[j]);
            }
        }
    }
}

// ===== 64x64-tile GEMM: 256 threads, 4 waves (2x2) of 32x32, 2-buffer =====
// EP 0: fp32 store. EP 2: ckv pack. EP 3: cQ pack *0.125. EP 4: Cf=baseb+gate*(acc+bias).
// EP 5: Cf=baseb+(acc+bias). Piggyback: blocks with y*64 >= N transpose one 128x64 tile
// of pw (4 experts' worth: tile t in [0,1024), e=t>>8) into pwT.
template<int EP>
__global__ __launch_bounds__(256) void gemm64(const unsigned short* __restrict__ A,
        const unsigned short* __restrict__ Bt, const float* __restrict__ bias,
        float* __restrict__ Cf, unsigned short* __restrict__ P0, unsigned short* __restrict__ P1,
        const float* __restrict__ baseb, const float* __restrict__ gatep,
        int M, int N, int K,
        const float* __restrict__ pw, unsigned short* __restrict__ pwT, int pR, int pC) {
    __shared__ unsigned short sh[8960];   // 17.9KB: GEMM As/Bs (8192 shorts) or prep tile
    int tid = threadIdx.x;
    if (pw != nullptr && (int)blockIdx.y * 64 >= N) {
        int t = blockIdx.x + gridDim.x * (blockIdx.y - (unsigned)(N / 64));
        int e = t >> 8, lt = t & 255;
        tcast_tile(pw + (size_t)e * ESZ, pwT + (size_t)e * ESZ, pR, pC, lt, sh, tid);
        return;
    }
    int m0 = blockIdx.x * 64, n0 = blockIdx.y * 64;
    int lane = tid & 63;
    int wv = tid >> 6;                        // 0..3
    int wm = (wv >> 1) * 32, wn = (wv & 1) * 32;
    f32x4 acc[2][2] = {};
    int r0 = tid >> 2, q8 = (tid & 3) * 8;    // r0 in [0,64)
    const unsigned short* gA = A + (size_t)(m0 + r0) * K + q8;
    const unsigned short* gB = Bt + (size_t)(n0 + r0) * K + q8;
    int ra = (lane & 15) * 32 + (lane >> 4) * 8;
    auto stage = [&](int kk, int bufi) {
        gload16(gA + kk, &sh[bufi * 2048 + tid * 8]);
        gload16(gB + kk, &sh[4096 + bufi * 2048 + tid * 8]);
    };
    int nsteps = K / 32;
    stage(0, 0);
    int cur = 0;
    for (int s = 0; s < nsteps; ++s) {
        if (s + 1 < nsteps) {
            stage((s + 1) * 32, cur ^ 1);
            asm volatile("s_waitcnt vmcnt(2)" ::: "memory");
        } else {
            asm volatile("s_waitcnt vmcnt(0)" ::: "memory");
        }
        __builtin_amdgcn_s_barrier();
        bf16x8 af[2], bf[2];
        #pragma unroll
        for (int f = 0; f < 2; ++f) {
            af[f] = *(const bf16x8*)&sh[cur * 2048 + (wm + f * 16) * 32 + ra];
            bf[f] = *(const bf16x8*)&sh[4096 + cur * 2048 + (wn + f * 16) * 32 + ra];
        }
        #pragma unroll
        for (int i = 0; i < 2; ++i)
            #pragma unroll
            for (int j = 0; j < 2; ++j)
                acc[i][j] = __builtin_amdgcn_mfma_f32_16x16x32_bf16(af[i], bf[j], acc[i][j], 0, 0, 0);
        asm volatile("s_waitcnt lgkmcnt(0)" ::: "memory");
        __builtin_amdgcn_s_barrier();
        cur ^= 1;
    }
    // D layout: col = lane&15, row = (lane>>4)*4 + reg
    int colb = n0 + wn + (lane & 15);
    int rowb = m0 + wm + (lane >> 4) * 4;
    float bv[2];
    #pragma unroll
    for (int j = 0; j < 2; ++j) bv[j] = bias[colb + j * 16];
    if (EP == 0 || EP == 4 || EP == 5) {
        #pragma unroll
        for (int j = 0; j < 2; ++j) {
            int col = colb + j * 16;
            #pragma unroll
            for (int i = 0; i < 2; ++i)
                #pragma unroll
                for (int r = 0; r < 4; ++r) {
                    int row = rowb + i * 16 + r;
                    size_t gi = (size_t)row * N + col;
                    float v = acc[i][j][r] + bv[j];
                    if (EP == 0) {
                        Cf[gi] = v;
                    } else if (EP == 4) {
                        float g = gatep[(row >> 10) * (6 * Hh) + col];
                        Cf[gi] = baseb[gi] + g * v;
                    } else {
                        Cf[gi] = baseb[gi] + v;
                    }
                }
        }
        return;
    }
    int nh = (colb >> 6) & 15;
    int type = colb >> 10;
    int hd0 = colb & 63;
    #pragma unroll
    for (int i = 0; i < 2; ++i) {
        #pragma unroll
        for (int r = 0; r < 4; ++r) {
            int row = rowb + i * 16 + r;
            if (EP == 2) {
                int b = row >> 8, s = row & 255;
                unsigned short* dst = (type == 0) ? P0 : P1;
                size_t obase = ((size_t)((b * 16 + nh) * 256 + s)) * 64;
                #pragma unroll
                for (int j = 0; j < 2; ++j)
                    dst[obase + hd0 + j * 16] = f2bf(acc[i][j][r] + bv[j]);
            } else {  // EP == 3: cQ pack, pre-scaled by 1/sqrt(HD)
                int b = row >> 10, s = row & 1023;
                size_t obase = ((size_t)((b * 16 + nh) * 1024 + s)) * 64;
                #pragma unroll
                for (int j = 0; j < 2; ++j)
                    P0[obase + hd0 + j * 16] = f2bf((acc[i][j][r] + bv[j]) * 0.125f);
            }
        }
    }
}

// ---------------- gathered MoE fc1 (512-thread / 8-wave, 128x128, 2-buf) ----------------
__global__ __launch_bounds__(512) void gemm_moe1(const unsigned short* __restrict__ A,
        const unsigned short* __restrict__ W, const float* __restrict__ bias,
        unsigned short* __restrict__ Og, const int* __restrict__ cnt,
        const int* __restrict__ offp, const int* __restrict__ gtok) {
    __shared__ unsigned short As[2][128 * 32];
    __shared__ unsigned short Bs[2][128 * 32];
    int m0 = blockIdx.x * 128;
    if (m0 >= offp[Ee]) return;
    int e = 0;
    while (offp[e + 1] <= m0) ++e;
    int base = offp[e], valid = cnt[e];
    int n0 = blockIdx.y * 128;
    int tid = threadIdx.x;
    int lane = tid & 63;
    int wv = tid >> 6;
    int wm = (wv >> 1) * 32, wn = (wv & 1) * 64;
    f32x4 acc[2][4] = {};
    int r0 = tid >> 2, q8 = (tid & 3) * 8;
    int lr0 = m0 - base + r0;
    int tok0 = gtok[base + (lr0 < valid ? lr0 : 0)];
    const unsigned short* gA = A + (size_t)tok0 * Hh + q8;
    const unsigned short* Wt = W + (size_t)e * Dd * Hh;
    const unsigned short* gB = Wt + (size_t)(n0 + r0) * Hh + q8;
    int ra = (lane & 15) * 32 + (lane >> 4) * 8;
    auto stage = [&](int kk, int bufi) {
        gload16(gA + kk, &As[bufi][tid * 8]);
        gload16(gB + kk, &Bs[bufi][tid * 8]);
    };
    int nsteps = Hh / 32;
    stage(0, 0);
    int cur = 0;
    for (int s = 0; s < nsteps; ++s) {
        if (s + 1 < nsteps) {
            stage((s + 1) * 32, cur ^ 1);
            asm volatile("s_waitcnt vmcnt(2)" ::: "memory");
        } else {
            asm volatile("s_waitcnt vmcnt(0)" ::: "memory");
        }
        __builtin_amdgcn_s_barrier();
        bf16x8 af[2], bf[4];
        #pragma unroll
        for (int f = 0; f < 2; ++f) af[f] = *(const bf16x8*)&As[cur][(wm + f * 16) * 32 + ra];
        #pragma unroll
        for (int f = 0; f < 4; ++f) bf[f] = *(const bf16x8*)&Bs[cur][(wn + f * 16) * 32 + ra];
        #pragma unroll
        for (int i = 0; i < 2; ++i)
            #pragma unroll
            for (int j = 0; j < 4; ++j)
                acc[i][j] = __builtin_amdgcn_mfma_f32_16x16x32_bf16(af[i], bf[j], acc[i][j], 0, 0, 0);
        asm volatile("s_waitcnt lgkmcnt(0)" ::: "memory");
        __builtin_amdgcn_s_barrier();
        cur ^= 1;
    }
    int colb = n0 + wn + (lane & 15);
    int rowtb = wm + (lane >> 4) * 4;
    const float* bp = bias + (size_t)e * Dd;
    #pragma unroll
    for (int j = 0; j < 4; ++j) {
        int col = colb + j * 16;
        float bv = bp[col];
        #pragma unroll
        for (int i = 0; i < 2; ++i) {
            #pragma unroll
            for (int r = 0; r < 4; ++r) {
                int rt = rowtb + i * 16 + r;
                if (m0 - base + rt < valid)
                    Og[(size_t)(m0 + rt) * Dd + col] = f2bf(geluf(acc[i][j][r] + bv));
            }
        }
    }
}

// ---------------- gathered MoE fc2 (512-thread, 128x128, split-K=2): stores y[z][g][col] ----------------
__global__ __launch_bounds__(512) void gemm_moe2(const unsigned short* __restrict__ A,
        const unsigned short* __restrict__ W, const float* __restrict__ bias,
        float* __restrict__ y, const int* __restrict__ cnt,
        const int* __restrict__ offp) {
    __shared__ unsigned short As[2][128 * 32];
    __shared__ unsigned short Bs[2][128 * 32];
    int m0 = blockIdx.x * 128;
    if (m0 >= offp[Ee]) return;
    int e = 0;
    while (offp[e + 1] <= m0) ++e;
    int base = offp[e], valid = cnt[e];
    int n0 = blockIdx.y * 128;
    int kz = blockIdx.z;                      // 0 or 1: K half
    int k0 = kz * (Dd / 2);
    int tid = threadIdx.x;
    int lane = tid & 63;
    int wv = tid >> 6;
    int wm = (wv >> 1) * 32, wn = (wv & 1) * 64;
    f32x4 acc[2][4] = {};
    int r0 = tid >> 2, q8 = (tid & 3) * 8;
    const unsigned short* gA = A + (size_t)(m0 + r0) * Dd + k0 + q8;
    const unsigned short* Wt = W + (size_t)e * Hh * Dd;
    const unsigned short* gB = Wt + (size_t)(n0 + r0) * Dd + k0 + q8;
    int ra = (lane & 15) * 32 + (lane >> 4) * 8;
    auto stage = [&](int kk, int bufi) {
        gload16(gA + kk, &As[bufi][tid * 8]);
        gload16(gB + kk, &Bs[bufi][tid * 8]);
    };
    int nsteps = (Dd / 2) / 32;
    stage(0, 0);
    int cur = 0;
    for (int s = 0; s < nsteps; ++s) {
        if (s + 1 < nsteps) {
            stage((s + 1) * 32, cur ^ 1);
            asm volatile("s_waitcnt vmcnt(2)" ::: "memory");
        } else {
            asm volatile("s_waitcnt vmcnt(0)" ::: "memory");
        }
        __builtin_amdgcn_s_barrier();
        bf16x8 af[2], bf[4];
        #pragma unroll
        for (int f = 0; f < 2; ++f) af[f] = *(const bf16x8*)&As[cur][(wm + f * 16) * 32 + ra];
        #pragma unroll
        for (int f = 0; f < 4; ++f) bf[f] = *(const bf16x8*)&Bs[cur][(wn + f * 16) * 32 + ra];
        #pragma unroll
        for (int i = 0; i < 2; ++i)
            #pragma unroll
            for (int j = 0; j < 4; ++j)
                acc[i][j] = __builtin_amdgcn_mfma_f32_16x16x32_bf16(af[i], bf[j], acc[i][j], 0, 0, 0);
        asm volatile("s_waitcnt lgkmcnt(0)" ::: "memory");
        __builtin_amdgcn_s_barrier();
        cur ^= 1;
    }
    int colb = n0 + wn + (lane & 15);
    int rowtb = wm + (lane >> 4) * 4;
    const float* bp = bias + (size_t)e * Hh;
    float* yz = y + (size_t)kz * PADROWS * Hh;
    #pragma unroll
    for (int j = 0; j < 4; ++j) {
        int col = colb + j * 16;
        float bv = (kz == 0) ? bp[col] : 0.0f;
        #pragma unroll
        for (int i = 0; i < 2; ++i) {
            #pragma unroll
            for (int r = 0; r < 4; ++r) {
                int rt = rowtb + i * 16 + r;
                int g = m0 + rt;
                if (g - base < valid)
                    yz[(size_t)g * Hh + col] = acc[i][j][r] + bv;
            }
        }
    }
}

// ---------------- MoE combine: out[t] += g2 .* (w0*(y0+y1)[g0] + w1*(y0+y1)[g1]) ----------------
__global__ __launch_bounds__(256) void moe_combine(const float* __restrict__ y,
        const int* __restrict__ gpos, const float* __restrict__ gwt,
        const float* __restrict__ gate2, float* __restrict__ outp) {
    int t = blockIdx.x;
    int j = threadIdx.x * 4;
    int g0 = gpos[2 * t], g1 = gpos[2 * t + 1];
    float w0 = gwt[g0], w1 = gwt[g1];
    const float* g2p = gate2 + (size_t)(t >> 10) * (6 * Hh);
    const size_t soff = (size_t)PADROWS * Hh;
    float4 a0 = *(const float4*)&y[(size_t)g0 * Hh + j];
    float4 a1 = *(const float4*)&y[soff + (size_t)g0 * Hh + j];
    float4 b0 = *(const float4*)&y[(size_t)g1 * Hh + j];
    float4 b1 = *(const float4*)&y[soff + (size_t)g1 * Hh + j];
    float4 g2 = *(const float4*)&g2p[j];
    float4 o = *(const float4*)&outp[(size_t)t * Hh + j];
    o.x += g2.x * (w0 * (a0.x + a1.x) + w1 * (b0.x + b1.x));
    o.y += g2.y * (w0 * (a0.y + a1.y) + w1 * (b0.y + b1.y));
    o.z += g2.z * (w0 * (a0.z + a1.z) + w1 * (b0.z + b1.z));
    o.w += g2.w * (w0 * (a0.w + a1.w) + w1 * (b0.w + b1.w));
    *(float4*)&outp[(size_t)t * Hh + j] = o;
}

// ---------------- MFMA flash attention + piggy-backed ew1 transposes (experts 0-3) --------
__global__ __launch_bounds__(256) void fattn_m(const unsigned short* __restrict__ Qp,
        const unsigned short* __restrict__ Kp, const unsigned short* __restrict__ Vtp,
        unsigned short* __restrict__ O, int Skv,
        const float* __restrict__ ew1, unsigned short* __restrict__ ew1T) {
    __shared__ unsigned short shbuf[4 * 64 * 72];   // 36,864B; prep tile needs 8,960 shorts
    int tid = threadIdx.x;
    if (blockIdx.y >= 32) {
        int tile = blockIdx.x + 16 * (blockIdx.y - 32);   // 0..1023 (ew1 experts 0-3)
        int e = tile >> 8, lt = tile & 255;
        tcast_tile(ew1 + (size_t)e * ESZ, ew1T + (size_t)e * ESZ, 1024, 2048, lt, shbuf, tid);
        return;
    }
    unsigned short* Qs  = shbuf;
    unsigned short* Ks  = shbuf + 64 * 72;
    unsigned short* Vts = shbuf + 2 * 64 * 72;
    unsigned short* Ps  = shbuf + 3 * 64 * 72;
    int q0 = blockIdx.x * 64;
    int bh = blockIdx.y;
    int b = bh >> 4, nh = bh & 15;
    int lane = tid & 63, w = tid >> 6;
    int sr = tid >> 2, sp = (tid & 3) * 16;   // staging: row, 16-elem chunk
    {
        const unsigned short* src = &Qp[((size_t)bh * 1024 + q0 + sr) * 64 + sp];
        *(ushort8*)&Qs[sr * 72 + sp] = *(const ushort8*)&src[0];
        *(ushort8*)&Qs[sr * 72 + sp + 8] = *(const ushort8*)&src[8];
    }
    f32x4 acc[4] = {};
    float m_old[4], l_run[4];
    #pragma unroll
    for (int r = 0; r < 4; ++r) { m_old[r] = -1e30f; l_run[r] = 0.0f; }
    int wrow = w * 16;
    int k8 = (lane >> 4) * 8;
    ushort8 pkA, pkB, pvA, pvB;
    {
        const unsigned short* ksrc = &Kp[((size_t)bh * Skv + sr) * 64 + sp];
        pkA = *(const ushort8*)&ksrc[0];
        pkB = *(const ushort8*)&ksrc[8];
        const unsigned short* vsrc = &Vtp[((size_t)bh * 64 + sr) * Skv + sp];
        pvA = *(const ushort8*)&vsrc[0];
        pvB = *(const ushort8*)&vsrc[8];
    }
    for (int k0 = 0; k0 < Skv; k0 += 64) {
        asm volatile("s_waitcnt lgkmcnt(0)" ::: "memory");
        __builtin_amdgcn_s_barrier();                  // Ks/Vts free (prev PV reads done)
        *(ushort8*)&Ks[sr * 72 + sp] = pkA;
        *(ushort8*)&Ks[sr * 72 + sp + 8] = pkB;
        *(ushort8*)&Vts[sr * 72 + sp] = pvA;
        *(ushort8*)&Vts[sr * 72 + sp + 8] = pvB;
        if (k0 + 64 < Skv) {
            const unsigned short* ksrc = &Kp[((size_t)bh * Skv + k0 + 64 + sr) * 64 + sp];
            pkA = *(const ushort8*)&ksrc[0];
            pkB = *(const ushort8*)&ksrc[8];
            const unsigned short* vsrc = &Vtp[((size_t)bh * 64 + sr) * Skv + k0 + 64 + sp];
            pvA = *(const ushort8*)&vsrc[0];
            pvB = *(const ushort8*)&vsrc[8];
        }
        asm volatile("s_waitcnt lgkmcnt(0)" ::: "memory");
        __builtin_amdgcn_s_barrier();                  // staging (and iter-0 Qs) visible
        bf16x8 aq0 = *(const bf16x8*)&Qs[(wrow + (lane & 15)) * 72 + k8];
        bf16x8 aq1 = *(const bf16x8*)&Qs[(wrow + (lane & 15)) * 72 + 32 + k8];
        f32x4 sf[4];
        __builtin_amdgcn_s_setprio(1);
        #pragma unroll
        for (int j = 0; j < 4; ++j) {
            bf16x8 bk0 = *(const bf16x8*)&Ks[(j * 16 + (lane & 15)) * 72 + k8];
            bf16x8 bk1 = *(const bf16x8*)&Ks[(j * 16 + (lane & 15)) * 72 + 32 + k8];
            f32x4 z = {};
            z = __builtin_amdgcn_mfma_f32_16x16x32_bf16(aq0, bk0, z, 0, 0, 0);
            z = __builtin_amdgcn_mfma_f32_16x16x32_bf16(aq1, bk1, z, 0, 0, 0);
            sf[j] = z;
        }
        __builtin_amdgcn_s_setprio(0);
        float p[4][4];
        float fsc[4];
        #pragma unroll
        for (int r = 0; r < 4; ++r) {
            float mx = fmaxf(fmaxf(sf[0][r], sf[1][r]), fmaxf(sf[2][r], sf[3][r]));
            #pragma unroll
            for (int mk = 1; mk < 16; mk <<= 1) mx = fmaxf(mx, __shfl_xor(mx, mk));
            float mn = fmaxf(m_old[r], mx);
            float f = __expf(m_old[r] - mn);
            float rs = 0.0f;
            #pragma unroll
            for (int j = 0; j < 4; ++j) {
                p[j][r] = __expf(sf[j][r] - mn);
                rs += p[j][r];
            }
            #pragma unroll
            for (int mk = 1; mk < 16; mk <<= 1) rs += __shfl_xor(rs, mk);
            l_run[r] = l_run[r] * f + rs;
            m_old[r] = mn;
            fsc[r] = f;
        }
        #pragma unroll
        for (int jd = 0; jd < 4; ++jd)
            #pragma unroll
            for (int r = 0; r < 4; ++r) acc[jd][r] *= fsc[r];
        #pragma unroll
        for (int j = 0; j < 4; ++j)
            #pragma unroll
            for (int r = 0; r < 4; ++r)
                Ps[(wrow + (lane >> 4) * 4 + r) * 72 + j * 16 + (lane & 15)] = f2bf(p[j][r]);
        asm volatile("s_waitcnt lgkmcnt(0)" ::: "memory");
        __builtin_amdgcn_s_barrier();                  // Ps visible
        bf16x8 ap0 = *(const bf16x8*)&Ps[(wrow + (lane & 15)) * 72 + k8];
        bf16x8 ap1 = *(const bf16x8*)&Ps[(wrow + (lane & 15)) * 72 + 32 + k8];
        __builtin_amdgcn_s_setprio(1);
        #pragma unroll
        for (int jd = 0; jd < 4; ++jd) {
            bf16x8 bv0 = *(const bf16x8*)&Vts[(jd * 16 + (lane & 15)) * 72 + k8];
            bf16x8 bv1 = *(const bf16x8*)&Vts[(jd * 16 + (lane & 15)) * 72 + 32 + k8];
            acc[jd] = __builtin_amdgcn_mfma_f32_16x16x32_bf16(ap0, bv0, acc[jd], 0, 0, 0);
            acc[jd] = __builtin_amdgcn_mfma_f32_16x16x32_bf16(ap1, bv1, acc[jd], 0, 0, 0);
        }
        __builtin_amdgcn_s_setprio(0);
    }
    float inv[4];
    #pragma unroll
    for (int r = 0; r < 4; ++r) inv[r] = 1.0f / l_run[r];
    #pragma unroll
    for (int jd = 0; jd < 4; ++jd)
        #pragma unroll
        for (int r = 0; r < 4; ++r)
            O[((size_t)(b * Ss + q0 + wrow + (lane >> 4) * 4 + r)) * Hh + nh * 64 + jd * 16 + (lane & 15)]
                = f2bf(acc[jd][r] * inv[r]);
}

// ---------------- MoE gate: one wave per token, coalesced ----------------
__global__ __launch_bounds__(256) void gate_kernel(const float* __restrict__ h,
        const float* __restrict__ gw, float* __restrict__ probs, int* __restrict__ topi,
        float* __restrict__ topw) {
    int t = blockIdx.x * 4 + (threadIdx.x >> 6);
    int lane = threadIdx.x & 63;
    const float* hp = h + (size_t)t * Hh;
    float lg[Ee] = {};
    #pragma unroll
    for (int s = 0; s < 4; ++s) {
        int d0 = s * 256 + lane * 4;
        float4 hv = *(const float4*)&hp[d0];
        float hv4[4] = {hv.x, hv.y, hv.z, hv.w};
        #pragma unroll
        for (int c = 0; c < 4; ++c) {
            float hx = hv4[c];
            const float* g0 = &gw[(size_t)(d0 + c) * Ee];
            #pragma unroll
            for (int e = 0; e < Ee; ++e) lg[e] += hx * g0[e];
        }
    }
    #pragma unroll
    for (int e = 0; e < Ee; ++e)
        #pragma unroll
        for (int mk = 1; mk < 64; mk <<= 1) lg[e] += __shfl_xor(lg[e], mk);
    if (lane == 0) {
        float m = lg[0];
        #pragma unroll
        for (int e = 1; e < Ee; ++e) m = fmaxf(m, lg[e]);
        float ssum = 0;
        #pragma unroll
        for (int e = 0; e < Ee; ++e) { lg[e] = expf(lg[e] - m); ssum += lg[e]; }
        float inv = 1.0f / ssum;
        #pragma unroll
        for (int e = 0; e < Ee; ++e) { lg[e] *= inv; probs[t * Ee + e] = lg[e]; }
        int i0 = 0;
        #pragma unroll
        for (int e = 1; e < Ee; ++e) if (lg[e] > lg[i0]) i0 = e;
        int i1 = (i0 == 0) ? 1 : 0;
        #pragma unroll
        for (int e = 0; e < Ee; ++e) if (e != i1 && e != i0 && lg[e] > lg[i1]) i1 = e;
        float w0 = lg[i0], w1 = lg[i1];
        float inv2 = 1.0f / (w0 + w1);
        topi[t * 2] = i0; topi[t * 2 + 1] = i1;
        topw[t * 2] = w0 * inv2; topw[t * 2 + 1] = w1 * inv2;
    }
}

// ---------------- fused MoE prep: count + scan + scatter + aux (single 1024-thread block) ----------------
__global__ __launch_bounds__(1024) void moe_prep(const float* __restrict__ probs,
        const int* __restrict__ topi, const float* __restrict__ topw,
        int* __restrict__ cnt, int* __restrict__ offp,
        int* __restrict__ gtok, float* __restrict__ gwt, int* __restrict__ gpos,
        float* __restrict__ auxout) {
    __shared__ int scnt[Ee], spos[Ee], soff[Ee + 1];
    __shared__ float sS[Ee], sC[Ee];
    int tid = threadIdx.x;
    if (tid < Ee) { scnt[tid] = 0; spos[tid] = 0; sS[tid] = 0.0f; sC[tid] = 0.0f; }
    __syncthreads();
    float lp[Ee] = {};
    float lc[Ee] = {};
    for (int t = tid; t < Tt; t += 1024) {
        int a0 = topi[2 * t], a1 = topi[2 * t + 1];
        atomicAdd(&scnt[a0], 1);
        atomicAdd(&scnt[a1], 1);
        #pragma unroll
        for (int e = 0; e < Ee; ++e) lp[e] += probs[t * Ee + e];
        lc[a0] += 1.0f; lc[a1] += 1.0f;
    }
    #pragma unroll
    for (int e = 0; e < Ee; ++e) {
        atomicAdd(&sS[e], lp[e]);
        atomicAdd(&sC[e], lc[e]);
    }
    __syncthreads();
    if (tid == 0) {
        int acc = 0;
        for (int e = 0; e < Ee; ++e) { soff[e] = acc; acc += (scnt[e] + 127) & ~127; }
        soff[Ee] = acc;
        float aux = 0.0f;
        for (int e = 0; e < Ee; ++e) aux += sS[e] * sC[e];
        auxout[0] = aux * (8.0f / 4096.0f);   // E/(B*B*S)
    }
    if (tid < Ee) cnt[tid] = scnt[tid];
    __syncthreads();
    if (tid <= Ee) offp[tid] = soff[tid];
    for (int t = tid; t < Tt; t += 1024) {
        #pragma unroll
        for (int s = 0; s < 2; ++s) {
            int e = topi[2 * t + s];
            int pos = atomicAdd(&spos[e], 1);
            int g = soff[e] + pos;
            gtok[g] = t;
            gwt[g] = topw[2 * t + s];
            gpos[2 * t + s] = g;
        }
    }
}

extern "C" void kernel_launch(void* const* d_in, const int* in_sizes, int n_in,
                              void* d_out, int out_size, void* d_ws, size_t ws_size,
                              hipStream_t stream) {
    (void)in_sizes; (void)n_in; (void)out_size; (void)ws_size;
    const float* x    = (const float*)d_in[0];
    const float* cond = (const float*)d_in[1];
    const float* enc  = (const float*)d_in[2];
    const float* rc   = (const float*)d_in[3];
    const float* rsn  = (const float*)d_in[4];
    const float* adw  = (const float*)d_in[5];
    const float* adb  = (const float*)d_in[6];
    const float* qw  = (const float*)d_in[7];  const float* qb  = (const float*)d_in[8];
    const float* kw  = (const float*)d_in[9];  const float* kb2 = (const float*)d_in[10];
    const float* vw  = (const float*)d_in[11]; const float* vb  = (const float*)d_in[12];
    const float* ow  = (const float*)d_in[13]; const float* ob  = (const float*)d_in[14];
    const float* cqw = (const float*)d_in[15]; const float* cqb = (const float*)d_in[16];
    const float* ckw = (const float*)d_in[17]; const float* ckb = (const float*)d_in[18];
    const float* cvw = (const float*)d_in[19]; const float* cvb = (const float*)d_in[20];
    const float* cow = (const float*)d_in[21]; const float* cob = (const float*)d_in[22];
    const float* cng = (const float*)d_in[23]; const float* cnb = (const float*)d_in[24];
    const float* gatew = (const float*)d_in[25];
    const float* ew1 = (const float*)d_in[26]; const float* eb1 = (const float*)d_in[27];
    const float* ew2 = (const float*)d_in[28]; const float* eb2 = (const float*)d_in[29];
    float* out = (float*)d_out;

    char* ws = (char*)d_ws;
    size_t off = 0;
    auto alloc = [&](size_t bytes) {
        char* p = ws + off;
        off += (bytes + 255) & ~(size_t)255;
        return (void*)p;
    };
    // fp32 buffers
    float* hbuf   = (float*)alloc((size_t)Tt * Hh * 4);
    float* mod    = (float*)alloc((size_t)Bb * 6 * Hh * 4);
    float* probs  = (float*)alloc((size_t)Tt * Ee * 4);
    float* topw   = (float*)alloc((size_t)Tt * 2 * 4);
    int*   topi   = (int*)alloc((size_t)Tt * 2 * 4);
    float* qkvb   = (float*)alloc(3072 * 4);
    float* ckvb   = (float*)alloc(2048 * 4);
    int*   cntbuf = (int*)alloc(16 * 4);
    int*   offp   = (int*)alloc(16 * 4);
    int*   gtok   = (int*)alloc((size_t)PADROWS * 4);
    float* gwt    = (float*)alloc((size_t)PADROWS * 4);
    int*   gpos   = (int*)alloc((size_t)Tt * 2 * 4);
    // bf16 buffers
    typedef unsigned short u16;
    u16* h1b   = (u16*)alloc((size_t)Tt * Hh * 2);
    u16* hcb   = (u16*)alloc((size_t)Tt * Hh * 2);
    u16* h2b   = (u16*)alloc((size_t)Tt * Hh * 2);
    u16* abb   = (u16*)alloc((size_t)Tt * Hh * 2);
    u16* encb  = (u16*)alloc((size_t)Bb * Ll * Cc * 2);
    u16* actg  = (u16*)alloc((size_t)PADROWS * Dd * 2);
    // packed attention operands
    u16* Qb16  = (u16*)alloc((size_t)32 * 1024 * 64 * 2);
    u16* Kb16  = (u16*)alloc((size_t)32 * 1024 * 64 * 2);
    u16* Vb16  = (u16*)alloc((size_t)32 * 1024 * 64 * 2);
    u16* Vt16  = (u16*)alloc((size_t)32 * 64 * 1024 * 2);
    u16* cQ16  = (u16*)alloc((size_t)32 * 1024 * 64 * 2);
    u16* cK16  = (u16*)alloc((size_t)32 * 256 * 64 * 2);
    u16* cV16  = (u16*)alloc((size_t)32 * 256 * 64 * 2);
    u16* cVt16 = (u16*)alloc((size_t)32 * 64 * 256 * 2);
    // bf16 transposed weights [N][K]
    u16* qkvwT = (u16*)alloc((size_t)3072 * 1024 * 2);
    u16* owT   = (u16*)alloc((size_t)1024 * 1024 * 2);
    u16* cqwT  = (u16*)alloc((size_t)1024 * 1024 * 2);
    u16* ckvwT = (u16*)alloc((size_t)2048 * 2048 * 2);
    u16* cowT  = (u16*)alloc((size_t)1024 * 1024 * 2);
    u16* ew1T  = (u16*)alloc((size_t)Ee * Hh * Dd * 2);
    u16* ew2T  = (u16*)alloc((size_t)Ee * Dd * Hh * 2);
    // MoE fc2 split-K partials y[2][PADROWS][Hh] fp32 (41.9 MB), aliased over the
    // Qb16..ckvwT span (~43 MB, all dead after step 11). ew1T/ew2T untouched.
    float* ybuf = (float*)Qb16;

    dim3 blk(256);
    dim3 blk512(512);
    // 0. zero mod (AdaLN accumulators), then fused prep incl. AdaLN K-split matvec
    hipMemsetAsync(mod, 0, (size_t)Bb * 6 * Hh * 4, stream);
    prep_all<<<dim3(1172), blk, 0, stream>>>(qw, kw, vw, qb, kb2, vb, ckb, cvb,
        cond, adw, adb, qkvwT, qkvb, ckvb, mod);
    // 2. h1 = ln(x)*(1+sc1)+sh1  -> bf16
    ln_affine<2><<<dim3(Tt), blk, 0, stream>>>(x, nullptr, h1b, mod + Hh, mod + 0, 6 * Hh, 1.0f);
    // 3. fused qkv projection + rope + pack (+1408 piggy-backed prep blocks)
    gemm_qkv<<<dim3(16, 24 + 88), blk512, 0, stream>>>(h1b, qkvwT, qkvb,
        Qb16, Kb16, Vb16, rc, rsn,
        ow, cqw, cow, ckw, cvw, enc, owT, cqwT, cowT, ckvwT, encb, 1024);
    // 4. V transpose [bh][64][1024]
    vtrans16<<<dim3(32, 2, 32), blk, 0, stream>>>(Vb16, Vt16, 1024);
    // 5. MFMA self-attention (+1024 ew1 expert-0..3 transpose tiles)
    fattn_m<<<dim3(16, 32 + 64), blk, 0, stream>>>(Qb16, Kb16, Vt16, abb, 1024,
        ew1, ew1T);
    // 6+7. output projection fused with residual (+1024 ew1 expert-4..7 tiles)
    gemm64<4><<<dim3(Tt / 64, Hh / 64 + 32), blk, 0, stream>>>(abb, owT, ob, out,
        nullptr, nullptr, x, mod + 2 * Hh, Tt, Hh, 1024,
        ew1 + 4 * ESZ, ew1T + 4 * ESZ, 1024, 2048);
    // 8. hc = ln(x1)*cn_g + cn_b -> bf16
    ln_affine<2><<<dim3(Tt), blk, 0, stream>>>(out, nullptr, hcb, cng, cnb, 0, 0.0f);
    // 9. cross q (packed, pre-scaled) (+1024 ew2 expert-0..3 tiles) + fused ck/cv (packed)
    gemm64<3><<<dim3(Tt / 64, Hh / 64 + 32), blk, 0, stream>>>(hcb, cqwT, cqb, nullptr,
        cQ16, nullptr, nullptr, nullptr, Tt, Hh, 1024,
        ew2, ew2T, 2048, 1024);
    gemm64<2><<<dim3(Bb * Ll / 64, 2048 / 64), blk, 0, stream>>>(encb, ckvwT, ckvb, nullptr,
        cK16, cV16, nullptr, nullptr, Bb * Ll, 2048, Cc,
        nullptr, nullptr, 0, 0);
    vtrans16<<<dim3(8, 2, 32), blk, 0, stream>>>(cV16, cVt16, 256);
    // 10. MFMA cross-attention (kv 256; no piggy-back blocks)
    fattn_m<<<dim3(16, 32), blk, 0, stream>>>(cQ16, cK16, cVt16, abb, 256,
        ew1, ew1T);
    // 11+12. cross output projection fused with residual (+1024 ew2 expert-4..7 tiles)
    gemm64<5><<<dim3(Tt / 64, Hh / 64 + 32), blk, 0, stream>>>(abb, cowT, cob, out,
        nullptr, nullptr, out, nullptr, Tt, Hh, 1024,
        ew2 + 4 * ESZ, ew2T + 4 * ESZ, 2048, 1024);
    // 13. h2 = ln(x2)*(1+sc2)+sh2 -> fp32 + bf16
    ln_affine<3><<<dim3(Tt), blk, 0, stream>>>(out, hbuf, h2b, mod + 4 * Hh, mod + 3 * Hh, 6 * Hh, 1.0f);
    // 14. gate + fused prep (count/scan/scatter/aux)
    gate_kernel<<<dim3(Tt / 4), blk, 0, stream>>>(hbuf, gatew, probs, topi, topw);
    moe_prep<<<dim3(1), dim3(1024), 0, stream>>>(probs, topi, topw, cntbuf, offp, gtok, gwt,
        gpos, out + (size_t)Tt * Hh);
    // 16+17. gathered MoE (128x128); fc2 split-K=2 -> y partials; combine folds residual
    gemm_moe1<<<dim3(PADROWS / 128, Dd / 128), blk512, 0, stream>>>(h2b, ew1T, eb1, actg, cntbuf, offp, gtok);
    gemm_moe2<<<dim3(PADROWS / 128, Hh / 128, 2), blk512, 0, stream>>>(actg, ew2T, eb2, ybuf, cntbuf, offp);
    moe_combine<<<dim3(Tt), blk, 0, stream>>>(ybuf, gpos, gwt, mod + 5 * Hh, out);
}

// Round 26
// 346.230 us; speedup vs baseline: 1.2286x; 1.0066x over previous
//
#include <hip/hip_runtime.h>
#include <math.h>

// Shapes (compile-time constants from the reference)
#define Hh 1024
#define Ss 1024
#define Bb 2
#define NHh 16
#define HDd 64
#define Tt 2048   // B*S
#define Ll 256
#define Cc 2048
#define Ee 8
#define Dd 2048
#define EPSf 1e-5f
#define PADROWS 5120
#define ESZ ((size_t)1024 * 2048)

using bf16x8 = __attribute__((ext_vector_type(8))) short;
using f32x4  = __attribute__((ext_vector_type(4))) float;
using ushort8 = __attribute__((ext_vector_type(8))) unsigned short;

__device__ __forceinline__ float geluf(float x) {
    return 0.5f * x * (1.0f + erff(x * 0.70710678118654752f));
}

__device__ __forceinline__ unsigned short f2bf(float x) {
    union { float f; unsigned int u; } c; c.f = x;
    unsigned int r = (c.u + 0x7fffu + ((c.u >> 16) & 1u)) >> 16;
    return (unsigned short)r;
}

__device__ __forceinline__ void gload16(const void* g, void* l) {
    __builtin_amdgcn_global_load_lds(
        (const __attribute__((address_space(1))) void*)g,
        (__attribute__((address_space(3))) void*)l, 16, 0, 0);
}

// ---------------- 128x64 transpose-cast tile, 256-thread variant ----------------
__device__ __forceinline__ void tcast_tile(const float* __restrict__ src,
        unsigned short* __restrict__ dst, int R, int C, int lt,
        unsigned short* __restrict__ tb, int tid) {
    int gx = R >> 7;
    int rt = lt % gx, ct = lt / gx;
    int r0 = rt * 128, c0 = ct * 64;
    int lr = tid >> 4;               // 0..15
    int lc4 = (tid & 15) << 2;       // 0..60
    #pragma unroll
    for (int p = 0; p < 8; ++p) {
        int row = lr + 16 * p;       // 0..127
        float4 v = *(const float4*)&src[(size_t)(r0 + row) * C + c0 + lc4];
        ushort4 h; h.x = f2bf(v.x); h.y = f2bf(v.y); h.z = f2bf(v.z); h.w = f2bf(v.w);
        *(ushort4*)&tb[row * 70 + lc4] = h;
    }
    __syncthreads();
    int wr = tid >> 5;               // 0..7
    int wc4 = (tid & 31) << 2;       // 0..124
    #pragma unroll
    for (int p = 0; p < 8; ++p) {
        int orow = wr + 8 * p;       // 0..63
        ushort4 o;
        o.x = tb[(wc4 + 0) * 70 + orow];
        o.y = tb[(wc4 + 1) * 70 + orow];
        o.z = tb[(wc4 + 2) * 70 + orow];
        o.w = tb[(wc4 + 3) * 70 + orow];
        *(ushort4*)&dst[(size_t)(c0 + orow) * R + r0 + wc4] = o;
    }
}

// ---------------- 128x64 transpose-cast tile, 512-thread variant ----------------
__device__ __forceinline__ void tcast_tile512(const float* __restrict__ src,
        unsigned short* __restrict__ dst, int R, int C, int lt,
        unsigned short* __restrict__ tb, int tid) {
    int gx = R >> 7;
    int rt = lt % gx, ct = lt / gx;
    int r0 = rt * 128, c0 = ct * 64;
    int lr = tid >> 4;               // 0..31
    int lc4 = (tid & 15) << 2;       // 0..60
    #pragma unroll
    for (int p = 0; p < 4; ++p) {
        int row = lr + 32 * p;       // 0..127
        float4 v = *(const float4*)&src[(size_t)(r0 + row) * C + c0 + lc4];
        ushort4 h; h.x = f2bf(v.x); h.y = f2bf(v.y); h.z = f2bf(v.z); h.w = f2bf(v.w);
        *(ushort4*)&tb[row * 70 + lc4] = h;
    }
    __syncthreads();
    int wr = tid >> 5;               // 0..15
    int wc4 = (tid & 31) << 2;       // 0..124
    #pragma unroll
    for (int p = 0; p < 4; ++p) {
        int orow = wr + 16 * p;      // 0..63
        ushort4 o;
        o.x = tb[(wc4 + 0) * 70 + orow];
        o.y = tb[(wc4 + 1) * 70 + orow];
        o.z = tb[(wc4 + 2) * 70 + orow];
        o.w = tb[(wc4 + 3) * 70 + orow];
        *(ushort4*)&dst[(size_t)(c0 + orow) * R + r0 + wc4] = o;
    }
}

// ---------------- upfront prep: q/k/v weight transposes + bias concat + AdaLN matvec ----------
// [0,384): qw/kw/vw tiles (128 each). [384,404): biascat.
// [404,1172): AdaLN K-split matvec: t = bid-404; jc = t%24 (256 cols), u = t/24 in [0,32):
//   bi = u>>4, ks = u&15 (K slice of 64). Deterministic: partials stored to modp[bi][ks][j];
//   bias folded into ks==0 slice; mod_reduce sums slices in fixed order.
__global__ __launch_bounds__(256) void prep_all(
        const float* __restrict__ qw, const float* __restrict__ kw, const float* __restrict__ vw,
        const float* __restrict__ qb, const float* __restrict__ kb, const float* __restrict__ vb,
        const float* __restrict__ ckb, const float* __restrict__ cvb,
        const float* __restrict__ cond, const float* __restrict__ adw, const float* __restrict__ adb,
        unsigned short* __restrict__ qkvwT, float* __restrict__ qkvb, float* __restrict__ ckvb,
        float* __restrict__ modp) {
    __shared__ unsigned short tb[128 * 70];
    __shared__ float ssf[64];
    int bid = blockIdx.x;
    int tid = threadIdx.x;
    if (bid < 384) {
        int seg = bid >> 7;
        int lt = bid & 127;
        const float* src = (seg == 0) ? qw : (seg == 1 ? kw : vw);
        unsigned short* dst = qkvwT + (size_t)seg * 1024 * 1024;
        tcast_tile(src, dst, 1024, 1024, lt, tb, tid);
        return;
    }
    if (bid < 404) {
        int i = (bid - 384) * 256 + tid;      // 5120
        if (i < 1024) qkvb[i] = qb[i];
        else if (i < 2048) qkvb[i] = kb[i - 1024];
        else if (i < 3072) qkvb[i] = vb[i - 2048];
        else if (i < 4096) ckvb[i - 3072] = ckb[i - 3072];
        else if (i < 5120) ckvb[i - 3072] = cvb[i - 4096];
        return;
    }
    // AdaLN partial matvec (deterministic: store, no atomics)
    int t = bid - 404;                // 0..767
    int jc = t % 24;
    int u = t / 24;                   // 0..31
    int bi = u >> 4, ks = u & 15;
    int k0 = ks * 64;
    if (tid < 64) {
        float c = cond[(size_t)bi * Hh + k0 + tid];
        ssf[tid] = c / (1.0f + expf(-c));
    }
    __syncthreads();
    int j = jc * 256 + tid;
    float acc = (ks == 0) ? adb[j] : 0.0f;
    const float* wp = adw + (size_t)k0 * (6 * Hh) + j;
    #pragma unroll 8
    for (int i = 0; i < 64; ++i)
        acc += ssf[i] * wp[(size_t)i * (6 * Hh)];
    modp[((size_t)bi * 16 + ks) * (6 * Hh) + j] = acc;
}

// ---------------- deterministic 16-way slice reduce: mod[bi][j] = sum_ks modp[bi][ks][j] ----
__global__ __launch_bounds__(256) void mod_reduce(const float* __restrict__ modp,
        float* __restrict__ mod) {
    int idx = blockIdx.x * 256 + threadIdx.x;     // 0..12287
    int bi = idx / (6 * Hh), j = idx % (6 * Hh);
    const float* p = modp + (size_t)bi * 16 * (6 * Hh) + j;
    float s = 0.0f;
    #pragma unroll
    for (int ks = 0; ks < 16; ++ks) s += p[(size_t)ks * (6 * Hh)];
    mod[idx] = s;
}

// ---------------- bf16 [bh][S][64] -> bf16 [bh][64][S] transpose (for V) ----------------
__global__ __launch_bounds__(256) void vtrans16(const unsigned short* __restrict__ in,
        unsigned short* __restrict__ out, int S) {
    __shared__ unsigned short sm[32][36];
    int bh = blockIdx.z;
    int s0 = blockIdx.x * 32, d0 = blockIdx.y * 32;
    int lr = threadIdx.x >> 3, lc = (threadIdx.x & 7) << 2;
    ushort4 v = *(const ushort4*)&in[((size_t)bh * S + s0 + lr) * 64 + d0 + lc];
    sm[lr][lc] = v.x; sm[lr][lc + 1] = v.y; sm[lr][lc + 2] = v.z; sm[lr][lc + 3] = v.w;
    __syncthreads();
    ushort4 o;
    o.x = sm[lc + 0][lr]; o.y = sm[lc + 1][lr]; o.z = sm[lc + 2][lr]; o.w = sm[lc + 3][lr];
    *(ushort4*)&out[((size_t)bh * 64 + d0 + lr) * S + s0 + lc] = o;
}

// ---------------- LayerNorm + affine. OM bit0: fp32 out, bit1: bf16 out ----------------
template<int OM>
__global__ __launch_bounds__(256) void ln_affine(const float* __restrict__ X, float* __restrict__ O32,
        unsigned short* __restrict__ O16,
        const float* __restrict__ scale, const float* __restrict__ shift, int bstride, float add1) {
    int t = blockIdx.x;
    int tid = threadIdx.x;
    const float* xr = X + (size_t)t * Hh;
    float4 xv = *(const float4*)&xr[tid * 4];
    float s = xv.x + xv.y + xv.z + xv.w;
    float q = xv.x * xv.x + xv.y * xv.y + xv.z * xv.z + xv.w * xv.w;
    #pragma unroll
    for (int off = 32; off > 0; off >>= 1) {
        s += __shfl_down(s, off);
        q += __shfl_down(q, off);
    }
    __shared__ float rsum[4], rsq[4];
    __shared__ float smean, srstd;
    int wv = tid >> 6, ln = tid & 63;
    if (ln == 0) { rsum[wv] = s; rsq[wv] = q; }
    __syncthreads();
    if (tid == 0) {
        float ts = rsum[0] + rsum[1] + rsum[2] + rsum[3];
        float tq = rsq[0] + rsq[1] + rsq[2] + rsq[3];
        float mean = ts * (1.0f / Hh);
        float var = tq * (1.0f / Hh) - mean * mean;
        smean = mean; srstd = rsqrtf(var + EPSf);
    }
    __syncthreads();
    float mean = smean, rstd = srstd;
    int bi = t >> 10;
    int j = tid * 4;
    const float* scp = scale + (size_t)bi * bstride;
    const float* shp = shift + (size_t)bi * bstride;
    float4 sc4 = *(const float4*)&scp[j];
    float4 sh4 = *(const float4*)&shp[j];
    float4 o;
    o.x = (xv.x - mean) * rstd * (add1 + sc4.x) + sh4.x;
    o.y = (xv.y - mean) * rstd * (add1 + sc4.y) + sh4.y;
    o.z = (xv.z - mean) * rstd * (add1 + sc4.z) + sh4.z;
    o.w = (xv.w - mean) * rstd * (add1 + sc4.w) + sh4.w;
    if (OM & 1) *(float4*)&O32[(size_t)t * Hh + j] = o;
    if (OM & 2) {
        ushort4 h; h.x = f2bf(o.x); h.y = f2bf(o.y); h.z = f2bf(o.z); h.w = f2bf(o.w);
        *(ushort4*)&O16[(size_t)t * Hh + j] = h;
    }
}

// ---------------- 512-thread qkv GEMM + piggy-backed remaining weight prep ----------------
__global__ __launch_bounds__(512) void gemm_qkv(const unsigned short* __restrict__ A,
        const unsigned short* __restrict__ Bt, const float* __restrict__ bias,
        unsigned short* __restrict__ P0, unsigned short* __restrict__ P1,
        unsigned short* __restrict__ P2, const float* __restrict__ rc, const float* __restrict__ rsn,
        const float* __restrict__ ow, const float* __restrict__ cqw, const float* __restrict__ cow,
        const float* __restrict__ ckw, const float* __restrict__ cvw, const float* __restrict__ enc,
        unsigned short* __restrict__ owT, unsigned short* __restrict__ cqwT,
        unsigned short* __restrict__ cowT, unsigned short* __restrict__ ckvwT,
        unsigned short* __restrict__ encb, int K) {
    __shared__ unsigned short sh[2 * 128 * 32 * 2];   // 32KB: GEMM As/Bs or prep tile (17.9KB)
    int tid = threadIdx.x;
    if (blockIdx.y >= 24) {
        int t = blockIdx.x + 16 * (blockIdx.y - 24);
        if (t < 384) {
            int seg = t >> 7, lt = t & 127;
            const float* src = (seg == 0) ? ow : (seg == 1 ? cqw : cow);
            unsigned short* dst = (seg == 0) ? owT : (seg == 1 ? cqwT : cowT);
            tcast_tile512(src, dst, 1024, 1024, lt, sh, tid);
        } else if (t < 896) {
            int t2 = t - 384;
            const float* src = (t2 < 256) ? ckw : cvw;
            unsigned short* dst = (t2 < 256) ? ckvwT : (ckvwT + (size_t)1024 * 2048);
            tcast_tile512(src, dst, 2048, 1024, t2 & 255, sh, tid);
        } else {
            int i = (t - 896) * 512 + tid;
            float4 v = ((const float4*)enc)[i];
            ushort4 o; o.x = f2bf(v.x); o.y = f2bf(v.y); o.z = f2bf(v.z); o.w = f2bf(v.w);
            ((ushort4*)encb)[i] = o;
        }
        return;
    }
    unsigned short* As0 = sh;
    unsigned short* Bs0 = sh + 2 * 128 * 32;
    int m0 = blockIdx.x * 128, n0 = blockIdx.y * 128;
    int lane = tid & 63;
    int wv = tid >> 6;
    int wm = (wv >> 1) * 32, wn = (wv & 1) * 64;
    f32x4 acc[2][4] = {};
    int r0 = tid >> 2, q8 = (tid & 3) * 8;
    const unsigned short* gA = A + (size_t)(m0 + r0) * K + q8;
    const unsigned short* gB = Bt + (size_t)(n0 + r0) * K + q8;
    int ra = (lane & 15) * 32 + (lane >> 4) * 8;
    auto stage = [&](int kk, int bufi) {
        gload16(gA + kk, &As0[bufi * 128 * 32 + tid * 8]);
        gload16(gB + kk, &Bs0[bufi * 128 * 32 + tid * 8]);
    };
    int nsteps = K / 32;
    stage(0, 0);
    int cur = 0;
    for (int s = 0; s < nsteps; ++s) {
        if (s + 1 < nsteps) {
            stage((s + 1) * 32, cur ^ 1);
            asm volatile("s_waitcnt vmcnt(2)" ::: "memory");
        } else {
            asm volatile("s_waitcnt vmcnt(0)" ::: "memory");
        }
        __builtin_amdgcn_s_barrier();
        bf16x8 af[2], bf[4];
        #pragma unroll
        for (int f = 0; f < 2; ++f) af[f] = *(const bf16x8*)&As0[cur * 128 * 32 + (wm + f * 16) * 32 + ra];
        #pragma unroll
        for (int f = 0; f < 4; ++f) bf[f] = *(const bf16x8*)&Bs0[cur * 128 * 32 + (wn + f * 16) * 32 + ra];
        #pragma unroll
        for (int i = 0; i < 2; ++i)
            #pragma unroll
            for (int j = 0; j < 4; ++j)
                acc[i][j] = __builtin_amdgcn_mfma_f32_16x16x32_bf16(af[i], bf[j], acc[i][j], 0, 0, 0);
        asm volatile("s_waitcnt lgkmcnt(0)" ::: "memory");
        __builtin_amdgcn_s_barrier();
        cur ^= 1;
    }
    int colb = n0 + wn + (lane & 15);
    int rowb = m0 + wm + (lane >> 4) * 4;
    float bv[4];
    #pragma unroll
    for (int j = 0; j < 4; ++j) bv[j] = bias[colb + j * 16];
    int nh = (colb >> 6) & 15;
    int type = colb >> 10;
    float qs = (type == 0) ? 0.125f : 1.0f;   // fold 1/sqrt(HD) into Q
    #pragma unroll
    for (int i = 0; i < 2; ++i) {
        #pragma unroll
        for (int r = 0; r < 4; ++r) {
            int row = rowb + i * 16 + r;
            int b = row >> 10, s = row & 1023;
            unsigned short* dst = (type == 0) ? P0 : (type == 1 ? P1 : P2);
            size_t obase = ((size_t)((b * 16 + nh) * 1024 + s)) * 64;
            if (type < 2) {
                #pragma unroll
                for (int j = 0; j < 2; ++j) {
                    int hd = j * 16 + (lane & 15);
                    float v0 = acc[i][j][r] + bv[j];
                    float v2 = acc[i][j + 2][r] + bv[j + 2];
                    float c1 = rc[s * 64 + hd], s1 = rsn[s * 64 + hd];
                    float c2 = rc[s * 64 + hd + 32], s2 = rsn[s * 64 + hd + 32];
                    dst[obase + hd] = f2bf((v0 * c1 - v2 * s1) * qs);
                    dst[obase + hd + 32] = f2bf((v2 * c2 + v0 * s2) * qs);
                }
            } else {
                #pragma unroll
                for (int j = 0; j < 4; ++j)
                    dst[obase + j * 16 + (lane & 15)] = f2bf(acc[i][j][r] + bv[j]);
            }
        }
    }
}

// ===== 64x64-tile GEMM: 256 threads, 4 waves (2x2) of 32x32, 2-buffer =====
// EP 0: fp32 store. EP 2: ckv pack. EP 3: cQ pack *0.125. EP 4: Cf=baseb+gate*(acc+bias).
// EP 5: Cf=baseb+(acc+bias). Piggyback: blocks with y*64 >= N transpose one 128x64 tile
// of pw (4 experts' worth: tile t in [0,1024), e=t>>8) into pwT.
template<int EP>
__global__ __launch_bounds__(256) void gemm64(const unsigned short* __restrict__ A,
        const unsigned short* __restrict__ Bt, const float* __restrict__ bias,
        float* __restrict__ Cf, unsigned short* __restrict__ P0, unsigned short* __restrict__ P1,
        const float* __restrict__ baseb, const float* __restrict__ gatep,
        int M, int N, int K,
        const float* __restrict__ pw, unsigned short* __restrict__ pwT, int pR, int pC) {
    __shared__ unsigned short sh[8960];   // 17.9KB: GEMM As/Bs (8192 shorts) or prep tile
    int tid = threadIdx.x;
    if (pw != nullptr && (int)blockIdx.y * 64 >= N) {
        int t = blockIdx.x + gridDim.x * (blockIdx.y - (unsigned)(N / 64));
        int e = t >> 8, lt = t & 255;
        tcast_tile(pw + (size_t)e * ESZ, pwT + (size_t)e * ESZ, pR, pC, lt, sh, tid);
        return;
    }
    int m0 = blockIdx.x * 64, n0 = blockIdx.y * 64;
    int lane = tid & 63;
    int wv = tid >> 6;                        // 0..3
    int wm = (wv >> 1) * 32, wn = (wv & 1) * 32;
    f32x4 acc[2][2] = {};
    int r0 = tid >> 2, q8 = (tid & 3) * 8;    // r0 in [0,64)
    const unsigned short* gA = A + (size_t)(m0 + r0) * K + q8;
    const unsigned short* gB = Bt + (size_t)(n0 + r0) * K + q8;
    int ra = (lane & 15) * 32 + (lane >> 4) * 8;
    auto stage = [&](int kk, int bufi) {
        gload16(gA + kk, &sh[bufi * 2048 + tid * 8]);
        gload16(gB + kk, &sh[4096 + bufi * 2048 + tid * 8]);
    };
    int nsteps = K / 32;
    stage(0, 0);
    int cur = 0;
    for (int s = 0; s < nsteps; ++s) {
        if (s + 1 < nsteps) {
            stage((s + 1) * 32, cur ^ 1);
            asm volatile("s_waitcnt vmcnt(2)" ::: "memory");
        } else {
            asm volatile("s_waitcnt vmcnt(0)" ::: "memory");
        }
        __builtin_amdgcn_s_barrier();
        bf16x8 af[2], bf[2];
        #pragma unroll
        for (int f = 0; f < 2; ++f) {
            af[f] = *(const bf16x8*)&sh[cur * 2048 + (wm + f * 16) * 32 + ra];
            bf[f] = *(const bf16x8*)&sh[4096 + cur * 2048 + (wn + f * 16) * 32 + ra];
        }
        #pragma unroll
        for (int i = 0; i < 2; ++i)
            #pragma unroll
            for (int j = 0; j < 2; ++j)
                acc[i][j] = __builtin_amdgcn_mfma_f32_16x16x32_bf16(af[i], bf[j], acc[i][j], 0, 0, 0);
        asm volatile("s_waitcnt lgkmcnt(0)" ::: "memory");
        __builtin_amdgcn_s_barrier();
        cur ^= 1;
    }
    // D layout: col = lane&15, row = (lane>>4)*4 + reg
    int colb = n0 + wn + (lane & 15);
    int rowb = m0 + wm + (lane >> 4) * 4;
    float bv[2];
    #pragma unroll
    for (int j = 0; j < 2; ++j) bv[j] = bias[colb + j * 16];
    if (EP == 0 || EP == 4 || EP == 5) {
        #pragma unroll
        for (int j = 0; j < 2; ++j) {
            int col = colb + j * 16;
            #pragma unroll
            for (int i = 0; i < 2; ++i)
                #pragma unroll
                for (int r = 0; r < 4; ++r) {
                    int row = rowb + i * 16 + r;
                    size_t gi = (size_t)row * N + col;
                    float v = acc[i][j][r] + bv[j];
                    if (EP == 0) {
                        Cf[gi] = v;
                    } else if (EP == 4) {
                        float g = gatep[(row >> 10) * (6 * Hh) + col];
                        Cf[gi] = baseb[gi] + g * v;
                    } else {
                        Cf[gi] = baseb[gi] + v;
                    }
                }
        }
        return;
    }
    int nh = (colb >> 6) & 15;
    int type = colb >> 10;
    int hd0 = colb & 63;
    #pragma unroll
    for (int i = 0; i < 2; ++i) {
        #pragma unroll
        for (int r = 0; r < 4; ++r) {
            int row = rowb + i * 16 + r;
            if (EP == 2) {
                int b = row >> 8, s = row & 255;
                unsigned short* dst = (type == 0) ? P0 : P1;
                size_t obase = ((size_t)((b * 16 + nh) * 256 + s)) * 64;
                #pragma unroll
                for (int j = 0; j < 2; ++j)
                    dst[obase + hd0 + j * 16] = f2bf(acc[i][j][r] + bv[j]);
            } else {  // EP == 3: cQ pack, pre-scaled by 1/sqrt(HD)
                int b = row >> 10, s = row & 1023;
                size_t obase = ((size_t)((b * 16 + nh) * 1024 + s)) * 64;
                #pragma unroll
                for (int j = 0; j < 2; ++j)
                    P0[obase + hd0 + j * 16] = f2bf((acc[i][j][r] + bv[j]) * 0.125f);
            }
        }
    }
}

// ---------------- gathered MoE fc1 (512-thread / 8-wave, 128x128, 2-buf) ----------------
__global__ __launch_bounds__(512) void gemm_moe1(const unsigned short* __restrict__ A,
        const unsigned short* __restrict__ W, const float* __restrict__ bias,
        unsigned short* __restrict__ Og, const int* __restrict__ cnt,
        const int* __restrict__ offp, const int* __restrict__ gtok) {
    __shared__ unsigned short As[2][128 * 32];
    __shared__ unsigned short Bs[2][128 * 32];
    int m0 = blockIdx.x * 128;
    if (m0 >= offp[Ee]) return;
    int e = 0;
    while (offp[e + 1] <= m0) ++e;
    int base = offp[e], valid = cnt[e];
    int n0 = blockIdx.y * 128;
    int tid = threadIdx.x;
    int lane = tid & 63;
    int wv = tid >> 6;
    int wm = (wv >> 1) * 32, wn = (wv & 1) * 64;
    f32x4 acc[2][4] = {};
    int r0 = tid >> 2, q8 = (tid & 3) * 8;
    int lr0 = m0 - base + r0;
    int tok0 = gtok[base + (lr0 < valid ? lr0 : 0)];
    const unsigned short* gA = A + (size_t)tok0 * Hh + q8;
    const unsigned short* Wt = W + (size_t)e * Dd * Hh;
    const unsigned short* gB = Wt + (size_t)(n0 + r0) * Hh + q8;
    int ra = (lane & 15) * 32 + (lane >> 4) * 8;
    auto stage = [&](int kk, int bufi) {
        gload16(gA + kk, &As[bufi][tid * 8]);
        gload16(gB + kk, &Bs[bufi][tid * 8]);
    };
    int nsteps = Hh / 32;
    stage(0, 0);
    int cur = 0;
    for (int s = 0; s < nsteps; ++s) {
        if (s + 1 < nsteps) {
            stage((s + 1) * 32, cur ^ 1);
            asm volatile("s_waitcnt vmcnt(2)" ::: "memory");
        } else {
            asm volatile("s_waitcnt vmcnt(0)" ::: "memory");
        }
        __builtin_amdgcn_s_barrier();
        bf16x8 af[2], bf[4];
        #pragma unroll
        for (int f = 0; f < 2; ++f) af[f] = *(const bf16x8*)&As[cur][(wm + f * 16) * 32 + ra];
        #pragma unroll
        for (int f = 0; f < 4; ++f) bf[f] = *(const bf16x8*)&Bs[cur][(wn + f * 16) * 32 + ra];
        #pragma unroll
        for (int i = 0; i < 2; ++i)
            #pragma unroll
            for (int j = 0; j < 4; ++j)
                acc[i][j] = __builtin_amdgcn_mfma_f32_16x16x32_bf16(af[i], bf[j], acc[i][j], 0, 0, 0);
        asm volatile("s_waitcnt lgkmcnt(0)" ::: "memory");
        __builtin_amdgcn_s_barrier();
        cur ^= 1;
    }
    int colb = n0 + wn + (lane & 15);
    int rowtb = wm + (lane >> 4) * 4;
    const float* bp = bias + (size_t)e * Dd;
    #pragma unroll
    for (int j = 0; j < 4; ++j) {
        int col = colb + j * 16;
        float bv = bp[col];
        #pragma unroll
        for (int i = 0; i < 2; ++i) {
            #pragma unroll
            for (int r = 0; r < 4; ++r) {
                int rt = rowtb + i * 16 + r;
                if (m0 - base + rt < valid)
                    Og[(size_t)(m0 + rt) * Dd + col] = f2bf(geluf(acc[i][j][r] + bv));
            }
        }
    }
}

// ---------------- gathered MoE fc2 (512-thread, 128x128, split-K=2): stores y[z][g][col] ----------------
__global__ __launch_bounds__(512) void gemm_moe2(const unsigned short* __restrict__ A,
        const unsigned short* __restrict__ W, const float* __restrict__ bias,
        float* __restrict__ y, const int* __restrict__ cnt,
        const int* __restrict__ offp) {
    __shared__ unsigned short As[2][128 * 32];
    __shared__ unsigned short Bs[2][128 * 32];
    int m0 = blockIdx.x * 128;
    if (m0 >= offp[Ee]) return;
    int e = 0;
    while (offp[e + 1] <= m0) ++e;
    int base = offp[e], valid = cnt[e];
    int n0 = blockIdx.y * 128;
    int kz = blockIdx.z;                      // 0 or 1: K half
    int k0 = kz * (Dd / 2);
    int tid = threadIdx.x;
    int lane = tid & 63;
    int wv = tid >> 6;
    int wm = (wv >> 1) * 32, wn = (wv & 1) * 64;
    f32x4 acc[2][4] = {};
    int r0 = tid >> 2, q8 = (tid & 3) * 8;
    const unsigned short* gA = A + (size_t)(m0 + r0) * Dd + k0 + q8;
    const unsigned short* Wt = W + (size_t)e * Hh * Dd;
    const unsigned short* gB = Wt + (size_t)(n0 + r0) * Dd + k0 + q8;
    int ra = (lane & 15) * 32 + (lane >> 4) * 8;
    auto stage = [&](int kk, int bufi) {
        gload16(gA + kk, &As[bufi][tid * 8]);
        gload16(gB + kk, &Bs[bufi][tid * 8]);
    };
    int nsteps = (Dd / 2) / 32;
    stage(0, 0);
    int cur = 0;
    for (int s = 0; s < nsteps; ++s) {
        if (s + 1 < nsteps) {
            stage((s + 1) * 32, cur ^ 1);
            asm volatile("s_waitcnt vmcnt(2)" ::: "memory");
        } else {
            asm volatile("s_waitcnt vmcnt(0)" ::: "memory");
        }
        __builtin_amdgcn_s_barrier();
        bf16x8 af[2], bf[4];
        #pragma unroll
        for (int f = 0; f < 2; ++f) af[f] = *(const bf16x8*)&As[cur][(wm + f * 16) * 32 + ra];
        #pragma unroll
        for (int f = 0; f < 4; ++f) bf[f] = *(const bf16x8*)&Bs[cur][(wn + f * 16) * 32 + ra];
        #pragma unroll
        for (int i = 0; i < 2; ++i)
            #pragma unroll
            for (int j = 0; j < 4; ++j)
                acc[i][j] = __builtin_amdgcn_mfma_f32_16x16x32_bf16(af[i], bf[j], acc[i][j], 0, 0, 0);
        asm volatile("s_waitcnt lgkmcnt(0)" ::: "memory");
        __builtin_amdgcn_s_barrier();
        cur ^= 1;
    }
    int colb = n0 + wn + (lane & 15);
    int rowtb = wm + (lane >> 4) * 4;
    const float* bp = bias + (size_t)e * Hh;
    float* yz = y + (size_t)kz * PADROWS * Hh;
    #pragma unroll
    for (int j = 0; j < 4; ++j) {
        int col = colb + j * 16;
        float bv = (kz == 0) ? bp[col] : 0.0f;
        #pragma unroll
        for (int i = 0; i < 2; ++i) {
            #pragma unroll
            for (int r = 0; r < 4; ++r) {
                int rt = rowtb + i * 16 + r;
                int g = m0 + rt;
                if (g - base < valid)
                    yz[(size_t)g * Hh + col] = acc[i][j][r] + bv;
            }
        }
    }
}

// ---------------- MoE combine: out[t] += g2 .* (w0*(y0+y1)[g0] + w1*(y0+y1)[g1]) ----------------
__global__ __launch_bounds__(256) void moe_combine(const float* __restrict__ y,
        const int* __restrict__ gpos, const float* __restrict__ gwt,
        const float* __restrict__ gate2, float* __restrict__ outp) {
    int t = blockIdx.x;
    int j = threadIdx.x * 4;
    int g0 = gpos[2 * t], g1 = gpos[2 * t + 1];
    float w0 = gwt[g0], w1 = gwt[g1];
    const float* g2p = gate2 + (size_t)(t >> 10) * (6 * Hh);
    const size_t soff = (size_t)PADROWS * Hh;
    float4 a0 = *(const float4*)&y[(size_t)g0 * Hh + j];
    float4 a1 = *(const float4*)&y[soff + (size_t)g0 * Hh + j];
    float4 b0 = *(const float4*)&y[(size_t)g1 * Hh + j];
    float4 b1 = *(const float4*)&y[soff + (size_t)g1 * Hh + j];
    float4 g2 = *(const float4*)&g2p[j];
    float4 o = *(const float4*)&outp[(size_t)t * Hh + j];
    o.x += g2.x * (w0 * (a0.x + a1.x) + w1 * (b0.x + b1.x));
    o.y += g2.y * (w0 * (a0.y + a1.y) + w1 * (b0.y + b1.y));
    o.z += g2.z * (w0 * (a0.z + a1.z) + w1 * (b0.z + b1.z));
    o.w += g2.w * (w0 * (a0.w + a1.w) + w1 * (b0.w + b1.w));
    *(float4*)&outp[(size_t)t * Hh + j] = o;
}

// ---------------- MFMA flash attention + piggy-backed ew1 transposes (experts 0-3) --------
__global__ __launch_bounds__(256) void fattn_m(const unsigned short* __restrict__ Qp,
        const unsigned short* __restrict__ Kp, const unsigned short* __restrict__ Vtp,
        unsigned short* __restrict__ O, int Skv,
        const float* __restrict__ ew1, unsigned short* __restrict__ ew1T) {
    __shared__ unsigned short shbuf[4 * 64 * 72];   // 36,864B; prep tile needs 8,960 shorts
    int tid = threadIdx.x;
    if (blockIdx.y >= 32) {
        int tile = blockIdx.x + 16 * (blockIdx.y - 32);   // 0..1023 (ew1 experts 0-3)
        int e = tile >> 8, lt = tile & 255;
        tcast_tile(ew1 + (size_t)e * ESZ, ew1T + (size_t)e * ESZ, 1024, 2048, lt, shbuf, tid);
        return;
    }
    unsigned short* Qs  = shbuf;
    unsigned short* Ks  = shbuf + 64 * 72;
    unsigned short* Vts = shbuf + 2 * 64 * 72;
    unsigned short* Ps  = shbuf + 3 * 64 * 72;
    int q0 = blockIdx.x * 64;
    int bh = blockIdx.y;
    int b = bh >> 4, nh = bh & 15;
    int lane = tid & 63, w = tid >> 6;
    int sr = tid >> 2, sp = (tid & 3) * 16;   // staging: row, 16-elem chunk
    {
        const unsigned short* src = &Qp[((size_t)bh * 1024 + q0 + sr) * 64 + sp];
        *(ushort8*)&Qs[sr * 72 + sp] = *(const ushort8*)&src[0];
        *(ushort8*)&Qs[sr * 72 + sp + 8] = *(const ushort8*)&src[8];
    }
    f32x4 acc[4] = {};
    float m_old[4], l_run[4];
    #pragma unroll
    for (int r = 0; r < 4; ++r) { m_old[r] = -1e30f; l_run[r] = 0.0f; }
    int wrow = w * 16;
    int k8 = (lane >> 4) * 8;
    ushort8 pkA, pkB, pvA, pvB;
    {
        const unsigned short* ksrc = &Kp[((size_t)bh * Skv + sr) * 64 + sp];
        pkA = *(const ushort8*)&ksrc[0];
        pkB = *(const ushort8*)&ksrc[8];
        const unsigned short* vsrc = &Vtp[((size_t)bh * 64 + sr) * Skv + sp];
        pvA = *(const ushort8*)&vsrc[0];
        pvB = *(const ushort8*)&vsrc[8];
    }
    for (int k0 = 0; k0 < Skv; k0 += 64) {
        asm volatile("s_waitcnt lgkmcnt(0)" ::: "memory");
        __builtin_amdgcn_s_barrier();                  // Ks/Vts free (prev PV reads done)
        *(ushort8*)&Ks[sr * 72 + sp] = pkA;
        *(ushort8*)&Ks[sr * 72 + sp + 8] = pkB;
        *(ushort8*)&Vts[sr * 72 + sp] = pvA;
        *(ushort8*)&Vts[sr * 72 + sp + 8] = pvB;
        if (k0 + 64 < Skv) {
            const unsigned short* ksrc = &Kp[((size_t)bh * Skv + k0 + 64 + sr) * 64 + sp];
            pkA = *(const ushort8*)&ksrc[0];
            pkB = *(const ushort8*)&ksrc[8];
            const unsigned short* vsrc = &Vtp[((size_t)bh * 64 + sr) * Skv + k0 + 64 + sp];
            pvA = *(const ushort8*)&vsrc[0];
            pvB = *(const ushort8*)&vsrc[8];
        }
        asm volatile("s_waitcnt lgkmcnt(0)" ::: "memory");
        __builtin_amdgcn_s_barrier();                  // staging (and iter-0 Qs) visible
        bf16x8 aq0 = *(const bf16x8*)&Qs[(wrow + (lane & 15)) * 72 + k8];
        bf16x8 aq1 = *(const bf16x8*)&Qs[(wrow + (lane & 15)) * 72 + 32 + k8];
        f32x4 sf[4];
        __builtin_amdgcn_s_setprio(1);
        #pragma unroll
        for (int j = 0; j < 4; ++j) {
            bf16x8 bk0 = *(const bf16x8*)&Ks[(j * 16 + (lane & 15)) * 72 + k8];
            bf16x8 bk1 = *(const bf16x8*)&Ks[(j * 16 + (lane & 15)) * 72 + 32 + k8];
            f32x4 z = {};
            z = __builtin_amdgcn_mfma_f32_16x16x32_bf16(aq0, bk0, z, 0, 0, 0);
            z = __builtin_amdgcn_mfma_f32_16x16x32_bf16(aq1, bk1, z, 0, 0, 0);
            sf[j] = z;
        }
        __builtin_amdgcn_s_setprio(0);
        float p[4][4];
        float fsc[4];
        #pragma unroll
        for (int r = 0; r < 4; ++r) {
            float mx = fmaxf(fmaxf(sf[0][r], sf[1][r]), fmaxf(sf[2][r], sf[3][r]));
            #pragma unroll
            for (int mk = 1; mk < 16; mk <<= 1) mx = fmaxf(mx, __shfl_xor(mx, mk));
            float mn = fmaxf(m_old[r], mx);
            float f = __expf(m_old[r] - mn);
            float rs = 0.0f;
            #pragma unroll
            for (int j = 0; j < 4; ++j) {
                p[j][r] = __expf(sf[j][r] - mn);
                rs += p[j][r];
            }
            #pragma unroll
            for (int mk = 1; mk < 16; mk <<= 1) rs += __shfl_xor(rs, mk);
            l_run[r] = l_run[r] * f + rs;
            m_old[r] = mn;
            fsc[r] = f;
        }
        #pragma unroll
        for (int jd = 0; jd < 4; ++jd)
            #pragma unroll
            for (int r = 0; r < 4; ++r) acc[jd][r] *= fsc[r];
        #pragma unroll
        for (int j = 0; j < 4; ++j)
            #pragma unroll
            for (int r = 0; r < 4; ++r)
                Ps[(wrow + (lane >> 4) * 4 + r) * 72 + j * 16 + (lane & 15)] = f2bf(p[j][r]);
        asm volatile("s_waitcnt lgkmcnt(0)" ::: "memory");
        __builtin_amdgcn_s_barrier();                  // Ps visible
        bf16x8 ap0 = *(const bf16x8*)&Ps[(wrow + (lane & 15)) * 72 + k8];
        bf16x8 ap1 = *(const bf16x8*)&Ps[(wrow + (lane & 15)) * 72 + 32 + k8];
        __builtin_amdgcn_s_setprio(1);
        #pragma unroll
        for (int jd = 0; jd < 4; ++jd) {
            bf16x8 bv0 = *(const bf16x8*)&Vts[(jd * 16 + (lane & 15)) * 72 + k8];
            bf16x8 bv1 = *(const bf16x8*)&Vts[(jd * 16 + (lane & 15)) * 72 + 32 + k8];
            acc[jd] = __builtin_amdgcn_mfma_f32_16x16x32_bf16(ap0, bv0, acc[jd], 0, 0, 0);
            acc[jd] = __builtin_amdgcn_mfma_f32_16x16x32_bf16(ap1, bv1, acc[jd], 0, 0, 0);
        }
        __builtin_amdgcn_s_setprio(0);
    }
    float inv[4];
    #pragma unroll
    for (int r = 0; r < 4; ++r) inv[r] = 1.0f / l_run[r];
    #pragma unroll
    for (int jd = 0; jd < 4; ++jd)
        #pragma unroll
        for (int r = 0; r < 4; ++r)
            O[((size_t)(b * Ss + q0 + wrow + (lane >> 4) * 4 + r)) * Hh + nh * 64 + jd * 16 + (lane & 15)]
                = f2bf(acc[jd][r] * inv[r]);
}

// ---------------- MoE gate: one wave per token, coalesced ----------------
__global__ __launch_bounds__(256) void gate_kernel(const float* __restrict__ h,
        const float* __restrict__ gw, float* __restrict__ probs, int* __restrict__ topi,
        float* __restrict__ topw) {
    int t = blockIdx.x * 4 + (threadIdx.x >> 6);
    int lane = threadIdx.x & 63;
    const float* hp = h + (size_t)t * Hh;
    float lg[Ee] = {};
    #pragma unroll
    for (int s = 0; s < 4; ++s) {
        int d0 = s * 256 + lane * 4;
        float4 hv = *(const float4*)&hp[d0];
        float hv4[4] = {hv.x, hv.y, hv.z, hv.w};
        #pragma unroll
        for (int c = 0; c < 4; ++c) {
            float hx = hv4[c];
            const float* g0 = &gw[(size_t)(d0 + c) * Ee];
            #pragma unroll
            for (int e = 0; e < Ee; ++e) lg[e] += hx * g0[e];
        }
    }
    #pragma unroll
    for (int e = 0; e < Ee; ++e)
        #pragma unroll
        for (int mk = 1; mk < 64; mk <<= 1) lg[e] += __shfl_xor(lg[e], mk);
    if (lane == 0) {
        float m = lg[0];
        #pragma unroll
        for (int e = 1; e < Ee; ++e) m = fmaxf(m, lg[e]);
        float ssum = 0;
        #pragma unroll
        for (int e = 0; e < Ee; ++e) { lg[e] = expf(lg[e] - m); ssum += lg[e]; }
        float inv = 1.0f / ssum;
        #pragma unroll
        for (int e = 0; e < Ee; ++e) { lg[e] *= inv; probs[t * Ee + e] = lg[e]; }
        int i0 = 0;
        #pragma unroll
        for (int e = 1; e < Ee; ++e) if (lg[e] > lg[i0]) i0 = e;
        int i1 = (i0 == 0) ? 1 : 0;
        #pragma unroll
        for (int e = 0; e < Ee; ++e) if (e != i1 && e != i0 && lg[e] > lg[i1]) i1 = e;
        float w0 = lg[i0], w1 = lg[i1];
        float inv2 = 1.0f / (w0 + w1);
        topi[t * 2] = i0; topi[t * 2 + 1] = i1;
        topw[t * 2] = w0 * inv2; topw[t * 2 + 1] = w1 * inv2;
    }
}

// ---------------- fused MoE prep: count + scan + scatter + aux (single 1024-thread block) ----------------
__global__ __launch_bounds__(1024) void moe_prep(const float* __restrict__ probs,
        const int* __restrict__ topi, const float* __restrict__ topw,
        int* __restrict__ cnt, int* __restrict__ offp,
        int* __restrict__ gtok, float* __restrict__ gwt, int* __restrict__ gpos,
        float* __restrict__ auxout) {
    __shared__ int scnt[Ee], spos[Ee], soff[Ee + 1];
    __shared__ float sS[Ee], sC[Ee];
    int tid = threadIdx.x;
    if (tid < Ee) { scnt[tid] = 0; spos[tid] = 0; sS[tid] = 0.0f; sC[tid] = 0.0f; }
    __syncthreads();
    float lp[Ee] = {};
    float lc[Ee] = {};
    for (int t = tid; t < Tt; t += 1024) {
        int a0 = topi[2 * t], a1 = topi[2 * t + 1];
        atomicAdd(&scnt[a0], 1);
        atomicAdd(&scnt[a1], 1);
        #pragma unroll
        for (int e = 0; e < Ee; ++e) lp[e] += probs[t * Ee + e];
        lc[a0] += 1.0f; lc[a1] += 1.0f;
    }
    #pragma unroll
    for (int e = 0; e < Ee; ++e) {
        atomicAdd(&sS[e], lp[e]);
        atomicAdd(&sC[e], lc[e]);
    }
    __syncthreads();
    if (tid == 0) {
        int acc = 0;
        for (int e = 0; e < Ee; ++e) { soff[e] = acc; acc += (scnt[e] + 127) & ~127; }
        soff[Ee] = acc;
        float aux = 0.0f;
        for (int e = 0; e < Ee; ++e) aux += sS[e] * sC[e];
        auxout[0] = aux * (8.0f / 4096.0f);   // E/(B*B*S)
    }
    if (tid < Ee) cnt[tid] = scnt[tid];
    __syncthreads();
    if (tid <= Ee) offp[tid] = soff[tid];
    for (int t = tid; t < Tt; t += 1024) {
        #pragma unroll
        for (int s = 0; s < 2; ++s) {
            int e = topi[2 * t + s];
            int pos = atomicAdd(&spos[e], 1);
            int g = soff[e] + pos;
            gtok[g] = t;
            gwt[g] = topw[2 * t + s];
            gpos[2 * t + s] = g;
        }
    }
}

extern "C" void kernel_launch(void* const* d_in, const int* in_sizes, int n_in,
                              void* d_out, int out_size, void* d_ws, size_t ws_size,
                              hipStream_t stream) {
    (void)in_sizes; (void)n_in; (void)out_size; (void)ws_size;
    const float* x    = (const float*)d_in[0];
    const float* cond = (const float*)d_in[1];
    const float* enc  = (const float*)d_in[2];
    const float* rc   = (const float*)d_in[3];
    const float* rsn  = (const float*)d_in[4];
    const float* adw  = (const float*)d_in[5];
    const float* adb  = (const float*)d_in[6];
    const float* qw  = (const float*)d_in[7];  const float* qb  = (const float*)d_in[8];
    const float* kw  = (const float*)d_in[9];  const float* kb2 = (const float*)d_in[10];
    const float* vw  = (const float*)d_in[11]; const float* vb  = (const float*)d_in[12];
    const float* ow  = (const float*)d_in[13]; const float* ob  = (const float*)d_in[14];
    const float* cqw = (const float*)d_in[15]; const float* cqb = (const float*)d_in[16];
    const float* ckw = (const float*)d_in[17]; const float* ckb = (const float*)d_in[18];
    const float* cvw = (const float*)d_in[19]; const float* cvb = (const float*)d_in[20];
    const float* cow = (const float*)d_in[21]; const float* cob = (const float*)d_in[22];
    const float* cng = (const float*)d_in[23]; const float* cnb = (const float*)d_in[24];
    const float* gatew = (const float*)d_in[25];
    const float* ew1 = (const float*)d_in[26]; const float* eb1 = (const float*)d_in[27];
    const float* ew2 = (const float*)d_in[28]; const float* eb2 = (const float*)d_in[29];
    float* out = (float*)d_out;

    char* ws = (char*)d_ws;
    size_t off = 0;
    auto alloc = [&](size_t bytes) {
        char* p = ws + off;
        off += (bytes + 255) & ~(size_t)255;
        return (void*)p;
    };
    // fp32 buffers
    float* hbuf   = (float*)alloc((size_t)Tt * Hh * 4);
    float* mod    = (float*)alloc((size_t)Bb * 6 * Hh * 4);
    float* modp   = (float*)alloc((size_t)Bb * 16 * 6 * Hh * 4);
    float* probs  = (float*)alloc((size_t)Tt * Ee * 4);
    float* topw   = (float*)alloc((size_t)Tt * 2 * 4);
    int*   topi   = (int*)alloc((size_t)Tt * 2 * 4);
    float* qkvb   = (float*)alloc(3072 * 4);
    float* ckvb   = (float*)alloc(2048 * 4);
    int*   cntbuf = (int*)alloc(16 * 4);
    int*   offp   = (int*)alloc(16 * 4);
    int*   gtok   = (int*)alloc((size_t)PADROWS * 4);
    float* gwt    = (float*)alloc((size_t)PADROWS * 4);
    int*   gpos   = (int*)alloc((size_t)Tt * 2 * 4);
    // bf16 buffers
    typedef unsigned short u16;
    u16* h1b   = (u16*)alloc((size_t)Tt * Hh * 2);
    u16* hcb   = (u16*)alloc((size_t)Tt * Hh * 2);
    u16* h2b   = (u16*)alloc((size_t)Tt * Hh * 2);
    u16* abb   = (u16*)alloc((size_t)Tt * Hh * 2);
    u16* encb  = (u16*)alloc((size_t)Bb * Ll * Cc * 2);
    u16* actg  = (u16*)alloc((size_t)PADROWS * Dd * 2);
    // packed attention operands
    u16* Qb16  = (u16*)alloc((size_t)32 * 1024 * 64 * 2);
    u16* Kb16  = (u16*)alloc((size_t)32 * 1024 * 64 * 2);
    u16* Vb16  = (u16*)alloc((size_t)32 * 1024 * 64 * 2);
    u16* Vt16  = (u16*)alloc((size_t)32 * 64 * 1024 * 2);
    u16* cQ16  = (u16*)alloc((size_t)32 * 1024 * 64 * 2);
    u16* cK16  = (u16*)alloc((size_t)32 * 256 * 64 * 2);
    u16* cV16  = (u16*)alloc((size_t)32 * 256 * 64 * 2);
    u16* cVt16 = (u16*)alloc((size_t)32 * 64 * 256 * 2);
    // bf16 transposed weights [N][K]
    u16* qkvwT = (u16*)alloc((size_t)3072 * 1024 * 2);
    u16* owT   = (u16*)alloc((size_t)1024 * 1024 * 2);
    u16* cqwT  = (u16*)alloc((size_t)1024 * 1024 * 2);
    u16* ckvwT = (u16*)alloc((size_t)2048 * 2048 * 2);
    u16* cowT  = (u16*)alloc((size_t)1024 * 1024 * 2);
    u16* ew1T  = (u16*)alloc((size_t)Ee * Hh * Dd * 2);
    u16* ew2T  = (u16*)alloc((size_t)Ee * Dd * Hh * 2);
    // MoE fc2 split-K partials y[2][PADROWS][Hh] fp32 (41.9 MB), aliased over the
    // Qb16..ckvwT span (~43 MB, all dead after step 11). ew1T/ew2T untouched.
    float* ybuf = (float*)Qb16;

    dim3 blk(256);
    dim3 blk512(512);
    // 0. fused prep incl. deterministic AdaLN K-split matvec (partials), then slice reduce
    prep_all<<<dim3(1172), blk, 0, stream>>>(qw, kw, vw, qb, kb2, vb, ckb, cvb,
        cond, adw, adb, qkvwT, qkvb, ckvb, modp);
    mod_reduce<<<dim3(Bb * 6 * Hh / 256), blk, 0, stream>>>(modp, mod);
    // 2. h1 = ln(x)*(1+sc1)+sh1  -> bf16
    ln_affine<2><<<dim3(Tt), blk, 0, stream>>>(x, nullptr, h1b, mod + Hh, mod + 0, 6 * Hh, 1.0f);
    // 3. fused qkv projection + rope + pack (+1408 piggy-backed prep blocks)
    gemm_qkv<<<dim3(16, 24 + 88), blk512, 0, stream>>>(h1b, qkvwT, qkvb,
        Qb16, Kb16, Vb16, rc, rsn,
        ow, cqw, cow, ckw, cvw, enc, owT, cqwT, cowT, ckvwT, encb, 1024);
    // 4. V transpose [bh][64][1024]
    vtrans16<<<dim3(32, 2, 32), blk, 0, stream>>>(Vb16, Vt16, 1024);
    // 5. MFMA self-attention (+1024 ew1 expert-0..3 transpose tiles)
    fattn_m<<<dim3(16, 32 + 64), blk, 0, stream>>>(Qb16, Kb16, Vt16, abb, 1024,
        ew1, ew1T);
    // 6+7. output projection fused with residual (+1024 ew1 expert-4..7 tiles)
    gemm64<4><<<dim3(Tt / 64, Hh / 64 + 32), blk, 0, stream>>>(abb, owT, ob, out,
        nullptr, nullptr, x, mod + 2 * Hh, Tt, Hh, 1024,
        ew1 + 4 * ESZ, ew1T + 4 * ESZ, 1024, 2048);
    // 8. hc = ln(x1)*cn_g + cn_b -> bf16
    ln_affine<2><<<dim3(Tt), blk, 0, stream>>>(out, nullptr, hcb, cng, cnb, 0, 0.0f);
    // 9. cross q (packed, pre-scaled) (+1024 ew2 expert-0..3 tiles) + fused ck/cv (packed)
    gemm64<3><<<dim3(Tt / 64, Hh / 64 + 32), blk, 0, stream>>>(hcb, cqwT, cqb, nullptr,
        cQ16, nullptr, nullptr, nullptr, Tt, Hh, 1024,
        ew2, ew2T, 2048, 1024);
    gemm64<2><<<dim3(Bb * Ll / 64, 2048 / 64), blk, 0, stream>>>(encb, ckvwT, ckvb, nullptr,
        cK16, cV16, nullptr, nullptr, Bb * Ll, 2048, Cc,
        nullptr, nullptr, 0, 0);
    vtrans16<<<dim3(8, 2, 32), blk, 0, stream>>>(cV16, cVt16, 256);
    // 10. MFMA cross-attention (kv 256; no piggy-back blocks)
    fattn_m<<<dim3(16, 32), blk, 0, stream>>>(cQ16, cK16, cVt16, abb, 256,
        ew1, ew1T);
    // 11+12. cross output projection fused with residual (+1024 ew2 expert-4..7 tiles)
    gemm64<5><<<dim3(Tt / 64, Hh / 64 + 32), blk, 0, stream>>>(abb, cowT, cob, out,
        nullptr, nullptr, out, nullptr, Tt, Hh, 1024,
        ew2 + 4 * ESZ, ew2T + 4 * ESZ, 2048, 1024);
    // 13. h2 = ln(x2)*(1+sc2)+sh2 -> fp32 + bf16
    ln_affine<3><<<dim3(Tt), blk, 0, stream>>>(out, hbuf, h2b, mod + 4 * Hh, mod + 3 * Hh, 6 * Hh, 1.0f);
    // 14. gate + fused prep (count/scan/scatter/aux)
    gate_kernel<<<dim3(Tt / 4), blk, 0, stream>>>(hbuf, gatew, probs, topi, topw);
    moe_prep<<<dim3(1), dim3(1024), 0, stream>>>(probs, topi, topw, cntbuf, offp, gtok, gwt,
        gpos, out + (size_t)Tt * Hh);
    // 16+17. gathered MoE (128x128); fc2 split-K=2 -> y partials; combine folds residual
    gemm_moe1<<<dim3(PADROWS / 128, Dd / 128), blk512, 0, stream>>>(h2b, ew1T, eb1, actg, cntbuf, offp, gtok);
    gemm_moe2<<<dim3(PADROWS / 128, Hh / 128, 2), blk512, 0, stream>>>(actg, ew2T, eb2, ybuf, cntbuf, offp);
    moe_combine<<<dim3(Tt), blk, 0, stream>>>(ybuf, gpos, gwt, mod + 5 * Hh, out);
}